// Round 1
// baseline (17806.628 us; speedup 1.0000x reference)
//
#include <hip/hip_runtime.h>
#include <cmath>
#include <cstddef>

// Problem constants (from reference): S=T=64, B=32, H=1024, G=4H, V=32000
constexpr int S = 64, T = 64, B = 32, H = 1024, G = 4096, V = 32000;

__device__ __forceinline__ float sigf(float x) { return 1.f / (1.f + expf(-x)); }

// ---------------- utility kernels ----------------
__global__ void zero_kernel(float* __restrict__ p, int n) {
  int i = blockIdx.x * 256 + threadIdx.x;
  if (i < n) p[i] = 0.f;
}

// attn_W is [S][2H]; build attn_WT [2H][S] so score kernel reads coalesced.
__global__ void transpose_attn(const float* __restrict__ W, float* __restrict__ WT) {
  int i = blockIdx.x * 256 + threadIdx.x;   // over 2H*S = 131072
  int k = i >> 6, s = i & 63;
  WT[i] = W[(size_t)s * (2 * H) + k];       // WT[k*64 + s]
}

// ---------------- encoder input GEMM ----------------
// encX[m][n] = sum_k enc_emb[input[m]][k] * Wih[n][k]   (m = s*B+b, 2048 rows)
__global__ __launch_bounds__(256)
void gemm_encx(const int* __restrict__ tok, const float* __restrict__ emb,
               const float* __restrict__ Wih, float* __restrict__ out) {
  __shared__ float At[32][33];
  __shared__ float Wt[128][33];
  const int tid = threadIdx.x;
  const int nbase = blockIdx.x * 128;
  const int mbase = blockIdx.y * 32;
  const int ra = tid >> 3, kqa = (tid & 7) * 4;
  const int rw = tid >> 1, kqw = (tid & 1) * 16;
  const int nq = (tid & 31) * 4, mq = (tid >> 5) * 4;
  float acc[4][4] = {};
  const float* arow = emb + (size_t)tok[mbase + ra] * H;
  const float* wrow0 = Wih + (size_t)(nbase + rw) * H + kqw;
  for (int k0 = 0; k0 < 1024; k0 += 32) {
    float4 av = *reinterpret_cast<const float4*>(arow + k0 + kqa);
    At[ra][kqa + 0] = av.x; At[ra][kqa + 1] = av.y;
    At[ra][kqa + 2] = av.z; At[ra][kqa + 3] = av.w;
#pragma unroll
    for (int q = 0; q < 4; ++q) {
      float4 wv = *reinterpret_cast<const float4*>(wrow0 + k0 + q * 4);
      Wt[rw][kqw + q * 4 + 0] = wv.x; Wt[rw][kqw + q * 4 + 1] = wv.y;
      Wt[rw][kqw + q * 4 + 2] = wv.z; Wt[rw][kqw + q * 4 + 3] = wv.w;
    }
    __syncthreads();
#pragma unroll
    for (int kk = 0; kk < 32; ++kk) {
      float a[4], w[4];
#pragma unroll
      for (int i = 0; i < 4; ++i) a[i] = At[mq + i][kk];
#pragma unroll
      for (int j = 0; j < 4; ++j) w[j] = Wt[nq + j][kk];
#pragma unroll
      for (int i = 0; i < 4; ++i)
#pragma unroll
        for (int j = 0; j < 4; ++j) acc[i][j] = fmaf(a[i], w[j], acc[i][j]);
    }
    __syncthreads();
  }
#pragma unroll
  for (int i = 0; i < 4; ++i) {
    float4 v = make_float4(acc[i][0], acc[i][1], acc[i][2], acc[i][3]);
    *reinterpret_cast<float4*>(out + (size_t)(mbase + mq + i) * G + nbase + nq) = v;
  }
}

// ---------------- generic M=32 GEMM: C = [A0|A1] @ [W0|W1]^T ----------------
// A0/A1: [32][1024] row-major. W halves: W(n,k<1024)=W0[n*ldw0+k], else W1[n*ldw1+k-1024].
// SPLITK>1: writes partials[(sk*32+m)*N + n]. SPLITK==1: writes out[m*N+n] (+bias).
template <bool TWO, int SPLITK, bool BIAS>
__global__ __launch_bounds__(256)
void gemm32(const float* __restrict__ A0, const float* __restrict__ A1,
            const float* __restrict__ W0, int ldw0,
            const float* __restrict__ W1, int ldw1,
            const float* __restrict__ bias,
            float* __restrict__ out, int N) {
  constexpr int KTOT = TWO ? 2048 : 1024;
  constexpr int KS = KTOT / SPLITK;
  __shared__ float At[32][33];
  __shared__ float Wt[128][33];
  const int tid = threadIdx.x;
  const int nbase = blockIdx.x * 128;
  const int kbase = blockIdx.y * KS;
  const int ra = tid >> 3, kqa = (tid & 7) * 4;
  const int rw = tid >> 1, kqw = (tid & 1) * 16;
  const int nq = (tid & 31) * 4, mq = (tid >> 5) * 4;
  float acc[4][4] = {};
  for (int k0 = kbase; k0 < kbase + KS; k0 += 32) {
    {
      int k = k0 + kqa;
      const float* src = (!TWO || k < 1024) ? (A0 + (size_t)ra * 1024 + k)
                                            : (A1 + (size_t)ra * 1024 + (k - 1024));
      float4 av = *reinterpret_cast<const float4*>(src);
      At[ra][kqa + 0] = av.x; At[ra][kqa + 1] = av.y;
      At[ra][kqa + 2] = av.z; At[ra][kqa + 3] = av.w;
    }
    {
      int k = k0 + kqw;
      int n = nbase + rw;
      const float* src = (!TWO || k < 1024) ? (W0 + (size_t)n * ldw0 + k)
                                            : (W1 + (size_t)n * ldw1 + (k - 1024));
#pragma unroll
      for (int q = 0; q < 4; ++q) {
        float4 wv = *reinterpret_cast<const float4*>(src + q * 4);
        Wt[rw][kqw + q * 4 + 0] = wv.x; Wt[rw][kqw + q * 4 + 1] = wv.y;
        Wt[rw][kqw + q * 4 + 2] = wv.z; Wt[rw][kqw + q * 4 + 3] = wv.w;
      }
    }
    __syncthreads();
#pragma unroll
    for (int kk = 0; kk < 32; ++kk) {
      float a[4], w[4];
#pragma unroll
      for (int i = 0; i < 4; ++i) a[i] = At[mq + i][kk];
#pragma unroll
      for (int j = 0; j < 4; ++j) w[j] = Wt[nq + j][kk];
#pragma unroll
      for (int i = 0; i < 4; ++i)
#pragma unroll
        for (int j = 0; j < 4; ++j) acc[i][j] = fmaf(a[i], w[j], acc[i][j]);
    }
    __syncthreads();
  }
  if (SPLITK == 1) {
#pragma unroll
    for (int i = 0; i < 4; ++i) {
      float4 v = make_float4(acc[i][0], acc[i][1], acc[i][2], acc[i][3]);
      if (BIAS) {
        v.x += bias[nbase + nq + 0]; v.y += bias[nbase + nq + 1];
        v.z += bias[nbase + nq + 2]; v.w += bias[nbase + nq + 3];
      }
      *reinterpret_cast<float4*>(out + (size_t)(mq + i) * N + nbase + nq) = v;
    }
  } else {
    float* dst = out + (size_t)blockIdx.y * 32 * N;
#pragma unroll
    for (int i = 0; i < 4; ++i) {
      float4 v = make_float4(acc[i][0], acc[i][1], acc[i][2], acc[i][3]);
      *reinterpret_cast<float4*>(dst + (size_t)(mq + i) * N + nbase + nq) = v;
    }
  }
}

// ---------------- LSTM pointwise (reduces split-K partials) ----------------
// gates[b][n] = bias[n] + (baseX ? baseX[b*G+n] : 0) + sum_sk parts[(sk*32+b)*G+n]
__global__ void lstm_update(const float* __restrict__ parts, const float* __restrict__ baseX,
                            const float* __restrict__ bias, float* __restrict__ h,
                            float* __restrict__ c, float* __restrict__ enc_out_slot) {
  int idx = blockIdx.x * 256 + threadIdx.x;   // 0..B*H-1
  int b = idx >> 10, hh = idx & 1023;
  float g4[4];
#pragma unroll
  for (int q = 0; q < 4; ++q) {
    int n = q * H + hh;
    float v = bias[n];
    if (baseX) v += baseX[(size_t)b * G + n];
#pragma unroll
    for (int sk = 0; sk < 4; ++sk) v += parts[((size_t)sk * 32 + b) * G + n];
    g4[q] = v;
  }
  float ig = sigf(g4[0]), fg = sigf(g4[1]), gg = tanhf(g4[2]), og = sigf(g4[3]);
  float cn = fg * c[idx] + ig * gg;
  float hn = og * tanhf(cn);
  c[idx] = cn;
  h[idx] = hn;
  if (enc_out_slot) enc_out_slot[idx] = hn;
}

// ---------------- decoder embedding gather + relu ----------------
__global__ void dec_gather_x(const int* __restrict__ use_tf, const int* __restrict__ target,
                             const int* __restrict__ prev_tok, const float* __restrict__ emb,
                             float* __restrict__ x_buf, int t) {
  int idx = blockIdx.x * 256 + threadIdx.x;
  int b = idx >> 10, k = idx & 1023;
  int tok = 0;
  if (t > 0) tok = (*use_tf) ? target[(t - 1) * B + b] : prev_tok[b];
  float v = emb[(size_t)tok * H + k];
  x_buf[idx] = v > 0.f ? v : 0.f;
}

// ---------------- attention scores + softmax (one block per b) ----------------
__global__ __launch_bounds__(256)
void attn_scores(const float* __restrict__ x_buf, const float* __restrict__ h,
                 const float* __restrict__ WT, const float* __restrict__ attn_b,
                 float* __restrict__ attn_w) {
  int b = blockIdx.x;
  int lane = threadIdx.x & 63, wv = threadIdx.x >> 6;
  float acc = 0.f;
  for (int k = wv * 512; k < wv * 512 + 512; ++k) {
    float xv = (k < 1024) ? x_buf[b * H + k] : h[b * H + (k - 1024)];
    acc = fmaf(xv, WT[k * 64 + lane], acc);
  }
  __shared__ float red[4][64];
  red[wv][lane] = acc;
  __syncthreads();
  if (wv == 0) {
    float sc = red[0][lane] + red[1][lane] + red[2][lane] + red[3][lane] + attn_b[lane];
    float m = sc;
    for (int off = 32; off; off >>= 1) m = fmaxf(m, __shfl_xor(m, off));
    float e = expf(sc - m);
    float ssum = e;
    for (int off = 32; off; off >>= 1) ssum += __shfl_xor(ssum, off);
    attn_w[b * 64 + lane] = e / ssum;
  }
}

// attn_v[b][d] = sum_s attn_w[b][s] * enc_out[s][b][d]
__global__ void attn_values_k(const float* __restrict__ aw, const float* __restrict__ enc_out,
                              float* __restrict__ attn_v) {
  int idx = blockIdx.x * 256 + threadIdx.x;
  int b = idx >> 10, d = idx & 1023;
  float acc = 0.f;
#pragma unroll 8
  for (int s = 0; s < 64; ++s)
    acc = fmaf(aw[b * 64 + s], enc_out[((size_t)s * B + b) * H + d], acc);
  attn_v[idx] = acc;
}

// newin = relu(sum_sk parts + bias)
__global__ void comb_reduce(const float* __restrict__ parts, const float* __restrict__ bias,
                            float* __restrict__ newin) {
  int idx = blockIdx.x * 256 + threadIdx.x;
  int b = idx >> 10, n = idx & 1023;
  float v = bias[n];
#pragma unroll
  for (int sk = 0; sk < 4; ++sk) v += parts[((size_t)sk * 32 + b) * H + n];
  newin[idx] = fmaxf(v, 0.f);
}

// ---------------- loss (online logsumexp) + argmax, one block per b ----------------
__global__ __launch_bounds__(256)
void loss_argmax(const float* __restrict__ logits, const int* __restrict__ target,
                 float* __restrict__ loss_part, int* __restrict__ prev_tok, int t) {
  int b = blockIdx.x, tid = threadIdx.x;
  const float* row = logits + (size_t)b * V;
  float m = -INFINITY, ssum = 0.f, bestv = -INFINITY;
  int besti = 0x7fffffff;
  for (int v = tid; v < V; v += 256) {
    float x = row[v];
    if (x > m) { ssum = ssum * expf(m - x) + 1.f; m = x; }
    else ssum += expf(x - m);
    if (x > bestv) { bestv = x; besti = v; }
  }
  __shared__ float sm[256], ss[256], sbv[256];
  __shared__ int sbi[256];
  sm[tid] = m; ss[tid] = ssum; sbv[tid] = bestv; sbi[tid] = besti;
  __syncthreads();
  for (int off = 128; off; off >>= 1) {
    if (tid < off) {
      float m2 = sm[tid + off], s2 = ss[tid + off];
      float mn = fmaxf(sm[tid], m2);
      ss[tid] = ss[tid] * expf(sm[tid] - mn) + s2 * expf(m2 - mn);
      sm[tid] = mn;
      float bv2 = sbv[tid + off]; int bi2 = sbi[tid + off];
      if (bv2 > sbv[tid] || (bv2 == sbv[tid] && bi2 < sbi[tid])) { sbv[tid] = bv2; sbi[tid] = bi2; }
    }
    __syncthreads();
  }
  if (tid == 0) {
    int tgt = target[t * B + b];
    float lp = row[tgt] - (sm[0] + logf(ss[0]));
    loss_part[t * B + b] = -lp * (1.f / (float)B);
    prev_tok[b] = sbi[0];
  }
}

__global__ void loss_sum(const float* __restrict__ loss_part, float* __restrict__ out) {
  int tid = threadIdx.x;
  float a = 0.f;
  for (int i = tid; i < T * B; i += 256) a += loss_part[i];
  __shared__ float red[256];
  red[tid] = a;
  __syncthreads();
  for (int off = 128; off; off >>= 1) {
    if (tid < off) red[tid] += red[tid + off];
    __syncthreads();
  }
  if (tid == 0) out[0] = red[0];
}

// ---------------- host launch ----------------
extern "C" void kernel_launch(void* const* d_in, const int* in_sizes, int n_in,
                              void* d_out, int out_size, void* d_ws, size_t ws_size,
                              hipStream_t stream) {
  const int*   input   = (const int*)d_in[0];
  const int*   target  = (const int*)d_in[1];
  const int*   use_tf  = (const int*)d_in[2];
  const float* enc_emb = (const float*)d_in[3];
  const float* enc_Wih = (const float*)d_in[4];
  const float* enc_Whh = (const float*)d_in[5];
  const float* enc_b   = (const float*)d_in[6];
  const float* dec_emb = (const float*)d_in[7];
  const float* dec_Wih = (const float*)d_in[8];
  const float* dec_Whh = (const float*)d_in[9];
  const float* dec_b   = (const float*)d_in[10];
  const float* attn_W  = (const float*)d_in[11];
  const float* attn_b  = (const float*)d_in[12];
  const float* comb_W  = (const float*)d_in[13];
  const float* comb_b  = (const float*)d_in[14];
  const float* out_W   = (const float*)d_in[15];
  const float* out_b   = (const float*)d_in[16];

  char* ws = (char*)d_ws;
  size_t off = 0;
  auto alloc = [&](size_t elems) {
    float* p = (float*)(ws + off);
    off += ((elems * 4 + 255) & ~(size_t)255);
    return p;
  };
  float* encX    = alloc((size_t)S * B * G);   // 33.5 MB
  float* enc_out = alloc((size_t)S * B * H);   // 8.4 MB
  float* hbuf    = alloc((size_t)B * H);       // h then c contiguous (zeroed together)
  float* cbuf    = alloc((size_t)B * H);
  float* x_buf   = alloc((size_t)B * H);
  float* attnWT  = alloc((size_t)2 * H * S);
  float* attn_w  = alloc((size_t)B * S);
  float* attn_v  = alloc((size_t)B * H);
  float* newin   = alloc((size_t)B * H);
  float* parts_g = alloc((size_t)4 * B * G);
  float* parts_c = alloc((size_t)4 * B * H);
  float* logits  = alloc((size_t)B * V);
  float* loss_p  = alloc((size_t)T * B);
  int*   prevtok = (int*)alloc((size_t)B);
  (void)ws_size; (void)in_sizes; (void)n_in; (void)out_size;

  // init: h,c = 0 (contiguous)
  zero_kernel<<<(2 * B * H) / 256, 256, 0, stream>>>(hbuf, 2 * B * H);
  transpose_attn<<<(2 * H * S) / 256, 256, 0, stream>>>(attn_W, attnWT);
  // encoder input projections, batched
  gemm_encx<<<dim3(G / 128, (S * B) / 32), 256, 0, stream>>>(input, enc_emb, enc_Wih, encX);

  // -------- encoder --------
  for (int s = 0; s < S; ++s) {
    gemm32<false, 4, false><<<dim3(G / 128, 4), 256, 0, stream>>>(
        hbuf, nullptr, enc_Whh, H, nullptr, 0, nullptr, parts_g, G);
    lstm_update<<<(B * H) / 256, 256, 0, stream>>>(
        parts_g, encX + (size_t)s * B * G, enc_b, hbuf, cbuf, enc_out + (size_t)s * B * H);
  }

  // -------- decoder --------
  for (int t = 0; t < T; ++t) {
    dec_gather_x<<<(B * H) / 256, 256, 0, stream>>>(use_tf, target, prevtok, dec_emb, x_buf, t);
    attn_scores<<<B, 256, 0, stream>>>(x_buf, hbuf, attnWT, attn_b, attn_w);
    attn_values_k<<<(B * H) / 256, 256, 0, stream>>>(attn_w, enc_out, attn_v);
    gemm32<true, 4, false><<<dim3(H / 128, 4), 256, 0, stream>>>(
        x_buf, attn_v, comb_W, 2 * H, comb_W + H, 2 * H, nullptr, parts_c, H);
    comb_reduce<<<(B * H) / 256, 256, 0, stream>>>(parts_c, comb_b, newin);
    gemm32<true, 4, false><<<dim3(G / 128, 4), 256, 0, stream>>>(
        newin, hbuf, dec_Wih, H, dec_Whh, H, nullptr, parts_g, G);
    lstm_update<<<(B * H) / 256, 256, 0, stream>>>(
        parts_g, nullptr, dec_b, hbuf, cbuf, nullptr);
    gemm32<false, 1, true><<<dim3(V / 128, 1), 256, 0, stream>>>(
        hbuf, nullptr, out_W, H, nullptr, 0, out_b, logits, V);
    loss_argmax<<<B, 256, 0, stream>>>(logits, target, loss_p, prevtok, t);
  }
  loss_sum<<<1, 256, 0, stream>>>(loss_p, (float*)d_out);
}

// Round 2
// 16091.756 us; speedup vs baseline: 1.1066x; 1.1066x over previous
//
#include <hip/hip_runtime.h>
#include <hip/hip_bf16.h>
#include <cmath>
#include <cstddef>

// S=T=64, B=32, H=1024, G=4H, V=32000
constexpr int S = 64, T = 64, B = 32, H = 1024, G = 4096, V = 32000;

typedef __hip_bfloat16 bf16;
typedef __attribute__((ext_vector_type(8))) short bf16x8;
typedef __attribute__((ext_vector_type(4))) float f32x4;

__device__ __forceinline__ float sigf(float x) { return 1.f / (1.f + expf(-x)); }
__device__ __forceinline__ float b2f(unsigned short u) {
  return __uint_as_float(((unsigned)u) << 16);
}
__device__ __forceinline__ f32x4 mfma16(bf16x8 a, bf16x8 b, f32x4 c) {
  return __builtin_amdgcn_mfma_f32_16x16x32_bf16(a, b, c, 0, 0, 0);
}

// ---------------- conversion / init kernels ----------------
__global__ void zero_hc(float* __restrict__ c, bf16* __restrict__ hb) {
  int i = blockIdx.x * 256 + threadIdx.x;   // 32768
  c[i] = 0.f;
  hb[i] = __float2bfloat16(0.f);
}

__global__ void cvt_bf16(const float* __restrict__ s, bf16* __restrict__ d, int n4) {
  int i = blockIdx.x * 256 + threadIdx.x;
  if (i >= n4) return;
  float4 v = *reinterpret_cast<const float4*>(s + (size_t)i * 4);
  bf16* dst = d + (size_t)i * 4;
  dst[0] = __float2bfloat16(v.x); dst[1] = __float2bfloat16(v.y);
  dst[2] = __float2bfloat16(v.z); dst[3] = __float2bfloat16(v.w);
}

// fused [dec_Wih | dec_Whh] -> [4096][2048] bf16
__global__ void cvt_gatesW(const float* __restrict__ Wih, const float* __restrict__ Whh,
                           bf16* __restrict__ d) {
  int i = blockIdx.x * 256 + threadIdx.x;   // 4096*512
  int n = i >> 9, k4 = (i & 511) * 4;
  const float* src = (k4 < 1024) ? (Wih + (size_t)n * 1024 + k4)
                                 : (Whh + (size_t)n * 1024 + (k4 - 1024));
  float4 v = *reinterpret_cast<const float4*>(src);
  bf16* dst = d + (size_t)n * 2048 + k4;
  dst[0] = __float2bfloat16(v.x); dst[1] = __float2bfloat16(v.y);
  dst[2] = __float2bfloat16(v.z); dst[3] = __float2bfloat16(v.w);
}

// encoder embedding gather -> bf16 X [2048][1024]
__global__ void gather_emb(const int* __restrict__ tok, const float* __restrict__ emb,
                           bf16* __restrict__ X) {
  int i = blockIdx.x * 256 + threadIdx.x;   // 2048*256
  int m = i >> 8, k4 = (i & 255) * 4;
  float4 v = *reinterpret_cast<const float4*>(emb + (size_t)tok[m] * H + k4);
  bf16* dst = X + (size_t)m * H + k4;
  dst[0] = __float2bfloat16(v.x); dst[1] = __float2bfloat16(v.y);
  dst[2] = __float2bfloat16(v.z); dst[3] = __float2bfloat16(v.w);
}

// ---------------- MFMA GEMM: C[32][N] = [A0|A1][32][KTOT] @ W[N][KTOT]^T ----------------
// A rows stride 1024 (each half). W row-major, ld = KTOT.
// EPI 0: f32 store; 1: f32 store + bias; 2: bf16 store of relu(x + bias)
template <int KTOT, int EPI>
__global__ __launch_bounds__(256) void gemm_mfma(
    const bf16* __restrict__ A0, const bf16* __restrict__ A1,
    const bf16* __restrict__ W, const float* __restrict__ bias,
    void* __restrict__ outp, int N) {
  const int tid = threadIdx.x;
  const int wave = tid >> 6, lane = tid & 63;
  const int nbase = blockIdx.x * 256 + wave * 64;
  const int mbase = blockIdx.y * 32;          // only encX uses gridDim.y>1
  const int r = lane & 15, kg = (lane >> 4) * 8;
  f32x4 acc[2][4] = {};
  const bf16* Wb0 = W + (size_t)(nbase + r) * KTOT + kg;
#pragma unroll 2
  for (int k0 = 0; k0 < KTOT; k0 += 32) {
    const bf16* Ab;
    if (KTOT == 2048 && k0 >= 1024)
      Ab = A1 + (size_t)r * 1024 + (k0 - 1024) + kg;
    else
      Ab = A0 + (size_t)(mbase + r) * 1024 + k0 + kg;
    bf16x8 a0 = *reinterpret_cast<const bf16x8*>(Ab);
    bf16x8 a1 = *reinterpret_cast<const bf16x8*>(Ab + 16 * 1024);
    const bf16* Wb = Wb0 + k0;
    bf16x8 b0 = *reinterpret_cast<const bf16x8*>(Wb);
    bf16x8 b1 = *reinterpret_cast<const bf16x8*>(Wb + (size_t)16 * KTOT);
    bf16x8 b2 = *reinterpret_cast<const bf16x8*>(Wb + (size_t)32 * KTOT);
    bf16x8 b3 = *reinterpret_cast<const bf16x8*>(Wb + (size_t)48 * KTOT);
    acc[0][0] = mfma16(a0, b0, acc[0][0]);
    acc[1][0] = mfma16(a1, b0, acc[1][0]);
    acc[0][1] = mfma16(a0, b1, acc[0][1]);
    acc[1][1] = mfma16(a1, b1, acc[1][1]);
    acc[0][2] = mfma16(a0, b2, acc[0][2]);
    acc[1][2] = mfma16(a1, b2, acc[1][2]);
    acc[0][3] = mfma16(a0, b3, acc[0][3]);
    acc[1][3] = mfma16(a1, b3, acc[1][3]);
  }
  // C/D layout (m89-verified): col = lane&15, row = (lane>>4)*4 + reg
#pragma unroll
  for (int mi = 0; mi < 2; ++mi) {
#pragma unroll
    for (int nj = 0; nj < 4; ++nj) {
      int col = nbase + nj * 16 + (lane & 15);
      int row0 = mbase + mi * 16 + ((lane >> 4) << 2);
#pragma unroll
      for (int reg = 0; reg < 4; ++reg) {
        float v = acc[mi][nj][reg];
        if (EPI == 2) {
          v = fmaxf(v + bias[col], 0.f);
          ((bf16*)outp)[(size_t)(row0 + reg) * N + col] = __float2bfloat16(v);
        } else {
          if (EPI == 1) v += bias[col];
          ((float*)outp)[(size_t)(row0 + reg) * N + col] = v;
        }
      }
    }
  }
}

// ---------------- fused decoder: embed+relu -> xb, scores MFMA, softmax ----------------
__global__ __launch_bounds__(256) void attn_fused(
    const int* __restrict__ use_tf, const int* __restrict__ target,
    const int* __restrict__ prevtok, const float* __restrict__ emb,
    bf16* __restrict__ xb, const bf16* __restrict__ hb,
    const bf16* __restrict__ attnW, const float* __restrict__ attn_b,
    float* __restrict__ attn_w, int t) {
  __shared__ float red[4][32][64];
  const int tid = threadIdx.x;
  // phase 1: x = relu(dec_emb[tok]) -> xb (bf16)
  const int utf = use_tf[0];
  for (int i = tid; i < B * 256; i += 256) {
    int b = i >> 8, k4 = (i & 255) * 4;
    int tok = 0;
    if (t > 0) tok = utf ? target[(t - 1) * B + b] : prevtok[b];
    float4 v = *reinterpret_cast<const float4*>(emb + (size_t)tok * H + k4);
    bf16* dst = xb + (size_t)b * H + k4;
    dst[0] = __float2bfloat16(fmaxf(v.x, 0.f));
    dst[1] = __float2bfloat16(fmaxf(v.y, 0.f));
    dst[2] = __float2bfloat16(fmaxf(v.z, 0.f));
    dst[3] = __float2bfloat16(fmaxf(v.w, 0.f));
  }
  __threadfence_block();
  __syncthreads();
  // phase 2: scores[32][64] = [x|h] @ attnW^T ; split-K across 4 waves
  const int wave = tid >> 6, lane = tid & 63;
  const int r = lane & 15, kg = (lane >> 4) * 8;
  f32x4 acc[2][4] = {};
  const bf16* Abase = (wave < 2) ? xb : hb;
  const int kb = (wave & 1) * 512;
  const int kwoff = (wave >> 1) * 1024;
  for (int k0 = kb; k0 < kb + 512; k0 += 32) {
    const bf16* Ab = Abase + (size_t)r * H + k0 + kg;
    bf16x8 a0 = *reinterpret_cast<const bf16x8*>(Ab);
    bf16x8 a1 = *reinterpret_cast<const bf16x8*>(Ab + 16 * H);
    const bf16* Wb = attnW + (size_t)r * 2048 + kwoff + k0 + kg;
    bf16x8 b0 = *reinterpret_cast<const bf16x8*>(Wb);
    bf16x8 b1 = *reinterpret_cast<const bf16x8*>(Wb + 16 * 2048);
    bf16x8 b2 = *reinterpret_cast<const bf16x8*>(Wb + 32 * 2048);
    bf16x8 b3 = *reinterpret_cast<const bf16x8*>(Wb + 48 * 2048);
    acc[0][0] = mfma16(a0, b0, acc[0][0]);
    acc[1][0] = mfma16(a1, b0, acc[1][0]);
    acc[0][1] = mfma16(a0, b1, acc[0][1]);
    acc[1][1] = mfma16(a1, b1, acc[1][1]);
    acc[0][2] = mfma16(a0, b2, acc[0][2]);
    acc[1][2] = mfma16(a1, b2, acc[1][2]);
    acc[0][3] = mfma16(a0, b3, acc[0][3]);
    acc[1][3] = mfma16(a1, b3, acc[1][3]);
  }
  {
    int prow = (lane >> 4) * 4, pcol = lane & 15;
#pragma unroll
    for (int mi = 0; mi < 2; ++mi)
#pragma unroll
      for (int nj = 0; nj < 4; ++nj)
#pragma unroll
        for (int reg = 0; reg < 4; ++reg)
          red[wave][mi * 16 + prow + reg][nj * 16 + pcol] = acc[mi][nj][reg];
  }
  __syncthreads();
  // phase 3: softmax per row (32 rows x 8 threads, 8 cols each)
  {
    int row = tid >> 3, c8 = (tid & 7) * 8;
    float e[8];
    float m = -1e30f;
#pragma unroll
    for (int j = 0; j < 8; ++j) {
      int col = c8 + j;
      float s = red[0][row][col] + red[1][row][col] + red[2][row][col] +
                red[3][row][col] + attn_b[col];
      e[j] = s;
      m = fmaxf(m, s);
    }
    for (int off = 1; off < 8; off <<= 1) m = fmaxf(m, __shfl_xor(m, off));
    float sum = 0.f;
#pragma unroll
    for (int j = 0; j < 8; ++j) { e[j] = expf(e[j] - m); sum += e[j]; }
    for (int off = 1; off < 8; off <<= 1) sum += __shfl_xor(sum, off);
    float inv = 1.f / sum;
#pragma unroll
    for (int j = 0; j < 8; ++j) attn_w[row * 64 + c8 + j] = e[j] * inv;
  }
}

// attn_v[b][d] = sum_s aw[b][s] * enc_bs[b][d][s]  (enc_bs contiguous in s)
__global__ void attn_values_k(const float* __restrict__ aw, const bf16* __restrict__ enc_bs,
                              bf16* __restrict__ vb) {
  __shared__ float w[64];
  int idx = blockIdx.x * 256 + threadIdx.x;
  int b = idx >> 10;
  if (threadIdx.x < 64) w[threadIdx.x] = aw[b * 64 + threadIdx.x];
  __syncthreads();
  const bf16* row = enc_bs + (size_t)idx * 64;
  float acc = 0.f;
#pragma unroll
  for (int j = 0; j < 8; ++j) {
    bf16x8 v = *reinterpret_cast<const bf16x8*>(row + j * 8);
#pragma unroll
    for (int e = 0; e < 8; ++e)
      acc = fmaf(w[j * 8 + e], b2f((unsigned short)v[e]), acc);
  }
  vb[idx] = __float2bfloat16(acc);
}

// ---------------- LSTM pointwise ----------------
__global__ void lstm_update(const float* __restrict__ gates, const float* __restrict__ baseX,
                            const float* __restrict__ bias, bf16* __restrict__ hb,
                            float* __restrict__ c, bf16* __restrict__ enc_bs, int s) {
  int idx = blockIdx.x * 256 + threadIdx.x;   // B*H
  int b = idx >> 10, hh = idx & 1023;
  float g4[4];
#pragma unroll
  for (int q = 0; q < 4; ++q) {
    int n = q * H + hh;
    float v = bias[n] + gates[(size_t)b * G + n];
    if (baseX) v += baseX[(size_t)b * G + n];
    g4[q] = v;
  }
  float ig = sigf(g4[0]), fg = sigf(g4[1]), gg = tanhf(g4[2]), og = sigf(g4[3]);
  float cn = fg * c[idx] + ig * gg;
  float hn = og * tanhf(cn);
  c[idx] = cn;
  hb[idx] = __float2bfloat16(hn);
  if (enc_bs) enc_bs[(size_t)idx * 64 + s] = __float2bfloat16(hn);
}

// ---------------- loss (online logsumexp) + argmax ----------------
__global__ __launch_bounds__(256)
void loss_argmax(const float* __restrict__ logits, const int* __restrict__ target,
                 float* __restrict__ loss_part, int* __restrict__ prev_tok, int t) {
  int b = blockIdx.x, tid = threadIdx.x;
  const float* row = logits + (size_t)b * V;
  float m = -INFINITY, ssum = 0.f, bestv = -INFINITY;
  int besti = 0x7fffffff;
  for (int v = tid; v < V; v += 256) {
    float x = row[v];
    if (x > m) { ssum = ssum * expf(m - x) + 1.f; m = x; }
    else ssum += expf(x - m);
    if (x > bestv) { bestv = x; besti = v; }
  }
  __shared__ float sm[256], ss[256], sbv[256];
  __shared__ int sbi[256];
  sm[tid] = m; ss[tid] = ssum; sbv[tid] = bestv; sbi[tid] = besti;
  __syncthreads();
  for (int off = 128; off; off >>= 1) {
    if (tid < off) {
      float m2 = sm[tid + off], s2 = ss[tid + off];
      float mn = fmaxf(sm[tid], m2);
      ss[tid] = ss[tid] * expf(sm[tid] - mn) + s2 * expf(m2 - mn);
      sm[tid] = mn;
      float bv2 = sbv[tid + off]; int bi2 = sbi[tid + off];
      if (bv2 > sbv[tid] || (bv2 == sbv[tid] && bi2 < sbi[tid])) { sbv[tid] = bv2; sbi[tid] = bi2; }
    }
    __syncthreads();
  }
  if (tid == 0) {
    int tgt = target[t * B + b];
    float lp = row[tgt] - (sm[0] + logf(ss[0]));
    loss_part[t * B + b] = -lp * (1.f / (float)B);
    prev_tok[b] = sbi[0];
  }
}

__global__ void loss_sum(const float* __restrict__ loss_part, float* __restrict__ out) {
  int tid = threadIdx.x;
  float a = 0.f;
  for (int i = tid; i < T * B; i += 256) a += loss_part[i];
  __shared__ float red[256];
  red[tid] = a;
  __syncthreads();
  for (int off = 128; off; off >>= 1) {
    if (tid < off) red[tid] += red[tid + off];
    __syncthreads();
  }
  if (tid == 0) out[0] = red[0];
}

// ---------------- host launch ----------------
extern "C" void kernel_launch(void* const* d_in, const int* in_sizes, int n_in,
                              void* d_out, int out_size, void* d_ws, size_t ws_size,
                              hipStream_t stream) {
  const int*   input   = (const int*)d_in[0];
  const int*   target  = (const int*)d_in[1];
  const int*   use_tf  = (const int*)d_in[2];
  const float* enc_emb = (const float*)d_in[3];
  const float* enc_Wih = (const float*)d_in[4];
  const float* enc_Whh = (const float*)d_in[5];
  const float* enc_b   = (const float*)d_in[6];
  const float* dec_emb = (const float*)d_in[7];
  const float* dec_Wih = (const float*)d_in[8];
  const float* dec_Whh = (const float*)d_in[9];
  const float* dec_b   = (const float*)d_in[10];
  const float* attn_W  = (const float*)d_in[11];
  const float* attn_b  = (const float*)d_in[12];
  const float* comb_W  = (const float*)d_in[13];
  const float* comb_b  = (const float*)d_in[14];
  const float* out_W   = (const float*)d_in[15];
  const float* out_b   = (const float*)d_in[16];
  (void)in_sizes; (void)n_in; (void)out_size; (void)ws_size;

  char* ws = (char*)d_ws;
  size_t off = 0;
  auto alloc = [&](size_t bytes) {
    void* p = ws + off;
    off += ((bytes + 255) & ~(size_t)255);
    return p;
  };
  float* encX    = (float*)alloc((size_t)S * B * G * 4);      // 33.5 MB
  float* gates   = (float*)alloc((size_t)B * G * 4);
  float* cbuf    = (float*)alloc((size_t)B * H * 4);
  float* logits  = (float*)alloc((size_t)B * V * 4);
  float* attn_w  = (float*)alloc((size_t)B * S * 4);
  float* loss_p  = (float*)alloc((size_t)T * B * 4);
  int*   prevtok = (int*)alloc(B * 4);
  bf16*  hb      = (bf16*)alloc((size_t)B * H * 2);
  bf16*  xb      = (bf16*)alloc((size_t)B * H * 2);
  bf16*  vb      = (bf16*)alloc((size_t)B * H * 2);
  bf16*  nb      = (bf16*)alloc((size_t)B * H * 2);
  bf16*  Xbf     = (bf16*)alloc((size_t)S * B * H * 2);       // 4.2 MB
  bf16*  enc_bs  = (bf16*)alloc((size_t)B * H * S * 2);       // 4.2 MB  [b][d][s]
  bf16*  encWih_bf = (bf16*)alloc((size_t)G * H * 2);         // 8.4 MB
  bf16*  encWhh_bf = (bf16*)alloc((size_t)G * H * 2);
  bf16*  decGW_bf  = (bf16*)alloc((size_t)G * 2 * H * 2);     // 16.8 MB
  bf16*  combW_bf  = (bf16*)alloc((size_t)H * 2 * H * 2);     // 4.2 MB
  bf16*  attnW_bf  = (bf16*)alloc((size_t)S * 2 * H * 2);
  bf16*  outW_bf   = (bf16*)alloc((size_t)V * H * 2);         // 65.5 MB

  // ---- one-time prep ----
  zero_hc<<<(B * H) / 256, 256, 0, stream>>>(cbuf, hb);
  cvt_bf16<<<(G * H / 4) / 256, 256, 0, stream>>>(enc_Wih, encWih_bf, G * H / 4);
  cvt_bf16<<<(G * H / 4) / 256, 256, 0, stream>>>(enc_Whh, encWhh_bf, G * H / 4);
  cvt_bf16<<<(2 * H * H / 4) / 256, 256, 0, stream>>>(comb_W, combW_bf, 2 * H * H / 4);
  cvt_bf16<<<(S * 2 * H / 4) / 256, 256, 0, stream>>>(attn_W, attnW_bf, S * 2 * H / 4);
  cvt_bf16<<<(V * H / 4) / 256, 256, 0, stream>>>(out_W, outW_bf, V * H / 4);
  cvt_gatesW<<<(G * 512) / 256, 256, 0, stream>>>(dec_Wih, dec_Whh, decGW_bf);
  gather_emb<<<(S * B * 256) / 256, 256, 0, stream>>>(input, enc_emb, Xbf);
  // encX[2048][4096] = Xbf @ enc_Wih^T  (grid: 16 N-chunks x 64 M-chunks)
  gemm_mfma<1024, 0><<<dim3(G / 256, (S * B) / 32), 256, 0, stream>>>(
      Xbf, nullptr, encWih_bf, nullptr, encX, G);

  // ---- encoder ----
  for (int s = 0; s < S; ++s) {
    gemm_mfma<1024, 0><<<dim3(G / 256, 1), 256, 0, stream>>>(
        hb, nullptr, encWhh_bf, nullptr, gates, G);
    lstm_update<<<(B * H) / 256, 256, 0, stream>>>(
        gates, encX + (size_t)s * B * G, enc_b, hb, cbuf, enc_bs, s);
  }

  // ---- decoder ----
  for (int t = 0; t < T; ++t) {
    attn_fused<<<1, 256, 0, stream>>>(use_tf, target, prevtok, dec_emb,
                                      xb, hb, attnW_bf, attn_b, attn_w, t);
    attn_values_k<<<(B * H) / 256, 256, 0, stream>>>(attn_w, enc_bs, vb);
    gemm_mfma<2048, 2><<<dim3(H / 256, 1), 256, 0, stream>>>(
        xb, vb, combW_bf, comb_b, nb, H);
    gemm_mfma<2048, 0><<<dim3(G / 256, 1), 256, 0, stream>>>(
        nb, hb, decGW_bf, nullptr, gates, G);
    lstm_update<<<(B * H) / 256, 256, 0, stream>>>(
        gates, nullptr, dec_b, hb, cbuf, nullptr, 0);
    gemm_mfma<1024, 1><<<dim3(V / 256, 1), 256, 0, stream>>>(
        hb, nullptr, outW_bf, out_b, logits, V);
    loss_argmax<<<B, 256, 0, stream>>>(logits, target, loss_p, prevtok, t);
  }
  loss_sum<<<1, 256, 0, stream>>>(loss_p, (float*)d_out);
}

// Round 4
// 8487.891 us; speedup vs baseline: 2.0979x; 1.8958x over previous
//
#include <hip/hip_runtime.h>
#include <cmath>
#include <cstddef>

// S=T=64, B=32, H=1024, G=4H, V=32000
constexpr int S_ = 64, T_ = 64, B_ = 32, H_ = 1024, G_ = 4096, V_ = 32000;
constexpr int NB = 256, NTHR = NB * 256, NWAVE = NB * 4;

typedef unsigned short u16;   // bf16 bit pattern
typedef __attribute__((ext_vector_type(8))) short bf16x8;
typedef __attribute__((ext_vector_type(4))) float f32x4;

__device__ __forceinline__ float sigf(float x) { return 1.f / (1.f + expf(-x)); }
__device__ __forceinline__ float b2f(u16 u) { return __uint_as_float(((unsigned)u) << 16); }
__device__ __forceinline__ u16 f2b(float f) {
  unsigned u = __float_as_uint(f);
  return (u16)((u + 0x7fff + ((u >> 16) & 1)) >> 16);  // RNE
}
__device__ __forceinline__ f32x4 mfma16(bf16x8 a, bf16x8 b, f32x4 c) {
  return __builtin_amdgcn_mfma_f32_16x16x32_bf16(a, b, c, 0, 0, 0);
}

struct Params {
  const int *input, *target, *use_tf;
  const float *enc_emb, *enc_Wih, *enc_Whh, *enc_b;
  const float *dec_emb, *dec_Wih, *dec_Whh, *dec_b;
  const float *attn_W, *attn_b, *comb_W, *comb_b, *out_W, *out_b;
  float* out;
  u16 *Xbf, *encXbf, *enc_bs, *hall, *hbuf, *xb, *vb, *nbuf;
  float *gatesH, *cbuf, *loss_p;
  int* prevtok;
  u16 *wencWih, *wencWhh, *wdecG, *wcomb, *wattn, *wout;
  unsigned* bar;   // [16 group counters spaced 16u] + [256]=root + [272]=gen
};

// ---------- two-level device-scope grid barrier ----------
__device__ __forceinline__ void gbar(unsigned* bar, unsigned target) {
  __syncthreads();
  if (threadIdx.x == 0) {
    __threadfence();
    int g = blockIdx.x >> 4;
    unsigned a = __hip_atomic_fetch_add(bar + g * 16, 1u, __ATOMIC_ACQ_REL,
                                        __HIP_MEMORY_SCOPE_AGENT);
    if (a == 15u) {
      unsigned r = __hip_atomic_fetch_add(bar + 256, 1u, __ATOMIC_ACQ_REL,
                                          __HIP_MEMORY_SCOPE_AGENT);
      if (r == 15u) {
        for (int i = 0; i < 16; ++i)
          __hip_atomic_store(bar + i * 16, 0u, __ATOMIC_RELAXED, __HIP_MEMORY_SCOPE_AGENT);
        __hip_atomic_store(bar + 256, 0u, __ATOMIC_RELAXED, __HIP_MEMORY_SCOPE_AGENT);
        __hip_atomic_store(bar + 272, target, __ATOMIC_RELEASE, __HIP_MEMORY_SCOPE_AGENT);
      }
    }
    while (__hip_atomic_load(bar + 272, __ATOMIC_ACQUIRE, __HIP_MEMORY_SCOPE_AGENT) < target)
      __builtin_amdgcn_s_sleep(2);
  }
  __syncthreads();
}

// ---------- per-wave 32x64 tile GEMM, K=1024, bf16 out (+opt bias) ----------
template <bool BIAS>
__device__ void wave_gemm_bf16(const u16* __restrict__ A, const u16* __restrict__ W,
                               int colbase, const float* __restrict__ bias,
                               u16* __restrict__ out, int ldo) {
  const int lane = threadIdx.x & 63;
  const int r = lane & 15, kg = (lane >> 4) * 8;
  const u16* Ar = A + (size_t)r * 1024 + kg;
  const u16* Wr = W + (size_t)(colbase + r) * 1024 + kg;
  f32x4 acc[2][4] = {};
#pragma unroll 2
  for (int k0 = 0; k0 < 1024; k0 += 32) {
    bf16x8 a0 = *(const bf16x8*)(Ar + k0);
    bf16x8 a1 = *(const bf16x8*)(Ar + 16 * 1024 + k0);
    bf16x8 b0 = *(const bf16x8*)(Wr + k0);
    bf16x8 b1 = *(const bf16x8*)(Wr + 16 * 1024 + k0);
    bf16x8 b2 = *(const bf16x8*)(Wr + 32 * 1024 + k0);
    bf16x8 b3 = *(const bf16x8*)(Wr + 48 * 1024 + k0);
    acc[0][0] = mfma16(a0, b0, acc[0][0]);
    acc[1][0] = mfma16(a1, b0, acc[1][0]);
    acc[0][1] = mfma16(a0, b1, acc[0][1]);
    acc[1][1] = mfma16(a1, b1, acc[1][1]);
    acc[0][2] = mfma16(a0, b2, acc[0][2]);
    acc[1][2] = mfma16(a1, b2, acc[1][2]);
    acc[0][3] = mfma16(a0, b3, acc[0][3]);
    acc[1][3] = mfma16(a1, b3, acc[1][3]);
  }
#pragma unroll
  for (int mi = 0; mi < 2; ++mi)
#pragma unroll
    for (int nj = 0; nj < 4; ++nj) {
      int col = colbase + nj * 16 + (lane & 15);
      int row0 = mi * 16 + ((lane >> 4) << 2);
#pragma unroll
      for (int reg = 0; reg < 4; ++reg) {
        float v = acc[mi][nj][reg];
        if (BIAS) v += bias[col];
        out[(size_t)(row0 + reg) * ldo + col] = f2b(v);
      }
    }
}

// ---------- block 32x64 grouped-col GEMM, K=1024 split over 4 waves -> sg[32][64] ----------
// gate col of frag q = q*1024 + grp*16 + f;   sg[b][q*16+f]
__device__ void grouped_gemm(const u16* __restrict__ A, const u16* __restrict__ Wm,
                             int ldw, int wkoff, int grp, float* red, float* sg) {
  const int tid = threadIdx.x, w = tid >> 6, lane = tid & 63;
  const int r = lane & 15, kg = (lane >> 4) * 8;
  const int kw0 = w * 256;
  const u16* Ar = A + (size_t)r * 1024 + kw0 + kg;
  const u16* W0 = Wm + (size_t)(grp * 16 + r) * ldw + wkoff + kw0 + kg;
  const u16* W1 = W0 + (size_t)1024 * ldw;
  const u16* W2 = W0 + (size_t)2048 * ldw;
  const u16* W3 = W0 + (size_t)3072 * ldw;
  f32x4 acc[2][4] = {};
#pragma unroll
  for (int k0 = 0; k0 < 256; k0 += 32) {
    bf16x8 a0 = *(const bf16x8*)(Ar + k0);
    bf16x8 a1 = *(const bf16x8*)(Ar + 16 * 1024 + k0);
    bf16x8 b0 = *(const bf16x8*)(W0 + k0);
    bf16x8 b1 = *(const bf16x8*)(W1 + k0);
    bf16x8 b2 = *(const bf16x8*)(W2 + k0);
    bf16x8 b3 = *(const bf16x8*)(W3 + k0);
    acc[0][0] = mfma16(a0, b0, acc[0][0]);
    acc[1][0] = mfma16(a1, b0, acc[1][0]);
    acc[0][1] = mfma16(a0, b1, acc[0][1]);
    acc[1][1] = mfma16(a1, b1, acc[1][1]);
    acc[0][2] = mfma16(a0, b2, acc[0][2]);
    acc[1][2] = mfma16(a1, b2, acc[1][2]);
    acc[0][3] = mfma16(a0, b3, acc[0][3]);
    acc[1][3] = mfma16(a1, b3, acc[1][3]);
  }
#pragma unroll
  for (int mi = 0; mi < 2; ++mi)
#pragma unroll
    for (int nj = 0; nj < 4; ++nj)
#pragma unroll
      for (int reg = 0; reg < 4; ++reg)
        red[(((w * 8) + mi * 4 + nj) * 64 + lane) * 4 + reg] = acc[mi][nj][reg];
  __syncthreads();
#pragma unroll
  for (int pp = 0; pp < 2; ++pp) {
    int p2 = w * 2 + pp, mi = p2 >> 2, nj = p2 & 3;
#pragma unroll
    for (int reg = 0; reg < 4; ++reg) {
      float v = red[((0 + p2) * 64 + lane) * 4 + reg] +
                red[((8 + p2) * 64 + lane) * 4 + reg] +
                red[((16 + p2) * 64 + lane) * 4 + reg] +
                red[((24 + p2) * 64 + lane) * 4 + reg];
      sg[(mi * 16 + ((lane >> 4) << 2) + reg) * 64 + nj * 16 + (lane & 15)] = v;
    }
  }
  __syncthreads();
}

// ---------- comb: 32x64 contiguous-col tile, K=2048 over [xb|vb], relu+bias -> nbuf ----------
__device__ void comb_block(const Params& p, int cb, float* red) {
  const int tid = threadIdx.x, w = tid >> 6, lane = tid & 63;
  const int r = lane & 15, kg = (lane >> 4) * 8;
  const int kw0 = w * 512;
  const u16* Abase = p.xb;
  int koff = kw0;
  if (kw0 >= 1024) { Abase = p.vb; koff = kw0 - 1024; }
  const u16* Ar = Abase + (size_t)r * 1024 + koff + kg;
  const u16* Wr = p.wcomb + (size_t)(cb * 64 + r) * 2048 + kw0 + kg;
  f32x4 acc[2][4] = {};
#pragma unroll 2
  for (int k0 = 0; k0 < 512; k0 += 32) {
    bf16x8 a0 = *(const bf16x8*)(Ar + k0);
    bf16x8 a1 = *(const bf16x8*)(Ar + 16 * 1024 + k0);
    bf16x8 b0 = *(const bf16x8*)(Wr + k0);
    bf16x8 b1 = *(const bf16x8*)(Wr + 16 * 2048 + k0);
    bf16x8 b2 = *(const bf16x8*)(Wr + 32 * 2048 + k0);
    bf16x8 b3 = *(const bf16x8*)(Wr + 48 * 2048 + k0);
    acc[0][0] = mfma16(a0, b0, acc[0][0]);
    acc[1][0] = mfma16(a1, b0, acc[1][0]);
    acc[0][1] = mfma16(a0, b1, acc[0][1]);
    acc[1][1] = mfma16(a1, b1, acc[1][1]);
    acc[0][2] = mfma16(a0, b2, acc[0][2]);
    acc[1][2] = mfma16(a1, b2, acc[1][2]);
    acc[0][3] = mfma16(a0, b3, acc[0][3]);
    acc[1][3] = mfma16(a1, b3, acc[1][3]);
  }
#pragma unroll
  for (int mi = 0; mi < 2; ++mi)
#pragma unroll
    for (int nj = 0; nj < 4; ++nj)
#pragma unroll
      for (int reg = 0; reg < 4; ++reg)
        red[(((w * 8) + mi * 4 + nj) * 64 + lane) * 4 + reg] = acc[mi][nj][reg];
  __syncthreads();
#pragma unroll
  for (int pp = 0; pp < 2; ++pp) {
    int p2 = w * 2 + pp, mi = p2 >> 2, nj = p2 & 3;
    int col = cb * 64 + nj * 16 + (lane & 15);
    int row0 = mi * 16 + ((lane >> 4) << 2);
#pragma unroll
    for (int reg = 0; reg < 4; ++reg) {
      float v = red[((0 + p2) * 64 + lane) * 4 + reg] +
                red[((8 + p2) * 64 + lane) * 4 + reg] +
                red[((16 + p2) * 64 + lane) * 4 + reg] +
                red[((24 + p2) * 64 + lane) * 4 + reg];
      v = fmaxf(v + p.comb_b[col], 0.f);
      p.nbuf[(size_t)(row0 + reg) * 1024 + col] = f2b(v);
    }
  }
  __syncthreads();
}

// ---------- log-softmax loss over one bf16 logits row ----------
template <bool AM>
__device__ void loss_row_bf16(const u16* __restrict__ row, int tgt,
                              float* __restrict__ loss_out, int* __restrict__ am_out,
                              float* sh) {
  float* sm = sh;
  float* ss = sh + 256;
  float* sbv = sh + 512;
  int* sbi = (int*)(sh + 768);
  const int tid = threadIdx.x;
  float m = -INFINITY, ssum = 0.f, bestv = -INFINITY;
  int besti = 0x7fffffff;
  for (int v = tid; v < V_; v += 256) {
    float x = b2f(row[v]);
    if (x > m) { ssum = ssum * expf(m - x) + 1.f; m = x; }
    else ssum += expf(x - m);
    if (AM) { if (x > bestv) { bestv = x; besti = v; } }
  }
  sm[tid] = m; ss[tid] = ssum;
  if (AM) { sbv[tid] = bestv; sbi[tid] = besti; }
  __syncthreads();
  for (int off = 128; off; off >>= 1) {
    if (tid < off) {
      float m2 = sm[tid + off], s2 = ss[tid + off];
      float mn = fmaxf(sm[tid], m2);
      ss[tid] = ss[tid] * expf(sm[tid] - mn) + s2 * expf(m2 - mn);
      sm[tid] = mn;
      if (AM) {
        float bv2 = sbv[tid + off];
        int bi2 = sbi[tid + off];
        if (bv2 > sbv[tid] || (bv2 == sbv[tid] && bi2 < sbi[tid])) { sbv[tid] = bv2; sbi[tid] = bi2; }
      }
    }
    __syncthreads();
  }
  if (tid == 0) {
    float lp = b2f(row[tgt]) - (sm[0] + logf(ss[0]));
    *loss_out = -lp * (1.f / 32.f);
    if (AM) *am_out = sbi[0];
  }
  __syncthreads();
}

// =================== main persistent kernel ===================
__global__ void binit(unsigned* bar) {
  int i = threadIdx.x;
  if (i < 288) bar[i] = 0u;
}

__global__ __launch_bounds__(256) void seq2seq_all(Params p) {
  __shared__ float red_s[8192];   // 32 KB (also reused: attn smem, loss smem)
  __shared__ float sg_s[2048];    // 8 KB reduced gate tile
  unsigned bargen = 0;
  const int tid = threadIdx.x, bid = blockIdx.x;
  const int gtid = bid * 256 + tid;
  const int gwid = bid * 4 + (tid >> 6);
  const int utf = p.use_tf[0];

  // ---------- phase 0: zero state + weight conversions + embedding gather ----------
  for (int i = gtid; i < B_ * H_; i += NTHR) { p.cbuf[i] = 0.f; p.hbuf[i] = 0; }
  for (int i = gtid; i < G_ * H_ / 4; i += NTHR) {
    float4 v = *(const float4*)(p.enc_Wih + (size_t)i * 4);
    *(ushort4*)(p.wencWih + (size_t)i * 4) = make_ushort4(f2b(v.x), f2b(v.y), f2b(v.z), f2b(v.w));
  }
  for (int i = gtid; i < G_ * H_ / 4; i += NTHR) {
    float4 v = *(const float4*)(p.enc_Whh + (size_t)i * 4);
    *(ushort4*)(p.wencWhh + (size_t)i * 4) = make_ushort4(f2b(v.x), f2b(v.y), f2b(v.z), f2b(v.w));
  }
  for (int i = gtid; i < 2 * H_ * H_ / 4; i += NTHR) {
    float4 v = *(const float4*)(p.comb_W + (size_t)i * 4);
    *(ushort4*)(p.wcomb + (size_t)i * 4) = make_ushort4(f2b(v.x), f2b(v.y), f2b(v.z), f2b(v.w));
  }
  for (int i = gtid; i < S_ * 2 * H_ / 4; i += NTHR) {
    float4 v = *(const float4*)(p.attn_W + (size_t)i * 4);
    *(ushort4*)(p.wattn + (size_t)i * 4) = make_ushort4(f2b(v.x), f2b(v.y), f2b(v.z), f2b(v.w));
  }
  for (int i = gtid; i < V_ * H_ / 4; i += NTHR) {
    float4 v = *(const float4*)(p.out_W + (size_t)i * 4);
    *(ushort4*)(p.wout + (size_t)i * 4) = make_ushort4(f2b(v.x), f2b(v.y), f2b(v.z), f2b(v.w));
  }
  for (int i = gtid; i < G_ * 512; i += NTHR) {   // [dec_Wih | dec_Whh] fused
    int n = i >> 9, k4 = (i & 511) * 4;
    const float* src = (k4 < 1024) ? (p.dec_Wih + (size_t)n * 1024 + k4)
                                   : (p.dec_Whh + (size_t)n * 1024 + (k4 - 1024));
    float4 v = *(const float4*)src;
    *(ushort4*)(p.wdecG + (size_t)n * 2048 + k4) = make_ushort4(f2b(v.x), f2b(v.y), f2b(v.z), f2b(v.w));
  }
  for (int i = gtid; i < S_ * B_ * 256; i += NTHR) {   // encoder embedding gather
    int m = i >> 8, k4 = (i & 255) * 4;
    float4 v = *(const float4*)(p.enc_emb + (size_t)p.input[m] * 1024 + k4);
    *(ushort4*)(p.Xbf + (size_t)m * 1024 + k4) = make_ushort4(f2b(v.x), f2b(v.y), f2b(v.z), f2b(v.w));
  }
  gbar(p.bar, ++bargen);

  // ---------- phase 1: encXbf = Xbf @ wencWih^T  (2048x4096, K=1024) ----------
  for (int task = gwid; task < 64 * 64; task += NWAVE) {
    int mt = task >> 6, ct = task & 63;
    wave_gemm_bf16<false>(p.Xbf + (size_t)mt * 32 * 1024, p.wencWih, ct * 64, nullptr,
                          p.encXbf + (size_t)mt * 32 * G_, G_);
  }
  gbar(p.bar, ++bargen);

  // ---------- phase 2: encoder, 1 barrier/step ----------
  int pe = 0;
  for (int s = 0; s < 64; ++s) {
    if (bid < 64) {
      const u16* hprev = p.hbuf + (size_t)pe * B_ * H_;
      u16* hnext = p.hbuf + (size_t)(pe ^ 1) * B_ * H_;
      grouped_gemm(hprev, p.wencWhh, 1024, 0, bid, red_s, sg_s);
#pragma unroll
      for (int q2 = 0; q2 < 2; ++q2) {
        int sl = tid * 2 + q2;
        int b = sl >> 4, jj = sl & 15, j = bid * 16 + jj;
        size_t xo = (size_t)(s * 32 + b) * G_;
        float g0 = sg_s[b * 64 + jj]      + b2f(p.encXbf[xo + j])        + p.enc_b[j];
        float g1 = sg_s[b * 64 + 16 + jj] + b2f(p.encXbf[xo + 1024 + j]) + p.enc_b[1024 + j];
        float g2 = sg_s[b * 64 + 32 + jj] + b2f(p.encXbf[xo + 2048 + j]) + p.enc_b[2048 + j];
        float g3 = sg_s[b * 64 + 48 + jj] + b2f(p.encXbf[xo + 3072 + j]) + p.enc_b[3072 + j];
        float ig = sigf(g0), fg = sigf(g1), gg = tanhf(g2), og = sigf(g3);
        float cn = fg * p.cbuf[b * 1024 + j] + ig * gg;
        float hn = og * tanhf(cn);
        p.cbuf[b * 1024 + j] = cn;
        u16 hb2 = f2b(hn);
        hnext[b * 1024 + j] = hb2;
        p.enc_bs[((size_t)b * 1024 + j) * 64 + s] = hb2;
      }
    }
    pe ^= 1;
    gbar(p.bar, ++bargen);
  }

  // ---------- phase 3: decoder ----------
  int pd = pe;   // == 0; final encoder h in hbuf[0]
  for (int t = 0; t < 64; ++t) {
    const u16* hprev = p.hbuf + (size_t)pd * B_ * H_;
    u16* hnext = p.hbuf + (size_t)(pd ^ 1) * B_ * H_;
    // phase A: attention (blocks 0..31)  ||  gatesH GEMM (blocks 64..127)
    if (bid < 32) {
      float* xsh = red_s;
      float* hsh = red_s + 1024;
      float* ssc = red_s + 2048;
      float* aw = red_s + 2304;
      const int b = bid;
      int tok = 0;
      if (t > 0) tok = utf ? p.target[(t - 1) * 32 + b] : p.prevtok[b];
      {
        float4 v = *(const float4*)(p.dec_emb + (size_t)tok * 1024 + tid * 4);
        float x0 = fmaxf(v.x, 0.f), x1 = fmaxf(v.y, 0.f);
        float x2 = fmaxf(v.z, 0.f), x3 = fmaxf(v.w, 0.f);
        xsh[tid * 4 + 0] = x0; xsh[tid * 4 + 1] = x1;
        xsh[tid * 4 + 2] = x2; xsh[tid * 4 + 3] = x3;
        *(ushort4*)(p.xb + (size_t)b * 1024 + tid * 4) =
            make_ushort4(f2b(x0), f2b(x1), f2b(x2), f2b(x3));
        ushort4 hq = *(const ushort4*)(hprev + (size_t)b * 1024 + tid * 4);
        hsh[tid * 4 + 0] = b2f(hq.x); hsh[tid * 4 + 1] = b2f(hq.y);
        hsh[tid * 4 + 2] = b2f(hq.z); hsh[tid * 4 + 3] = b2f(hq.w);
      }
      __syncthreads();
      {
        const int sidx = tid & 63, q = tid >> 6;
        const u16* wr = p.wattn + (size_t)sidx * 2048 + q * 512;
        const float* src = (q < 2) ? (xsh + q * 512) : (hsh + (q - 2) * 512);
        float acc = 0.f;
        for (int k8 = 0; k8 < 64; ++k8) {
          bf16x8 v = *(const bf16x8*)(wr + k8 * 8);
#pragma unroll
          for (int e = 0; e < 8; ++e)
            acc = fmaf(src[k8 * 8 + e], b2f((u16)v[e]), acc);
        }
        ssc[q * 64 + sidx] = acc;
      }
      __syncthreads();
      if (tid < 64) {
        float sc = ssc[tid] + ssc[64 + tid] + ssc[128 + tid] + ssc[192 + tid] + p.attn_b[tid];
        float m = sc;
#pragma unroll
        for (int off = 32; off; off >>= 1) m = fmaxf(m, __shfl_xor(m, off));
        float e = expf(sc - m), sum = e;
#pragma unroll
        for (int off = 32; off; off >>= 1) sum += __shfl_xor(sum, off);
        aw[tid] = e / sum;
      }
      __syncthreads();
      for (int j = tid; j < 1024; j += 256) {
        const u16* rowp = p.enc_bs + ((size_t)b * 1024 + j) * 64;
        float acc = 0.f;
#pragma unroll
        for (int s8 = 0; s8 < 8; ++s8) {
          bf16x8 v = *(const bf16x8*)(rowp + s8 * 8);
#pragma unroll
          for (int e = 0; e < 8; ++e)
            acc = fmaf(aw[s8 * 8 + e], b2f((u16)v[e]), acc);
        }
        p.vb[(size_t)b * 1024 + j] = f2b(acc);
      }
    } else if (bid >= 64 && bid < 128) {
      const int grp = bid - 64;
      grouped_gemm(hprev, p.wdecG, 2048, 1024, grp, red_s, sg_s);
#pragma unroll
      for (int q2 = 0; q2 < 2; ++q2) {
        int sl = tid * 2 + q2;
        int b = sl >> 4, jj = sl & 15, j = grp * 16 + jj;
        p.gatesH[(size_t)b * G_ + j] = sg_s[b * 64 + jj];
        p.gatesH[(size_t)b * G_ + 1024 + j] = sg_s[b * 64 + 16 + jj];
        p.gatesH[(size_t)b * G_ + 2048 + j] = sg_s[b * 64 + 32 + jj];
        p.gatesH[(size_t)b * G_ + 3072 + j] = sg_s[b * 64 + 48 + jj];
      }
    }
    gbar(p.bar, ++bargen);
    // phase B: comb GEMM (blocks 0..15)
    if (bid < 16) comb_block(p, bid, red_s);
    gbar(p.bar, ++bargen);
    // phase C: gates-x GEMM + add gatesH + LSTM (blocks 0..63)
    if (bid < 64) {
      grouped_gemm(p.nbuf, p.wdecG, 2048, 0, bid, red_s, sg_s);
#pragma unroll
      for (int q2 = 0; q2 < 2; ++q2) {
        int sl = tid * 2 + q2;
        int b = sl >> 4, jj = sl & 15, j = bid * 16 + jj;
        float g0 = sg_s[b * 64 + jj]      + p.gatesH[(size_t)b * G_ + j]        + p.dec_b[j];
        float g1 = sg_s[b * 64 + 16 + jj] + p.gatesH[(size_t)b * G_ + 1024 + j] + p.dec_b[1024 + j];
        float g2 = sg_s[b * 64 + 32 + jj] + p.gatesH[(size_t)b * G_ + 2048 + j] + p.dec_b[2048 + j];
        float g3 = sg_s[b * 64 + 48 + jj] + p.gatesH[(size_t)b * G_ + 3072 + j] + p.dec_b[3072 + j];
        float ig = sigf(g0), fg = sigf(g1), gg = tanhf(g2), og = sigf(g3);
        float cn = fg * p.cbuf[b * 1024 + j] + ig * gg;
        float hn = og * tanhf(cn);
        p.cbuf[b * 1024 + j] = cn;
        u16 hb2 = f2b(hn);
        hnext[b * 1024 + j] = hb2;
        p.hall[((size_t)t * 32 + b) * 1024 + j] = hb2;
      }
    }
    pd ^= 1;
    gbar(p.bar, ++bargen);
    if (!utf) {   // per-step logits + argmax + loss (grid-uniform branch)
      for (int task = gwid; task < 500; task += NWAVE)
        wave_gemm_bf16<true>(hnext, p.wout, task * 64, p.out_b, p.encXbf, V_);
      gbar(p.bar, ++bargen);
      if (bid < 32)
        loss_row_bf16<true>(p.encXbf + (size_t)bid * V_, p.target[t * 32 + bid],
                            &p.loss_p[t * 32 + bid], &p.prevtok[bid], red_s);
      gbar(p.bar, ++bargen);
    }
  }

  // ---------- phase 4: batched logits + loss (teacher forcing) ----------
  if (utf) {
    for (int ch = 0; ch < 8; ++ch) {
      const u16* A = p.hall + (size_t)ch * 256 * 1024;
      for (int task = gwid; task < 8 * 500; task += NWAVE) {
        int mt = task / 500, ct = task % 500;
        wave_gemm_bf16<true>(A + (size_t)mt * 32 * 1024, p.wout, ct * 64, p.out_b,
                             p.encXbf + (size_t)mt * 32 * V_, V_);
      }
      gbar(p.bar, ++bargen);
      {
        int m = ch * 256 + bid;
        loss_row_bf16<false>(p.encXbf + (size_t)bid * V_, p.target[m], &p.loss_p[m],
                             nullptr, red_s);
      }
      gbar(p.bar, ++bargen);
    }
  }

  // ---------- final sum ----------
  if (bid == 0) {
    float a = 0.f;
    for (int i = tid; i < T_ * B_; i += 256) a += p.loss_p[i];
    red_s[tid] = a;
    __syncthreads();
    for (int off = 128; off; off >>= 1) {
      if (tid < off) red_s[tid] += red_s[tid + off];
      __syncthreads();
    }
    if (tid == 0) p.out[0] = red_s[0];
  }
}

// ---------------- host launch ----------------
extern "C" void kernel_launch(void* const* d_in, const int* in_sizes, int n_in,
                              void* d_out, int out_size, void* d_ws, size_t ws_size,
                              hipStream_t stream) {
  (void)in_sizes; (void)n_in; (void)out_size; (void)ws_size;
  Params p;
  p.input   = (const int*)d_in[0];
  p.target  = (const int*)d_in[1];
  p.use_tf  = (const int*)d_in[2];
  p.enc_emb = (const float*)d_in[3];
  p.enc_Wih = (const float*)d_in[4];
  p.enc_Whh = (const float*)d_in[5];
  p.enc_b   = (const float*)d_in[6];
  p.dec_emb = (const float*)d_in[7];
  p.dec_Wih = (const float*)d_in[8];
  p.dec_Whh = (const float*)d_in[9];
  p.dec_b   = (const float*)d_in[10];
  p.attn_W  = (const float*)d_in[11];
  p.attn_b  = (const float*)d_in[12];
  p.comb_W  = (const float*)d_in[13];
  p.comb_b  = (const float*)d_in[14];
  p.out_W   = (const float*)d_in[15];
  p.out_b   = (const float*)d_in[16];
  p.out     = (float*)d_out;

  char* ws = (char*)d_ws;
  size_t off = 0;
  auto alloc = [&](size_t bytes) {
    void* q = ws + off;
    off += ((bytes + 255) & ~(size_t)255);
    return q;
  };
  p.Xbf     = (u16*)alloc((size_t)S_ * B_ * H_ * 2);       // 4.2 MB
  p.encXbf  = (u16*)alloc((size_t)S_ * B_ * G_ * 2);       // 16.8 MB (reused as logits)
  p.enc_bs  = (u16*)alloc((size_t)B_ * H_ * S_ * 2);       // 4.2 MB  [b][d][s]
  p.hall    = (u16*)alloc((size_t)T_ * B_ * H_ * 2);       // 4.2 MB
  p.hbuf    = (u16*)alloc((size_t)2 * B_ * H_ * 2);        // double-buffered h
  p.xb      = (u16*)alloc((size_t)B_ * H_ * 2);
  p.vb      = (u16*)alloc((size_t)B_ * H_ * 2);
  p.nbuf    = (u16*)alloc((size_t)B_ * H_ * 2);
  p.gatesH  = (float*)alloc((size_t)B_ * G_ * 4);          // 512 KB
  p.cbuf    = (float*)alloc((size_t)B_ * H_ * 4);
  p.loss_p  = (float*)alloc((size_t)T_ * B_ * 4);
  p.prevtok = (int*)alloc(B_ * 4);
  p.bar     = (unsigned*)alloc(1024);
  p.wencWih = (u16*)alloc((size_t)G_ * H_ * 2);            // 8.4 MB
  p.wencWhh = (u16*)alloc((size_t)G_ * H_ * 2);            // 8.4 MB
  p.wdecG   = (u16*)alloc((size_t)G_ * 2 * H_ * 2);        // 16.8 MB
  p.wcomb   = (u16*)alloc((size_t)H_ * 2 * H_ * 2);        // 4.2 MB
  p.wattn   = (u16*)alloc((size_t)S_ * 2 * H_ * 2);        // 0.26 MB
  p.wout    = (u16*)alloc((size_t)V_ * H_ * 2);            // 65.5 MB
  // total ~134 MB

  binit<<<1, 288, 0, stream>>>(p.bar);
  seq2seq_all<<<NB, 256, 0, stream>>>(p);
}

// Round 7
// 8164.963 us; speedup vs baseline: 2.1809x; 1.0396x over previous
//
#include <hip/hip_runtime.h>
#include <cmath>
#include <cstddef>

// S=T=64, B=32, H=1024, G=4H, V=32000
constexpr int S_ = 64, T_ = 64, B_ = 32, H_ = 1024, G_ = 4096, V_ = 32000;
constexpr int NB = 256, NTHR = NB * 256, NWAVE = NB * 4;

typedef unsigned short u16;   // bf16 bit pattern
typedef __attribute__((ext_vector_type(8))) short bf16x8;
typedef __attribute__((ext_vector_type(4))) float f32x4;

__device__ __forceinline__ float sigf(float x) { return 1.f / (1.f + expf(-x)); }
__device__ __forceinline__ float b2f(u16 u) { return __uint_as_float(((unsigned)u) << 16); }
__device__ __forceinline__ u16 f2b(float f) {
  unsigned u = __float_as_uint(f);
  return (u16)((u + 0x7fff + ((u >> 16) & 1)) >> 16);  // RNE
}
__device__ __forceinline__ f32x4 mfma16(bf16x8 a, bf16x8 b, f32x4 c) {
  return __builtin_amdgcn_mfma_f32_16x16x32_bf16(a, b, c, 0, 0, 0);
}

struct Params {
  const int *input, *target, *use_tf;
  const float *enc_emb, *enc_Wih, *enc_Whh, *enc_b;
  const float *dec_emb, *dec_Wih, *dec_Whh, *dec_b;
  const float *attn_W, *attn_b, *comb_W, *comb_b, *out_W, *out_b;
  float* out;
  u16 *Xbf, *encXbf, *enc_bs, *hall, *hbuf, *xb, *vb, *nbuf;
  float *gatesH, *cbuf, *loss_p;
  int* prevtok;
  u16 *wencWih, *wencWhh, *wdecG, *wcomb, *wattn, *wout;
  unsigned* bar;   // [16 group counters spaced 16u] + [256]=root + [272]=gen
};

// ---------- two-level device-scope grid barrier ----------
__device__ __forceinline__ void gbar(unsigned* bar, unsigned target) {
  __syncthreads();
  if (threadIdx.x == 0) {
    __threadfence();
    int g = blockIdx.x >> 4;
    unsigned a = __hip_atomic_fetch_add(bar + g * 16, 1u, __ATOMIC_ACQ_REL,
                                        __HIP_MEMORY_SCOPE_AGENT);
    if (a == 15u) {
      unsigned r = __hip_atomic_fetch_add(bar + 256, 1u, __ATOMIC_ACQ_REL,
                                          __HIP_MEMORY_SCOPE_AGENT);
      if (r == 15u) {
        for (int i = 0; i < 16; ++i)
          __hip_atomic_store(bar + i * 16, 0u, __ATOMIC_RELAXED, __HIP_MEMORY_SCOPE_AGENT);
        __hip_atomic_store(bar + 256, 0u, __ATOMIC_RELAXED, __HIP_MEMORY_SCOPE_AGENT);
        __hip_atomic_store(bar + 272, target, __ATOMIC_RELEASE, __HIP_MEMORY_SCOPE_AGENT);
      }
    }
    while (__hip_atomic_load(bar + 272, __ATOMIC_ACQUIRE, __HIP_MEMORY_SCOPE_AGENT) < target)
      __builtin_amdgcn_s_sleep(2);
  }
  __syncthreads();
}

// ---------- per-wave 32x64 tile GEMM, K=1024, bf16 out (+opt bias) ----------
template <bool BIAS>
__device__ void wave_gemm_bf16(const u16* __restrict__ A, const u16* __restrict__ W,
                               int colbase, const float* __restrict__ bias,
                               u16* __restrict__ out, int ldo) {
  const int lane = threadIdx.x & 63;
  const int r = lane & 15, kg = (lane >> 4) * 8;
  const u16* Ar = A + (size_t)r * 1024 + kg;
  const u16* Wr = W + (size_t)(colbase + r) * 1024 + kg;
  f32x4 acc[2][4] = {};
#pragma unroll 2
  for (int k0 = 0; k0 < 1024; k0 += 32) {
    bf16x8 a0 = *(const bf16x8*)(Ar + k0);
    bf16x8 a1 = *(const bf16x8*)(Ar + 16 * 1024 + k0);
    bf16x8 b0 = *(const bf16x8*)(Wr + k0);
    bf16x8 b1 = *(const bf16x8*)(Wr + 16 * 1024 + k0);
    bf16x8 b2 = *(const bf16x8*)(Wr + 32 * 1024 + k0);
    bf16x8 b3 = *(const bf16x8*)(Wr + 48 * 1024 + k0);
    acc[0][0] = mfma16(a0, b0, acc[0][0]);
    acc[1][0] = mfma16(a1, b0, acc[1][0]);
    acc[0][1] = mfma16(a0, b1, acc[0][1]);
    acc[1][1] = mfma16(a1, b1, acc[1][1]);
    acc[0][2] = mfma16(a0, b2, acc[0][2]);
    acc[1][2] = mfma16(a1, b2, acc[1][2]);
    acc[0][3] = mfma16(a0, b3, acc[0][3]);
    acc[1][3] = mfma16(a1, b3, acc[1][3]);
  }
#pragma unroll
  for (int mi = 0; mi < 2; ++mi)
#pragma unroll
    for (int nj = 0; nj < 4; ++nj) {
      int col = colbase + nj * 16 + (lane & 15);
      int row0 = mi * 16 + ((lane >> 4) << 2);
#pragma unroll
      for (int reg = 0; reg < 4; ++reg) {
        float v = acc[mi][nj][reg];
        if (BIAS) v += bias[col];
        out[(size_t)(row0 + reg) * ldo + col] = f2b(v);
      }
    }
}

// ---------- block 32x64 grouped-col GEMM, K=1024 split over 4 waves -> sg[32][64] ----------
// gate col of frag q = q*1024 + grp*16 + f;   sg[b][q*16+f]
__device__ void grouped_gemm(const u16* __restrict__ A, const u16* __restrict__ Wm,
                             int ldw, int wkoff, int grp, float* red, float* sg) {
  const int tid = threadIdx.x, w = tid >> 6, lane = tid & 63;
  const int r = lane & 15, kg = (lane >> 4) * 8;
  const int kw0 = w * 256;
  const u16* Ar = A + (size_t)r * 1024 + kw0 + kg;
  const u16* W0 = Wm + (size_t)(grp * 16 + r) * ldw + wkoff + kw0 + kg;
  const u16* W1 = W0 + (size_t)1024 * ldw;
  const u16* W2 = W0 + (size_t)2048 * ldw;
  const u16* W3 = W0 + (size_t)3072 * ldw;
  f32x4 acc[2][4] = {};
#pragma unroll
  for (int k0 = 0; k0 < 256; k0 += 32) {
    bf16x8 a0 = *(const bf16x8*)(Ar + k0);
    bf16x8 a1 = *(const bf16x8*)(Ar + 16 * 1024 + k0);
    bf16x8 b0 = *(const bf16x8*)(W0 + k0);
    bf16x8 b1 = *(const bf16x8*)(W1 + k0);
    bf16x8 b2 = *(const bf16x8*)(W2 + k0);
    bf16x8 b3 = *(const bf16x8*)(W3 + k0);
    acc[0][0] = mfma16(a0, b0, acc[0][0]);
    acc[1][0] = mfma16(a1, b0, acc[1][0]);
    acc[0][1] = mfma16(a0, b1, acc[0][1]);
    acc[1][1] = mfma16(a1, b1, acc[1][1]);
    acc[0][2] = mfma16(a0, b2, acc[0][2]);
    acc[1][2] = mfma16(a1, b2, acc[1][2]);
    acc[0][3] = mfma16(a0, b3, acc[0][3]);
    acc[1][3] = mfma16(a1, b3, acc[1][3]);
  }
#pragma unroll
  for (int mi = 0; mi < 2; ++mi)
#pragma unroll
    for (int nj = 0; nj < 4; ++nj)
#pragma unroll
      for (int reg = 0; reg < 4; ++reg)
        red[(((w * 8) + mi * 4 + nj) * 64 + lane) * 4 + reg] = acc[mi][nj][reg];
  __syncthreads();
#pragma unroll
  for (int pp = 0; pp < 2; ++pp) {
    int p2 = w * 2 + pp, mi = p2 >> 2, nj = p2 & 3;
#pragma unroll
    for (int reg = 0; reg < 4; ++reg) {
      float v = red[((0 + p2) * 64 + lane) * 4 + reg] +
                red[((8 + p2) * 64 + lane) * 4 + reg] +
                red[((16 + p2) * 64 + lane) * 4 + reg] +
                red[((24 + p2) * 64 + lane) * 4 + reg];
      sg[(mi * 16 + ((lane >> 4) << 2) + reg) * 64 + nj * 16 + (lane & 15)] = v;
    }
  }
  __syncthreads();
}

// ---------- comb: 32x64 contiguous-col tile, K=2048 over [xb|vb], relu+bias -> nbuf ----------
__device__ void comb_block(const Params& p, int cb, float* red) {
  const int tid = threadIdx.x, w = tid >> 6, lane = tid & 63;
  const int r = lane & 15, kg = (lane >> 4) * 8;
  const int kw0 = w * 512;
  const u16* Abase = p.xb;
  int koff = kw0;
  if (kw0 >= 1024) { Abase = p.vb; koff = kw0 - 1024; }
  const u16* Ar = Abase + (size_t)r * 1024 + koff + kg;
  const u16* Wr = p.wcomb + (size_t)(cb * 64 + r) * 2048 + kw0 + kg;
  f32x4 acc[2][4] = {};
#pragma unroll 2
  for (int k0 = 0; k0 < 512; k0 += 32) {
    bf16x8 a0 = *(const bf16x8*)(Ar + k0);
    bf16x8 a1 = *(const bf16x8*)(Ar + 16 * 1024 + k0);
    bf16x8 b0 = *(const bf16x8*)(Wr + k0);
    bf16x8 b1 = *(const bf16x8*)(Wr + 16 * 2048 + k0);
    bf16x8 b2 = *(const bf16x8*)(Wr + 32 * 2048 + k0);
    bf16x8 b3 = *(const bf16x8*)(Wr + 48 * 2048 + k0);
    acc[0][0] = mfma16(a0, b0, acc[0][0]);
    acc[1][0] = mfma16(a1, b0, acc[1][0]);
    acc[0][1] = mfma16(a0, b1, acc[0][1]);
    acc[1][1] = mfma16(a1, b1, acc[1][1]);
    acc[0][2] = mfma16(a0, b2, acc[0][2]);
    acc[1][2] = mfma16(a1, b2, acc[1][2]);
    acc[0][3] = mfma16(a0, b3, acc[0][3]);
    acc[1][3] = mfma16(a1, b3, acc[1][3]);
  }
#pragma unroll
  for (int mi = 0; mi < 2; ++mi)
#pragma unroll
    for (int nj = 0; nj < 4; ++nj)
#pragma unroll
      for (int reg = 0; reg < 4; ++reg)
        red[(((w * 8) + mi * 4 + nj) * 64 + lane) * 4 + reg] = acc[mi][nj][reg];
  __syncthreads();
#pragma unroll
  for (int pp = 0; pp < 2; ++pp) {
    int p2 = w * 2 + pp, mi = p2 >> 2, nj = p2 & 3;
    int col = cb * 64 + nj * 16 + (lane & 15);
    int row0 = mi * 16 + ((lane >> 4) << 2);
#pragma unroll
    for (int reg = 0; reg < 4; ++reg) {
      float v = red[((0 + p2) * 64 + lane) * 4 + reg] +
                red[((8 + p2) * 64 + lane) * 4 + reg] +
                red[((16 + p2) * 64 + lane) * 4 + reg] +
                red[((24 + p2) * 64 + lane) * 4 + reg];
      v = fmaxf(v + p.comb_b[col], 0.f);
      p.nbuf[(size_t)(row0 + reg) * 1024 + col] = f2b(v);
    }
  }
  __syncthreads();
}

// ---------- log-softmax loss over one bf16 logits row ----------
template <bool AM>
__device__ void loss_row_bf16(const u16* __restrict__ row, int tgt,
                              float* __restrict__ loss_out, int* __restrict__ am_out,
                              float* sh) {
  float* sm = sh;
  float* ss = sh + 256;
  float* sbv = sh + 512;
  int* sbi = (int*)(sh + 768);
  const int tid = threadIdx.x;
  float m = -INFINITY, ssum = 0.f, bestv = -INFINITY;
  int besti = 0x7fffffff;
  for (int v = tid; v < V_; v += 256) {
    float x = b2f(row[v]);
    if (x > m) { ssum = ssum * expf(m - x) + 1.f; m = x; }
    else ssum += expf(x - m);
    if (AM) { if (x > bestv) { bestv = x; besti = v; } }
  }
  sm[tid] = m; ss[tid] = ssum;
  if (AM) { sbv[tid] = bestv; sbi[tid] = besti; }
  __syncthreads();
  for (int off = 128; off; off >>= 1) {
    if (tid < off) {
      float m2 = sm[tid + off], s2 = ss[tid + off];
      float mn = fmaxf(sm[tid], m2);
      ss[tid] = ss[tid] * expf(sm[tid] - mn) + s2 * expf(m2 - mn);
      sm[tid] = mn;
      if (AM) {
        float bv2 = sbv[tid + off];
        int bi2 = sbi[tid + off];
        if (bv2 > sbv[tid] || (bv2 == sbv[tid] && bi2 < sbi[tid])) { sbv[tid] = bv2; sbi[tid] = bi2; }
      }
    }
    __syncthreads();
  }
  if (tid == 0) {
    float lp = b2f(row[tgt]) - (sm[0] + logf(ss[0]));
    *loss_out = -lp * (1.f / 32.f);
    if (AM) *am_out = sbi[0];
  }
  __syncthreads();
}

// =================== main persistent kernel ===================
__global__ void binit(unsigned* bar) {
  int i = threadIdx.x;
  if (i < 288) bar[i] = 0u;
}

__global__ __launch_bounds__(256) void seq2seq_all(Params p) {
  __shared__ float red_s[8192];   // 32 KB (also reused: attn smem, loss smem)
  __shared__ float sg_s[2048];    // 8 KB reduced gate tile
  unsigned bargen = 0;
  const int tid = threadIdx.x, bid = blockIdx.x;
  const int gtid = bid * 256 + tid;
  const int gwid = bid * 4 + (tid >> 6);
  const int utf = p.use_tf[0];

  // ---------- phase 0: zero state + weight conversions + embedding gather ----------
  for (int i = gtid; i < B_ * H_; i += NTHR) { p.cbuf[i] = 0.f; p.hbuf[i] = 0; }
  for (int i = gtid; i < G_ * H_ / 4; i += NTHR) {
    float4 v = *(const float4*)(p.enc_Wih + (size_t)i * 4);
    *(ushort4*)(p.wencWih + (size_t)i * 4) = make_ushort4(f2b(v.x), f2b(v.y), f2b(v.z), f2b(v.w));
  }
  for (int i = gtid; i < G_ * H_ / 4; i += NTHR) {
    float4 v = *(const float4*)(p.enc_Whh + (size_t)i * 4);
    *(ushort4*)(p.wencWhh + (size_t)i * 4) = make_ushort4(f2b(v.x), f2b(v.y), f2b(v.z), f2b(v.w));
  }
  for (int i = gtid; i < 2 * H_ * H_ / 4; i += NTHR) {
    float4 v = *(const float4*)(p.comb_W + (size_t)i * 4);
    *(ushort4*)(p.wcomb + (size_t)i * 4) = make_ushort4(f2b(v.x), f2b(v.y), f2b(v.z), f2b(v.w));
  }
  for (int i = gtid; i < S_ * 2 * H_ / 4; i += NTHR) {
    float4 v = *(const float4*)(p.attn_W + (size_t)i * 4);
    *(ushort4*)(p.wattn + (size_t)i * 4) = make_ushort4(f2b(v.x), f2b(v.y), f2b(v.z), f2b(v.w));
  }
  for (int i = gtid; i < V_ * H_ / 4; i += NTHR) {
    float4 v = *(const float4*)(p.out_W + (size_t)i * 4);
    *(ushort4*)(p.wout + (size_t)i * 4) = make_ushort4(f2b(v.x), f2b(v.y), f2b(v.z), f2b(v.w));
  }
  for (int i = gtid; i < G_ * 512; i += NTHR) {   // [dec_Wih | dec_Whh] fused
    int n = i >> 9, k4 = (i & 511) * 4;
    const float* src = (k4 < 1024) ? (p.dec_Wih + (size_t)n * 1024 + k4)
                                   : (p.dec_Whh + (size_t)n * 1024 + (k4 - 1024));
    float4 v = *(const float4*)src;
    *(ushort4*)(p.wdecG + (size_t)n * 2048 + k4) = make_ushort4(f2b(v.x), f2b(v.y), f2b(v.z), f2b(v.w));
  }
  for (int i = gtid; i < S_ * B_ * 256; i += NTHR) {   // encoder embedding gather
    int m = i >> 8, k4 = (i & 255) * 4;
    float4 v = *(const float4*)(p.enc_emb + (size_t)p.input[m] * 1024 + k4);
    *(ushort4*)(p.Xbf + (size_t)m * 1024 + k4) = make_ushort4(f2b(v.x), f2b(v.y), f2b(v.z), f2b(v.w));
  }
  gbar(p.bar, ++bargen);

  // ---------- phase 1: encXbf = Xbf @ wencWih^T  (2048x4096, K=1024) ----------
  for (int task = gwid; task < 64 * 64; task += NWAVE) {
    int mt = task >> 6, ct = task & 63;
    wave_gemm_bf16<false>(p.Xbf + (size_t)mt * 32 * 1024, p.wencWih, ct * 64, nullptr,
                          p.encXbf + (size_t)mt * 32 * G_, G_);
  }
  gbar(p.bar, ++bargen);

  // ---------- phase 2: encoder, 1 barrier/step ----------
  int pe = 0;
  for (int s = 0; s < 64; ++s) {
    if (bid < 64) {
      const u16* hprev = p.hbuf + (size_t)pe * B_ * H_;
      u16* hnext = p.hbuf + (size_t)(pe ^ 1) * B_ * H_;
      grouped_gemm(hprev, p.wencWhh, 1024, 0, bid, red_s, sg_s);
#pragma unroll
      for (int q2 = 0; q2 < 2; ++q2) {
        int sl = tid * 2 + q2;
        int b = sl >> 4, jj = sl & 15, j = bid * 16 + jj;
        size_t xo = (size_t)(s * 32 + b) * G_;
        float g0 = sg_s[b * 64 + jj]      + b2f(p.encXbf[xo + j])        + p.enc_b[j];
        float g1 = sg_s[b * 64 + 16 + jj] + b2f(p.encXbf[xo + 1024 + j]) + p.enc_b[1024 + j];
        float g2 = sg_s[b * 64 + 32 + jj] + b2f(p.encXbf[xo + 2048 + j]) + p.enc_b[2048 + j];
        float g3 = sg_s[b * 64 + 48 + jj] + b2f(p.encXbf[xo + 3072 + j]) + p.enc_b[3072 + j];
        float ig = sigf(g0), fg = sigf(g1), gg = tanhf(g2), og = sigf(g3);
        float cn = fg * p.cbuf[b * 1024 + j] + ig * gg;
        float hn = og * tanhf(cn);
        p.cbuf[b * 1024 + j] = cn;
        u16 hb2 = f2b(hn);
        hnext[b * 1024 + j] = hb2;
        p.enc_bs[((size_t)b * 1024 + j) * 64 + s] = hb2;
      }
    }
    pe ^= 1;
    gbar(p.bar, ++bargen);
  }

  // ---------- phase 3: decoder ----------
  int pd = pe;   // == 0; final encoder h in hbuf[0]
  for (int t = 0; t < 64; ++t) {
    const u16* hprev = p.hbuf + (size_t)pd * B_ * H_;
    u16* hnext = p.hbuf + (size_t)(pd ^ 1) * B_ * H_;
    // phase A: attention (blocks 0..31)  ||  gatesH GEMM (blocks 64..127)
    if (bid < 32) {
      float* xsh = red_s;
      float* hsh = red_s + 1024;
      float* ssc = red_s + 2048;
      float* aw = red_s + 2304;
      const int b = bid;
      int tok = 0;
      if (t > 0) tok = utf ? p.target[(t - 1) * 32 + b] : p.prevtok[b];
      {
        float4 v = *(const float4*)(p.dec_emb + (size_t)tok * 1024 + tid * 4);
        float x0 = fmaxf(v.x, 0.f), x1 = fmaxf(v.y, 0.f);
        float x2 = fmaxf(v.z, 0.f), x3 = fmaxf(v.w, 0.f);
        xsh[tid * 4 + 0] = x0; xsh[tid * 4 + 1] = x1;
        xsh[tid * 4 + 2] = x2; xsh[tid * 4 + 3] = x3;
        *(ushort4*)(p.xb + (size_t)b * 1024 + tid * 4) =
            make_ushort4(f2b(x0), f2b(x1), f2b(x2), f2b(x3));
        ushort4 hq = *(const ushort4*)(hprev + (size_t)b * 1024 + tid * 4);
        hsh[tid * 4 + 0] = b2f(hq.x); hsh[tid * 4 + 1] = b2f(hq.y);
        hsh[tid * 4 + 2] = b2f(hq.z); hsh[tid * 4 + 3] = b2f(hq.w);
      }
      __syncthreads();
      {
        const int sidx = tid & 63, q = tid >> 6;
        const u16* wr = p.wattn + (size_t)sidx * 2048 + q * 512;
        const float* src = (q < 2) ? (xsh + q * 512) : (hsh + (q - 2) * 512);
        float acc = 0.f;
        for (int k8 = 0; k8 < 64; ++k8) {
          bf16x8 v = *(const bf16x8*)(wr + k8 * 8);
#pragma unroll
          for (int e = 0; e < 8; ++e)
            acc = fmaf(src[k8 * 8 + e], b2f((u16)v[e]), acc);
        }
        ssc[q * 64 + sidx] = acc;
      }
      __syncthreads();
      if (tid < 64) {
        float sc = ssc[tid] + ssc[64 + tid] + ssc[128 + tid] + ssc[192 + tid] + p.attn_b[tid];
        float m = sc;
#pragma unroll
        for (int off = 32; off; off >>= 1) m = fmaxf(m, __shfl_xor(m, off));
        float e = expf(sc - m), sum = e;
#pragma unroll
        for (int off = 32; off; off >>= 1) sum += __shfl_xor(sum, off);
        aw[tid] = e / sum;
      }
      __syncthreads();
      for (int j = tid; j < 1024; j += 256) {
        const u16* rowp = p.enc_bs + ((size_t)b * 1024 + j) * 64;
        float acc = 0.f;
#pragma unroll
        for (int s8 = 0; s8 < 8; ++s8) {
          bf16x8 v = *(const bf16x8*)(rowp + s8 * 8);
#pragma unroll
          for (int e = 0; e < 8; ++e)
            acc = fmaf(aw[s8 * 8 + e], b2f((u16)v[e]), acc);
        }
        p.vb[(size_t)b * 1024 + j] = f2b(acc);
      }
    } else if (bid >= 64 && bid < 128) {
      const int grp = bid - 64;
      grouped_gemm(hprev, p.wdecG, 2048, 1024, grp, red_s, sg_s);
#pragma unroll
      for (int q2 = 0; q2 < 2; ++q2) {
        int sl = tid * 2 + q2;
        int b = sl >> 4, jj = sl & 15, j = grp * 16 + jj;
        p.gatesH[(size_t)b * G_ + j]        = sg_s[b * 64 + jj];
        p.gatesH[(size_t)b * G_ + 1024 + j] = sg_s[b * 64 + 16 + jj];
        p.gatesH[(size_t)b * G_ + 2048 + j] = sg_s[b * 64 + 32 + jj];
        p.gatesH[(size_t)b * G_ + 3072 + j] = sg_s[b * 64 + 48 + jj];
      }
    }
    gbar(p.bar, ++bargen);
    // phase B: comb GEMM (blocks 0..15)
    if (bid < 16) comb_block(p, bid, red_s);
    gbar(p.bar, ++bargen);
    // phase C: gates-x GEMM + add gatesH + LSTM (blocks 0..63)
    if (bid < 64) {
      grouped_gemm(p.nbuf, p.wdecG, 2048, 0, bid, red_s, sg_s);
#pragma unroll
      for (int q2 = 0; q2 < 2; ++q2) {
        int sl = tid * 2 + q2;
        int b = sl >> 4, jj = sl & 15, j = bid * 16 + jj;
        float g0 = sg_s[b * 64 + jj]      + p.gatesH[(size_t)b * G_ + j]        + p.dec_b[j];
        float g1 = sg_s[b * 64 + 16 + jj] + p.gatesH[(size_t)b * G_ + 1024 + j] + p.dec_b[1024 + j];
        float g2 = sg_s[b * 64 + 32 + jj] + p.gatesH[(size_t)b * G_ + 2048 + j] + p.dec_b[2048 + j];
        float g3 = sg_s[b * 64 + 48 + jj] + p.gatesH[(size_t)b * G_ + 3072 + j] + p.dec_b[3072 + j];
        float ig = sigf(g0), fg = sigf(g1), gg = tanhf(g2), og = sigf(g3);
        float cn = fg * p.cbuf[b * 1024 + j] + ig * gg;
        float hn = og * tanhf(cn);
        p.cbuf[b * 1024 + j] = cn;
        u16 hb2 = f2b(hn);
        hnext[b * 1024 + j] = hb2;
        p.hall[((size_t)t * 32 + b) * 1024 + j] = hb2;
      }
    }
    pd ^= 1;
    gbar(p.bar, ++bargen);
    if (!utf) {   // per-step logits + argmax + loss (grid-uniform branch)
      for (int task = gwid; task < 500; task += NWAVE)
        wave_gemm_bf16<true>(p.hbuf + (size_t)pd * B_ * H_, p.wout, task * 64,
                             p.out_b, p.encXbf, V_);
      gbar(p.bar, ++bargen);
      if (bid < 32)
        loss_row_bf16<true>(p.encXbf + (size_t)bid * V_, p.target[t * 32 + bid],
                            &p.loss_p[t * 32 + bid], &p.prevtok[bid], red_s);
      gbar(p.bar, ++bargen);
    }
  }

  // ---------- phase 4: batched logits + loss (teacher forcing) ----------
  if (utf) {
    for (int ch = 0; ch < 8; ++ch) {
      const u16* A = p.hall + (size_t)ch * 256 * 1024;
      for (int task = gwid; task < 8 * 500; task += NWAVE) {
        // R7 change (the ONLY diff vs R4): ct-major task order so in-flight
        // tasks share wout column tiles across all 8 mt -> wout read ~1x/chunk
        // instead of 8x. Pure permutation of identical work items.
        int ct = task >> 3, mt = task & 7;
        wave_gemm_bf16<true>(A + (size_t)mt * 32 * 1024, p.wout, ct * 64, p.out_b,
                             p.encXbf + (size_t)mt * 32 * V_, V_);
      }
      gbar(p.bar, ++bargen);
      {
        int m = ch * 256 + bid;
        loss_row_bf16<false>(p.encXbf + (size_t)bid * V_, p.target[m], &p.loss_p[m],
                             nullptr, red_s);
      }
      gbar(p.bar, ++bargen);
    }
  }

  // ---------- final sum ----------
  if (bid == 0) {
    float a = 0.f;
    for (int i = tid; i < T_ * B_; i += 256) a += p.loss_p[i];
    red_s[tid] = a;
    __syncthreads();
    for (int off = 128; off; off >>= 1) {
      if (tid < off) red_s[tid] += red_s[tid + off];
      __syncthreads();
    }
    if (tid == 0) p.out[0] = red_s[0];
  }
}

// ---------------- host launch ----------------
extern "C" void kernel_launch(void* const* d_in, const int* in_sizes, int n_in,
                              void* d_out, int out_size, void* d_ws, size_t ws_size,
                              hipStream_t stream) {
  (void)in_sizes; (void)n_in; (void)out_size; (void)ws_size;
  Params p;
  p.input   = (const int*)d_in[0];
  p.target  = (const int*)d_in[1];
  p.use_tf  = (const int*)d_in[2];
  p.enc_emb = (const float*)d_in[3];
  p.enc_Wih = (const float*)d_in[4];
  p.enc_Whh = (const float*)d_in[5];
  p.enc_b   = (const float*)d_in[6];
  p.dec_emb = (const float*)d_in[7];
  p.dec_Wih = (const float*)d_in[8];
  p.dec_Whh = (const float*)d_in[9];
  p.dec_b   = (const float*)d_in[10];
  p.attn_W  = (const float*)d_in[11];
  p.attn_b  = (const float*)d_in[12];
  p.comb_W  = (const float*)d_in[13];
  p.comb_b  = (const float*)d_in[14];
  p.out_W   = (const float*)d_in[15];
  p.out_b   = (const float*)d_in[16];
  p.out     = (float*)d_out;

  char* ws = (char*)d_ws;
  size_t off = 0;
  auto alloc = [&](size_t bytes) {
    void* q = ws + off;
    off += ((bytes + 255) & ~(size_t)255);
    return q;
  };
  p.Xbf     = (u16*)alloc((size_t)S_ * B_ * H_ * 2);       // 4.2 MB
  p.encXbf  = (u16*)alloc((size_t)S_ * B_ * G_ * 2);       // 16.8 MB (reused as logits)
  p.enc_bs  = (u16*)alloc((size_t)B_ * H_ * S_ * 2);       // 4.2 MB  [b][d][s]
  p.hall    = (u16*)alloc((size_t)T_ * B_ * H_ * 2);       // 4.2 MB
  p.hbuf    = (u16*)alloc((size_t)2 * B_ * H_ * 2);        // double-buffered h
  p.xb      = (u16*)alloc((size_t)B_ * H_ * 2);
  p.vb      = (u16*)alloc((size_t)B_ * H_ * 2);
  p.nbuf    = (u16*)alloc((size_t)B_ * H_ * 2);
  p.gatesH  = (float*)alloc((size_t)B_ * G_ * 4);          // 512 KB
  p.cbuf    = (float*)alloc((size_t)B_ * H_ * 4);
  p.loss_p  = (float*)alloc((size_t)T_ * B_ * 4);
  p.prevtok = (int*)alloc(B_ * 4);
  p.bar     = (unsigned*)alloc(1024);
  p.wencWih = (u16*)alloc((size_t)G_ * H_ * 2);            // 8.4 MB
  p.wencWhh = (u16*)alloc((size_t)G_ * H_ * 2);            // 8.4 MB
  p.wdecG   = (u16*)alloc((size_t)G_ * 2 * H_ * 2);        // 16.8 MB
  p.wcomb   = (u16*)alloc((size_t)H_ * 2 * H_ * 2);        // 4.2 MB
  p.wattn   = (u16*)alloc((size_t)S_ * 2 * H_ * 2);        // 0.26 MB
  p.wout    = (u16*)alloc((size_t)V_ * H_ * 2);            // 65.5 MB
  // total ~134 MB

  binit<<<1, 288, 0, stream>>>(p.bar);
  seq2seq_all<<<NB, 256, 0, stream>>>(p);
}

// Round 8
// 7611.738 us; speedup vs baseline: 2.3394x; 1.0727x over previous
//
#include <hip/hip_runtime.h>
#include <cmath>
#include <cstddef>

// S=T=64, B=32, H=1024, G=4H, V=32000
constexpr int S_ = 64, T_ = 64, B_ = 32, H_ = 1024, G_ = 4096, V_ = 32000;
constexpr int NB = 256, BT = 512, NTHR = NB * BT, NWAVE = NB * 8;

typedef unsigned short u16;   // bf16 bit pattern
typedef __attribute__((ext_vector_type(8))) short bf16x8;
typedef __attribute__((ext_vector_type(4))) float f32x4;

__device__ __forceinline__ float sigf(float x) { return 1.f / (1.f + expf(-x)); }
__device__ __forceinline__ float b2f(u16 u) { return __uint_as_float(((unsigned)u) << 16); }
__device__ __forceinline__ u16 f2b(float f) {
  unsigned u = __float_as_uint(f);
  return (u16)((u + 0x7fff + ((u >> 16) & 1)) >> 16);  // RNE
}
__device__ __forceinline__ f32x4 mfma16(bf16x8 a, bf16x8 b, f32x4 c) {
  return __builtin_amdgcn_mfma_f32_16x16x32_bf16(a, b, c, 0, 0, 0);
}

struct Params {
  const int *input, *target, *use_tf;
  const float *enc_emb, *enc_Wih, *enc_Whh, *enc_b;
  const float *dec_emb, *dec_Wih, *dec_Whh, *dec_b;
  const float *attn_W, *attn_b, *comb_W, *comb_b, *out_W, *out_b;
  float* out;
  u16 *Xbf, *encXbf, *enc_bs, *hall, *hbuf, *xb, *vb, *nbuf, *xball, *ring;
  float *combX, *scoreX, *gatesH, *cbuf, *loss_p;
  int* prevtok;
  u16 *wencWih, *wencWhh, *wdecG, *wcomb, *wattn, *wout;
  unsigned* bar;
};

// ---------- two-level device-scope grid barrier (256 arrivals, thread 0 only) ----------
__device__ __forceinline__ void gbar(unsigned* bar, unsigned target) {
  __syncthreads();
  if (threadIdx.x == 0) {
    __threadfence();
    int g = blockIdx.x >> 4;
    unsigned a = __hip_atomic_fetch_add(bar + g * 16, 1u, __ATOMIC_ACQ_REL,
                                        __HIP_MEMORY_SCOPE_AGENT);
    if (a == 15u) {
      unsigned r = __hip_atomic_fetch_add(bar + 256, 1u, __ATOMIC_ACQ_REL,
                                          __HIP_MEMORY_SCOPE_AGENT);
      if (r == 15u) {
        for (int i = 0; i < 16; ++i)
          __hip_atomic_store(bar + i * 16, 0u, __ATOMIC_RELAXED, __HIP_MEMORY_SCOPE_AGENT);
        __hip_atomic_store(bar + 256, 0u, __ATOMIC_RELAXED, __HIP_MEMORY_SCOPE_AGENT);
        __hip_atomic_store(bar + 272, target, __ATOMIC_RELEASE, __HIP_MEMORY_SCOPE_AGENT);
      }
    }
    while (__hip_atomic_load(bar + 272, __ATOMIC_ACQUIRE, __HIP_MEMORY_SCOPE_AGENT) < target)
      __builtin_amdgcn_s_sleep(2);
  }
  __syncthreads();
}

// ---------- per-wave 32x64 tile GEMM, K=1024 ----------
// EPI: 0 bf16, 1 bf16+bias, 2 f32, 3 f32+bias
template <int EPI>
__device__ void wave_gemm(const u16* __restrict__ A, const u16* __restrict__ W,
                          int ldw, int wkoff, int colbase, const float* __restrict__ bias,
                          void* __restrict__ outp, int ldo) {
  const int lane = threadIdx.x & 63;
  const int r = lane & 15, kg = (lane >> 4) * 8;
  const u16* Ar = A + (size_t)r * 1024 + kg;
  const u16* Wr = W + (size_t)(colbase + r) * ldw + wkoff + kg;
  f32x4 acc[2][4] = {};
#pragma unroll 2
  for (int k0 = 0; k0 < 1024; k0 += 32) {
    bf16x8 a0 = *(const bf16x8*)(Ar + k0);
    bf16x8 a1 = *(const bf16x8*)(Ar + 16 * 1024 + k0);
    bf16x8 b0 = *(const bf16x8*)(Wr + k0);
    bf16x8 b1 = *(const bf16x8*)(Wr + (size_t)16 * ldw + k0);
    bf16x8 b2 = *(const bf16x8*)(Wr + (size_t)32 * ldw + k0);
    bf16x8 b3 = *(const bf16x8*)(Wr + (size_t)48 * ldw + k0);
    acc[0][0] = mfma16(a0, b0, acc[0][0]);
    acc[1][0] = mfma16(a1, b0, acc[1][0]);
    acc[0][1] = mfma16(a0, b1, acc[0][1]);
    acc[1][1] = mfma16(a1, b1, acc[1][1]);
    acc[0][2] = mfma16(a0, b2, acc[0][2]);
    acc[1][2] = mfma16(a1, b2, acc[1][2]);
    acc[0][3] = mfma16(a0, b3, acc[0][3]);
    acc[1][3] = mfma16(a1, b3, acc[1][3]);
  }
#pragma unroll
  for (int mi = 0; mi < 2; ++mi)
#pragma unroll
    for (int nj = 0; nj < 4; ++nj) {
      int col = colbase + nj * 16 + (lane & 15);
      int row0 = mi * 16 + ((lane >> 4) << 2);
#pragma unroll
      for (int reg = 0; reg < 4; ++reg) {
        float v = acc[mi][nj][reg];
        if (EPI == 1 || EPI == 3) v += bias[col];
        if (EPI <= 1) ((u16*)outp)[(size_t)(row0 + reg) * ldo + col] = f2b(v);
        else ((float*)outp)[(size_t)(row0 + reg) * ldo + col] = v;
      }
    }
}

// ---------- block 32x64 grouped-col GEMM: 8-wave K-split (KSW=128) -> sg[32][64] ----------
// gate col of quadrant q = q*1024 + grp*16 + jj;  sg[b*64 + q*16 + jj]
__device__ void grouped_gemm8(const u16* __restrict__ A, const u16* __restrict__ Wm,
                              int ldw, int wkoff, int grp, float* red, float* sg) {
  const int tid = threadIdx.x, w = tid >> 6, lane = tid & 63;
  const int r = lane & 15, kg = (lane >> 4) * 8;
  const int kw0 = w * 128;
  const u16* Ar = A + (size_t)r * 1024 + kw0 + kg;
  const u16* W0 = Wm + (size_t)(grp * 16 + r) * ldw + wkoff + kw0 + kg;
  const u16* W1 = W0 + (size_t)1024 * ldw;
  const u16* W2 = W0 + (size_t)2048 * ldw;
  const u16* W3 = W0 + (size_t)3072 * ldw;
  f32x4 acc[2][4] = {};
#pragma unroll
  for (int k0 = 0; k0 < 128; k0 += 32) {
    bf16x8 a0 = *(const bf16x8*)(Ar + k0);
    bf16x8 a1 = *(const bf16x8*)(Ar + 16 * 1024 + k0);
    bf16x8 b0 = *(const bf16x8*)(W0 + k0);
    bf16x8 b1 = *(const bf16x8*)(W1 + k0);
    bf16x8 b2 = *(const bf16x8*)(W2 + k0);
    bf16x8 b3 = *(const bf16x8*)(W3 + k0);
    acc[0][0] = mfma16(a0, b0, acc[0][0]);
    acc[1][0] = mfma16(a1, b0, acc[1][0]);
    acc[0][1] = mfma16(a0, b1, acc[0][1]);
    acc[1][1] = mfma16(a1, b1, acc[1][1]);
    acc[0][2] = mfma16(a0, b2, acc[0][2]);
    acc[1][2] = mfma16(a1, b2, acc[1][2]);
    acc[0][3] = mfma16(a0, b3, acc[0][3]);
    acc[1][3] = mfma16(a1, b3, acc[1][3]);
  }
#pragma unroll
  for (int mi = 0; mi < 2; ++mi)
#pragma unroll
    for (int nj = 0; nj < 4; ++nj)
#pragma unroll
      for (int reg = 0; reg < 4; ++reg)
        red[(((w * 8) + mi * 4 + nj) * 64 + lane) * 4 + reg] = acc[mi][nj][reg];
  __syncthreads();
  {
    const int p2 = w;   // wave w reduces fragment p=w over 8 partials
    const int mi = p2 >> 2, nj = p2 & 3;
#pragma unroll
    for (int reg = 0; reg < 4; ++reg) {
      float v = 0.f;
#pragma unroll
      for (int ww = 0; ww < 8; ++ww)
        v += red[(((ww * 8) + p2) * 64 + lane) * 4 + reg];
      sg[(mi * 16 + ((lane >> 4) << 2) + reg) * 64 + nj * 16 + (lane & 15)] = v;
    }
  }
  __syncthreads();
}

// ---------- comb: 32-col tile per block, 8-wave K-split; +combX(optional)+bias, relu -> nbuf ----------
template <int KTOT, bool HASX>
__device__ void comb8(const Params& p, int cb, int t, float* red) {
  const int tid = threadIdx.x, w = tid >> 6, lane = tid & 63;
  const int r = lane & 15, kg = (lane >> 4) * 8;
  constexpr int KSW = KTOT / 8;
  const int kw0 = w * KSW;
  const u16* Abase;
  int koff;
  if (KTOT == 2048) { Abase = (kw0 < 1024) ? p.xb : p.vb; koff = kw0 & 1023; }
  else { Abase = p.vb; koff = kw0; }
  const u16* Ar = Abase + (size_t)r * 1024 + koff + kg;
  const int wko = (KTOT == 1024) ? 1024 : 0;   // v-part cols of comb_W when x precomputed
  const u16* W0 = p.wcomb + (size_t)(cb * 32 + r) * 2048 + wko + kw0 + kg;
  const u16* W1 = W0 + (size_t)16 * 2048;
  f32x4 acc[2][2] = {};
#pragma unroll
  for (int k0 = 0; k0 < KSW; k0 += 32) {
    bf16x8 a0 = *(const bf16x8*)(Ar + k0);
    bf16x8 a1 = *(const bf16x8*)(Ar + 16 * 1024 + k0);
    bf16x8 b0 = *(const bf16x8*)(W0 + k0);
    bf16x8 b1 = *(const bf16x8*)(W1 + k0);
    acc[0][0] = mfma16(a0, b0, acc[0][0]);
    acc[1][0] = mfma16(a1, b0, acc[1][0]);
    acc[0][1] = mfma16(a0, b1, acc[0][1]);
    acc[1][1] = mfma16(a1, b1, acc[1][1]);
  }
#pragma unroll
  for (int mi = 0; mi < 2; ++mi)
#pragma unroll
    for (int nj = 0; nj < 2; ++nj)
#pragma unroll
      for (int reg = 0; reg < 4; ++reg)
        red[(((w * 4) + mi * 2 + nj) * 64 + lane) * 4 + reg] = acc[mi][nj][reg];
  __syncthreads();
  if (w < 4) {
    const int p2 = w, mi = p2 >> 1, nj = p2 & 1;
#pragma unroll
    for (int reg = 0; reg < 4; ++reg) {
      float v = 0.f;
#pragma unroll
      for (int ww = 0; ww < 8; ++ww)
        v += red[(((ww * 4) + p2) * 64 + lane) * 4 + reg];
      int row = mi * 16 + ((lane >> 4) << 2) + reg;
      int col = cb * 32 + nj * 16 + (lane & 15);
      if (HASX) v += p.combX[(size_t)(t * 32 + row) * 1024 + col];
      v += p.comb_b[col];
      p.nbuf[(size_t)row * 1024 + col] = f2b(fmaxf(v, 0.f));
    }
  }
  __syncthreads();
}

// ---------- log-softmax loss over one bf16 logits row (512 threads) ----------
template <bool AM>
__device__ void loss_row_bf16(const u16* __restrict__ row, int tgt,
                              float* __restrict__ loss_out, int* __restrict__ am_out,
                              float* sh) {
  float* sm = sh;
  float* ss = sh + 512;
  float* sbv = sh + 1024;
  int* sbi = (int*)(sh + 1536);
  const int tid = threadIdx.x;
  float m = -INFINITY, ssum = 0.f, bestv = -INFINITY;
  int besti = 0x7fffffff;
  for (int v = tid; v < V_; v += BT) {
    float x = b2f(row[v]);
    if (x > m) { ssum = ssum * expf(m - x) + 1.f; m = x; }
    else ssum += expf(x - m);
    if (AM) { if (x > bestv) { bestv = x; besti = v; } }
  }
  sm[tid] = m; ss[tid] = ssum;
  if (AM) { sbv[tid] = bestv; sbi[tid] = besti; }
  __syncthreads();
  for (int off = 256; off; off >>= 1) {
    if (tid < off) {
      float m2 = sm[tid + off], s2 = ss[tid + off];
      float mn = fmaxf(sm[tid], m2);
      ss[tid] = ss[tid] * expf(sm[tid] - mn) + s2 * expf(m2 - mn);
      sm[tid] = mn;
      if (AM) {
        float bv2 = sbv[tid + off];
        int bi2 = sbi[tid + off];
        if (bv2 > sbv[tid] || (bv2 == sbv[tid] && bi2 < sbi[tid])) { sbv[tid] = bv2; sbi[tid] = bi2; }
      }
    }
    __syncthreads();
  }
  if (tid == 0) {
    float lp = b2f(row[tgt]) - (sm[0] + logf(ss[0]));
    *loss_out = -lp * (1.f / 32.f);
    if (AM) *am_out = sbi[0];
  }
  __syncthreads();
}

// =================== main persistent kernel ===================
__global__ void binit(unsigned* bar) {
  int i = threadIdx.x;
  if (i < 288) bar[i] = 0u;
}

__global__ __launch_bounds__(BT) void seq2seq_all(Params p) {
  __shared__ float red_s[16384];   // 64 KB (grouped reduce / attn smem / loss smem)
  __shared__ float sg_s[2048];     // 8 KB reduced gate tile
  unsigned bargen = 0;
  const int tid = threadIdx.x, bid = blockIdx.x;
  const int gtid = bid * BT + tid;
  const int gwid = bid * 8 + (tid >> 6);
  const int utf = p.use_tf[0];

  // ---------- phase 0: zero state + weight conversions + gathers ----------
  for (int i = gtid; i < B_ * H_; i += NTHR) { p.cbuf[i] = 0.f; p.hbuf[i] = 0; }
  for (int i = gtid; i < G_ * H_ / 4; i += NTHR) {
    float4 v = *(const float4*)(p.enc_Wih + (size_t)i * 4);
    *(ushort4*)(p.wencWih + (size_t)i * 4) = make_ushort4(f2b(v.x), f2b(v.y), f2b(v.z), f2b(v.w));
  }
  for (int i = gtid; i < G_ * H_ / 4; i += NTHR) {
    float4 v = *(const float4*)(p.enc_Whh + (size_t)i * 4);
    *(ushort4*)(p.wencWhh + (size_t)i * 4) = make_ushort4(f2b(v.x), f2b(v.y), f2b(v.z), f2b(v.w));
  }
  for (int i = gtid; i < 2 * H_ * H_ / 4; i += NTHR) {
    float4 v = *(const float4*)(p.comb_W + (size_t)i * 4);
    *(ushort4*)(p.wcomb + (size_t)i * 4) = make_ushort4(f2b(v.x), f2b(v.y), f2b(v.z), f2b(v.w));
  }
  for (int i = gtid; i < S_ * 2 * H_ / 4; i += NTHR) {
    float4 v = *(const float4*)(p.attn_W + (size_t)i * 4);
    *(ushort4*)(p.wattn + (size_t)i * 4) = make_ushort4(f2b(v.x), f2b(v.y), f2b(v.z), f2b(v.w));
  }
  for (int i = gtid; i < V_ * H_ / 4; i += NTHR) {
    float4 v = *(const float4*)(p.out_W + (size_t)i * 4);
    *(ushort4*)(p.wout + (size_t)i * 4) = make_ushort4(f2b(v.x), f2b(v.y), f2b(v.z), f2b(v.w));
  }
  for (int i = gtid; i < G_ * 512; i += NTHR) {   // [dec_Wih | dec_Whh]
    int n = i >> 9, k4 = (i & 511) * 4;
    const float* src = (k4 < 1024) ? (p.dec_Wih + (size_t)n * 1024 + k4)
                                   : (p.dec_Whh + (size_t)n * 1024 + (k4 - 1024));
    float4 v = *(const float4*)src;
    *(ushort4*)(p.wdecG + (size_t)n * 2048 + k4) = make_ushort4(f2b(v.x), f2b(v.y), f2b(v.z), f2b(v.w));
  }
  for (int i = gtid; i < S_ * B_ * 256; i += NTHR) {   // encoder embedding gather
    int m = i >> 8, k4 = (i & 255) * 4;
    float4 v = *(const float4*)(p.enc_emb + (size_t)p.input[m] * 1024 + k4);
    *(ushort4*)(p.Xbf + (size_t)m * 1024 + k4) = make_ushort4(f2b(v.x), f2b(v.y), f2b(v.z), f2b(v.w));
  }
  for (int i = gtid; i < T_ * B_ * 256; i += NTHR) {   // teacher-forced decoder x (relu)
    int m = i >> 8, k4 = (i & 255) * 4;
    int t = m >> 5, b = m & 31;
    int tok = (t == 0) ? 0 : p.target[(t - 1) * 32 + b];
    float4 v = *(const float4*)(p.dec_emb + (size_t)tok * 1024 + k4);
    *(ushort4*)(p.xball + (size_t)m * 1024 + k4) =
        make_ushort4(f2b(fmaxf(v.x, 0.f)), f2b(fmaxf(v.y, 0.f)),
                     f2b(fmaxf(v.z, 0.f)), f2b(fmaxf(v.w, 0.f)));
  }
  gbar(p.bar, ++bargen);

  // ---------- phase 1: batched GEMMs: encX (4096) | combX (1024) | scoreX (64) ----------
  for (int task = gwid; task < 4096 + 1024 + 64; task += NWAVE) {
    if (task < 4096) {
      int mt = task >> 6, ct = task & 63;
      wave_gemm<0>(p.Xbf + (size_t)mt * 32 * 1024, p.wencWih, 1024, 0, ct * 64,
                   nullptr, p.encXbf + (size_t)mt * 32 * G_, G_);
    } else if (task < 5120) {
      int tt = task - 4096, mt = tt >> 4, ct = tt & 15;
      wave_gemm<2>(p.xball + (size_t)mt * 32 * 1024, p.wcomb, 2048, 0, ct * 64,
                   nullptr, p.combX + (size_t)mt * 32 * 1024, 1024);
    } else {
      int mt = task - 5120;
      wave_gemm<3>(p.xball + (size_t)mt * 32 * 1024, p.wattn, 2048, 0, 0,
                   p.attn_b, p.scoreX + (size_t)mt * 32 * 64, 64);
    }
  }
  gbar(p.bar, ++bargen);

  // ---------- phase 2: encoder, 1 barrier/step ----------
  int pe = 0;
  for (int s = 0; s < 64; ++s) {
    if (bid < 64) {
      const u16* hprev = p.hbuf + (size_t)pe * B_ * H_;
      u16* hnext = p.hbuf + (size_t)(pe ^ 1) * B_ * H_;
      grouped_gemm8(hprev, p.wencWhh, 1024, 0, bid, red_s, sg_s);
      {
        int slot = tid;   // 512 slots = 32 b x 16 jj
        int b = slot >> 4, jj = slot & 15, j = bid * 16 + jj;
        size_t xo = (size_t)(s * 32 + b) * G_;
        float g0 = sg_s[b * 64 + jj]      + b2f(p.encXbf[xo + j])        + p.enc_b[j];
        float g1 = sg_s[b * 64 + 16 + jj] + b2f(p.encXbf[xo + 1024 + j]) + p.enc_b[1024 + j];
        float g2 = sg_s[b * 64 + 32 + jj] + b2f(p.encXbf[xo + 2048 + j]) + p.enc_b[2048 + j];
        float g3 = sg_s[b * 64 + 48 + jj] + b2f(p.encXbf[xo + 3072 + j]) + p.enc_b[3072 + j];
        float ig = sigf(g0), fg = sigf(g1), gg = tanhf(g2), og = sigf(g3);
        float cn = fg * p.cbuf[b * 1024 + j] + ig * gg;
        float hn = og * tanhf(cn);
        p.cbuf[b * 1024 + j] = cn;
        u16 hb2 = f2b(hn);
        hnext[b * 1024 + j] = hb2;
        p.enc_bs[((size_t)b * 1024 + j) * 64 + s] = hb2;
      }
    }
    pe ^= 1;
    gbar(p.bar, ++bargen);
  }

  // ---------- phase 3: decoder ----------
  int pd = pe;   // == 0
  if (utf) {
    for (int t = 0; t < 64; ++t) {
      const u16* hprev = p.hbuf + (size_t)pd * B_ * H_;
      u16* hnext = p.hbuf + (size_t)(pd ^ 1) * B_ * H_;
      // ---- phase A: attention h-part (0..31) || gatesH (64..127) ----
      if (bid < 32) {
        float* hsh = red_s;            // 1024
        float* ssc = red_s + 1024;     // 512
        float* aw  = red_s + 1536;     // 64
        const int b = bid;
        {
          ushort2 hq = *(const ushort2*)(hprev + (size_t)b * 1024 + tid * 2);
          hsh[tid * 2] = b2f(hq.x);
          hsh[tid * 2 + 1] = b2f(hq.y);
        }
        __syncthreads();
        {
          const int sidx = tid & 63, q = tid >> 6;   // q in 0..7, 128-K chunk
          const u16* wr = p.wattn + (size_t)sidx * 2048 + 1024 + q * 128;
          const float* src = hsh + q * 128;
          float acc = 0.f;
          for (int k8 = 0; k8 < 16; ++k8) {
            bf16x8 v = *(const bf16x8*)(wr + k8 * 8);
#pragma unroll
            for (int e = 0; e < 8; ++e)
              acc = fmaf(src[k8 * 8 + e], b2f((u16)v[e]), acc);
          }
          ssc[q * 64 + sidx] = acc;
        }
        __syncthreads();
        if (tid < 64) {
          float sc = p.scoreX[(size_t)(t * 32 + b) * 64 + tid];
#pragma unroll
          for (int q = 0; q < 8; ++q) sc += ssc[q * 64 + tid];
          float m = sc;
#pragma unroll
          for (int off = 32; off; off >>= 1) m = fmaxf(m, __shfl_xor(m, off));
          float e = expf(sc - m), sum = e;
#pragma unroll
          for (int off = 32; off; off >>= 1) sum += __shfl_xor(sum, off);
          aw[tid] = e / sum;
        }
        __syncthreads();
        for (int j = tid; j < 1024; j += BT) {
          const u16* rowp = p.enc_bs + ((size_t)b * 1024 + j) * 64;
          float acc = 0.f;
#pragma unroll
          for (int s8 = 0; s8 < 8; ++s8) {
            bf16x8 v = *(const bf16x8*)(rowp + s8 * 8);
#pragma unroll
            for (int e = 0; e < 8; ++e)
              acc = fmaf(aw[s8 * 8 + e], b2f((u16)v[e]), acc);
          }
          p.vb[(size_t)b * 1024 + j] = f2b(acc);
        }
      } else if (bid >= 64 && bid < 128) {
        const int grp = bid - 64;
        grouped_gemm8(hprev, p.wdecG, 2048, 1024, grp, red_s, sg_s);
        {
          int slot = tid;
          int b = slot >> 4, jj = slot & 15, j = grp * 16 + jj;
          p.gatesH[(size_t)b * G_ + j]        = sg_s[b * 64 + jj];
          p.gatesH[(size_t)b * G_ + 1024 + j] = sg_s[b * 64 + 16 + jj];
          p.gatesH[(size_t)b * G_ + 2048 + j] = sg_s[b * 64 + 32 + jj];
          p.gatesH[(size_t)b * G_ + 3072 + j] = sg_s[b * 64 + 48 + jj];
        }
      }
      gbar(p.bar, ++bargen);
      // ---- phase B: comb-v (0..31) || logits[t-1] (32..223) || loss[t-2] (224..255) ----
      if (bid < 32) {
        comb8<1024, true>(p, bid, t, red_s);
      } else if (bid < 224) {
        if (t >= 1) {
          int task = (bid - 32) * 8 + (tid >> 6);   // 1536 waves >= 500 tasks
          if (task < 500)
            wave_gemm<1>(p.hall + (size_t)(t - 1) * 32 * 1024, p.wout, 1024, 0,
                         task * 64, p.out_b,
                         p.ring + (size_t)((t - 1) & 1) * 32 * V_, V_);
        }
      } else {
        if (t >= 2) {
          int b2 = bid - 224;
          loss_row_bf16<false>(p.ring + (size_t)((t - 2) & 1) * 32 * V_ + (size_t)b2 * V_,
                               p.target[(t - 2) * 32 + b2],
                               &p.loss_p[(t - 2) * 32 + b2], nullptr, red_s);
        }
      }
      gbar(p.bar, ++bargen);
      // ---- phase C: gates-x + LSTM (0..63) ----
      if (bid < 64) {
        grouped_gemm8(p.nbuf, p.wdecG, 2048, 0, bid, red_s, sg_s);
        {
          int slot = tid;
          int b = slot >> 4, jj = slot & 15, j = bid * 16 + jj;
          float g0 = sg_s[b * 64 + jj]      + p.gatesH[(size_t)b * G_ + j]        + p.dec_b[j];
          float g1 = sg_s[b * 64 + 16 + jj] + p.gatesH[(size_t)b * G_ + 1024 + j] + p.dec_b[1024 + j];
          float g2 = sg_s[b * 64 + 32 + jj] + p.gatesH[(size_t)b * G_ + 2048 + j] + p.dec_b[2048 + j];
          float g3 = sg_s[b * 64 + 48 + jj] + p.gatesH[(size_t)b * G_ + 3072 + j] + p.dec_b[3072 + j];
          float ig = sigf(g0), fg = sigf(g1), gg = tanhf(g2), og = sigf(g3);
          float cn = fg * p.cbuf[b * 1024 + j] + ig * gg;
          float hn = og * tanhf(cn);
          p.cbuf[b * 1024 + j] = cn;
          u16 hb2 = f2b(hn);
          hnext[b * 1024 + j] = hb2;
          p.hall[((size_t)t * 32 + b) * 1024 + j] = hb2;
        }
      }
      gbar(p.bar, ++bargen);
      pd ^= 1;
    }
    // ---- E1: logits[63] (32..223) || loss[62] (224..255) ----
    if (bid >= 32 && bid < 224) {
      int task = (bid - 32) * 8 + (tid >> 6);
      if (task < 500)
        wave_gemm<1>(p.hall + (size_t)63 * 32 * 1024, p.wout, 1024, 0, task * 64,
                     p.out_b, p.ring + (size_t)1 * 32 * V_, V_);
    } else if (bid >= 224) {
      int b2 = bid - 224;
      loss_row_bf16<false>(p.ring + (size_t)0 * 32 * V_ + (size_t)b2 * V_,
                           p.target[62 * 32 + b2], &p.loss_p[62 * 32 + b2], nullptr, red_s);
    }
    gbar(p.bar, ++bargen);
    // ---- E2: loss[63] ----
    if (bid < 32)
      loss_row_bf16<false>(p.ring + (size_t)1 * 32 * V_ + (size_t)bid * V_,
                           p.target[63 * 32 + bid], &p.loss_p[63 * 32 + bid], nullptr, red_s);
    gbar(p.bar, ++bargen);
  } else {
    // ---- tf=0: per-step feedback path (correct, not speed-critical) ----
    for (int t = 0; t < 64; ++t) {
      const u16* hprev = p.hbuf + (size_t)pd * B_ * H_;
      u16* hnext = p.hbuf + (size_t)(pd ^ 1) * B_ * H_;
      if (bid < 32) {
        float* xsh = red_s;            // 1024
        float* hsh = red_s + 1024;     // 1024
        float* ssc = red_s + 2048;     // 512
        float* aw  = red_s + 2560;     // 64
        const int b = bid;
        int tok = (t > 0) ? p.prevtok[b] : 0;
        {
          float2 v = *(const float2*)(p.dec_emb + (size_t)tok * 1024 + tid * 2);
          float x0 = fmaxf(v.x, 0.f), x1 = fmaxf(v.y, 0.f);
          xsh[tid * 2] = x0; xsh[tid * 2 + 1] = x1;
          *(ushort2*)(p.xb + (size_t)b * 1024 + tid * 2) = make_ushort2(f2b(x0), f2b(x1));
          ushort2 hq = *(const ushort2*)(hprev + (size_t)b * 1024 + tid * 2);
          hsh[tid * 2] = b2f(hq.x); hsh[tid * 2 + 1] = b2f(hq.y);
        }
        __syncthreads();
        {
          const int sidx = tid & 63, q = tid >> 6;   // 256-K chunk, q<4 x-part, q>=4 h-part
          const u16* wr = p.wattn + (size_t)sidx * 2048 + q * 256;
          const float* src = (q < 4) ? (xsh + q * 256) : (hsh + (q - 4) * 256);
          float acc = 0.f;
          for (int k8 = 0; k8 < 32; ++k8) {
            bf16x8 v = *(const bf16x8*)(wr + k8 * 8);
#pragma unroll
            for (int e = 0; e < 8; ++e)
              acc = fmaf(src[k8 * 8 + e], b2f((u16)v[e]), acc);
          }
          ssc[q * 64 + sidx] = acc;
        }
        __syncthreads();
        if (tid < 64) {
          float sc = p.attn_b[tid];
#pragma unroll
          for (int q = 0; q < 8; ++q) sc += ssc[q * 64 + tid];
          float m = sc;
#pragma unroll
          for (int off = 32; off; off >>= 1) m = fmaxf(m, __shfl_xor(m, off));
          float e = expf(sc - m), sum = e;
#pragma unroll
          for (int off = 32; off; off >>= 1) sum += __shfl_xor(sum, off);
          aw[tid] = e / sum;
        }
        __syncthreads();
        for (int j = tid; j < 1024; j += BT) {
          const u16* rowp = p.enc_bs + ((size_t)b * 1024 + j) * 64;
          float acc = 0.f;
#pragma unroll
          for (int s8 = 0; s8 < 8; ++s8) {
            bf16x8 v = *(const bf16x8*)(rowp + s8 * 8);
#pragma unroll
            for (int e = 0; e < 8; ++e)
              acc = fmaf(aw[s8 * 8 + e], b2f((u16)v[e]), acc);
          }
          p.vb[(size_t)b * 1024 + j] = f2b(acc);
        }
      } else if (bid >= 64 && bid < 128) {
        const int grp = bid - 64;
        grouped_gemm8(hprev, p.wdecG, 2048, 1024, grp, red_s, sg_s);
        {
          int slot = tid;
          int b = slot >> 4, jj = slot & 15, j = grp * 16 + jj;
          p.gatesH[(size_t)b * G_ + j]        = sg_s[b * 64 + jj];
          p.gatesH[(size_t)b * G_ + 1024 + j] = sg_s[b * 64 + 16 + jj];
          p.gatesH[(size_t)b * G_ + 2048 + j] = sg_s[b * 64 + 32 + jj];
          p.gatesH[(size_t)b * G_ + 3072 + j] = sg_s[b * 64 + 48 + jj];
        }
      }
      gbar(p.bar, ++bargen);
      if (bid < 32) comb8<2048, false>(p, bid, t, red_s);
      gbar(p.bar, ++bargen);
      if (bid < 64) {
        grouped_gemm8(p.nbuf, p.wdecG, 2048, 0, bid, red_s, sg_s);
        {
          int slot = tid;
          int b = slot >> 4, jj = slot & 15, j = bid * 16 + jj;
          float g0 = sg_s[b * 64 + jj]      + p.gatesH[(size_t)b * G_ + j]        + p.dec_b[j];
          float g1 = sg_s[b * 64 + 16 + jj] + p.gatesH[(size_t)b * G_ + 1024 + j] + p.dec_b[1024 + j];
          float g2 = sg_s[b * 64 + 32 + jj] + p.gatesH[(size_t)b * G_ + 2048 + j] + p.dec_b[2048 + j];
          float g3 = sg_s[b * 64 + 48 + jj] + p.gatesH[(size_t)b * G_ + 3072 + j] + p.dec_b[3072 + j];
          float ig = sigf(g0), fg = sigf(g1), gg = tanhf(g2), og = sigf(g3);
          float cn = fg * p.cbuf[b * 1024 + j] + ig * gg;
          float hn = og * tanhf(cn);
          p.cbuf[b * 1024 + j] = cn;
          u16 hb2 = f2b(hn);
          hnext[b * 1024 + j] = hb2;
          p.hall[((size_t)t * 32 + b) * 1024 + j] = hb2;
        }
      }
      gbar(p.bar, ++bargen);
      pd ^= 1;
      for (int task = gwid; task < 500; task += NWAVE)
        wave_gemm<1>(p.hbuf + (size_t)pd * B_ * H_, p.wout, 1024, 0, task * 64,
                     p.out_b, p.ring, V_);
      gbar(p.bar, ++bargen);
      if (bid < 32)
        loss_row_bf16<true>(p.ring + (size_t)bid * V_, p.target[t * 32 + bid],
                            &p.loss_p[t * 32 + bid], &p.prevtok[bid], red_s);
      gbar(p.bar, ++bargen);
    }
  }

  // ---------- final sum ----------
  if (bid == 0) {
    float a = 0.f;
    for (int i = tid; i < T_ * B_; i += BT) a += p.loss_p[i];
    red_s[tid] = a;
    __syncthreads();
    for (int off = 256; off; off >>= 1) {
      if (tid < off) red_s[tid] += red_s[tid + off];
      __syncthreads();
    }
    if (tid == 0) p.out[0] = red_s[0];
  }
}

// ---------------- host launch ----------------
extern "C" void kernel_launch(void* const* d_in, const int* in_sizes, int n_in,
                              void* d_out, int out_size, void* d_ws, size_t ws_size,
                              hipStream_t stream) {
  (void)in_sizes; (void)n_in; (void)out_size; (void)ws_size;
  Params p;
  p.input   = (const int*)d_in[0];
  p.target  = (const int*)d_in[1];
  p.use_tf  = (const int*)d_in[2];
  p.enc_emb = (const float*)d_in[3];
  p.enc_Wih = (const float*)d_in[4];
  p.enc_Whh = (const float*)d_in[5];
  p.enc_b   = (const float*)d_in[6];
  p.dec_emb = (const float*)d_in[7];
  p.dec_Wih = (const float*)d_in[8];
  p.dec_Whh = (const float*)d_in[9];
  p.dec_b   = (const float*)d_in[10];
  p.attn_W  = (const float*)d_in[11];
  p.attn_b  = (const float*)d_in[12];
  p.comb_W  = (const float*)d_in[13];
  p.comb_b  = (const float*)d_in[14];
  p.out_W   = (const float*)d_in[15];
  p.out_b   = (const float*)d_in[16];
  p.out     = (float*)d_out;

  char* ws = (char*)d_ws;
  size_t off = 0;
  auto alloc = [&](size_t bytes) {
    void* q = ws + off;
    off += ((bytes + 255) & ~(size_t)255);
    return q;
  };
  p.Xbf     = (u16*)alloc((size_t)S_ * B_ * H_ * 2);       // 4.2 MB
  p.encXbf  = (u16*)alloc((size_t)S_ * B_ * G_ * 2);       // 16.8 MB (dead after encoder; ring aliases)
  p.enc_bs  = (u16*)alloc((size_t)B_ * H_ * S_ * 2);       // 4.2 MB  [b][d][s]
  p.hall    = (u16*)alloc((size_t)T_ * B_ * H_ * 2);       // 4.2 MB
  p.hbuf    = (u16*)alloc((size_t)2 * B_ * H_ * 2);
  p.xb      = (u16*)alloc((size_t)B_ * H_ * 2);
  p.vb      = (u16*)alloc((size_t)B_ * H_ * 2);
  p.nbuf    = (u16*)alloc((size_t)B_ * H_ * 2);
  p.xball   = (u16*)alloc((size_t)T_ * B_ * H_ * 2);       // 4.2 MB
  p.combX   = (float*)alloc((size_t)T_ * B_ * H_ * 4);     // 8.4 MB
  p.scoreX  = (float*)alloc((size_t)T_ * B_ * 64 * 4);     // 0.5 MB
  p.gatesH  = (float*)alloc((size_t)B_ * G_ * 4);          // 0.5 MB
  p.cbuf    = (float*)alloc((size_t)B_ * H_ * 4);
  p.loss_p  = (float*)alloc((size_t)T_ * B_ * 4);
  p.prevtok = (int*)alloc(B_ * 4);
  p.bar     = (unsigned*)alloc(1024);
  p.wencWih = (u16*)alloc((size_t)G_ * H_ * 2);            // 8.4 MB
  p.wencWhh = (u16*)alloc((size_t)G_ * H_ * 2);            // 8.4 MB
  p.wdecG   = (u16*)alloc((size_t)G_ * 2 * H_ * 2);        // 16.8 MB
  p.wcomb   = (u16*)alloc((size_t)H_ * 2 * H_ * 2);        // 4.2 MB
  p.wattn   = (u16*)alloc((size_t)S_ * 2 * H_ * 2);        // 0.26 MB
  p.wout    = (u16*)alloc((size_t)V_ * H_ * 2);            // 65.5 MB
  // logits ring (2 x 32 x 32000 bf16 = 4.1 MB) aliases dead-after-encoder encXbf (16.8 MB)
  p.ring = p.encXbf;
  // total ~147 MB

  binit<<<1, 288, 0, stream>>>(p.bar);
  seq2seq_all<<<NB, BT, 0, stream>>>(p);
}

// Round 9
// 6399.253 us; speedup vs baseline: 2.7826x; 1.1895x over previous
//
#include <hip/hip_runtime.h>
#include <cmath>
#include <cstddef>

// S=T=64, B=32, H=1024, G=4H, V=32000
constexpr int S_ = 64, T_ = 64, B_ = 32, H_ = 1024, G_ = 4096, V_ = 32000;
constexpr int NB = 256, BT = 512, NTHR = NB * BT, NWAVE = NB * 8;

typedef unsigned short u16;   // bf16 bit pattern
typedef __attribute__((ext_vector_type(8))) short bf16x8;
typedef __attribute__((ext_vector_type(4))) float f32x4;

__device__ __forceinline__ float sigf(float x) { return 1.f / (1.f + expf(-x)); }
__device__ __forceinline__ float b2f(u16 u) { return __uint_as_float(((unsigned)u) << 16); }
__device__ __forceinline__ u16 f2b(float f) {
  unsigned u = __float_as_uint(f);
  return (u16)((u + 0x7fff + ((u >> 16) & 1)) >> 16);  // RNE
}
__device__ __forceinline__ f32x4 mfma16(bf16x8 a, bf16x8 b, f32x4 c) {
  return __builtin_amdgcn_mfma_f32_16x16x32_bf16(a, b, c, 0, 0, 0);
}

struct Params {
  const int *input, *target, *use_tf;
  const float *enc_emb, *enc_Wih, *enc_Whh, *enc_b;
  const float *dec_emb, *dec_Wih, *dec_Whh, *dec_b;
  const float *attn_W, *attn_b, *comb_W, *comb_b, *out_W, *out_b;
  float* out;
  u16 *Xbf, *encXbf, *enc_bs, *hall, *hbuf, *xb, *vb, *nbuf, *xball, *ring;
  float *combX, *scoreX, *gatesH, *cbuf, *loss_p;
  int* prevtok;
  u16 *wencWih, *wencWhh, *wdecG, *wcomb, *wattn, *wout;
  unsigned* bar;
};

// ---------- two-level device-scope grid barrier (256 arrivals, thread 0 only) ----------
__device__ __forceinline__ void gbar(unsigned* bar, unsigned target) {
  __syncthreads();
  if (threadIdx.x == 0) {
    __threadfence();
    int g = blockIdx.x >> 4;
    unsigned a = __hip_atomic_fetch_add(bar + g * 16, 1u, __ATOMIC_ACQ_REL,
                                        __HIP_MEMORY_SCOPE_AGENT);
    if (a == 15u) {
      unsigned r = __hip_atomic_fetch_add(bar + 256, 1u, __ATOMIC_ACQ_REL,
                                          __HIP_MEMORY_SCOPE_AGENT);
      if (r == 15u) {
        for (int i = 0; i < 16; ++i)
          __hip_atomic_store(bar + i * 16, 0u, __ATOMIC_RELAXED, __HIP_MEMORY_SCOPE_AGENT);
        __hip_atomic_store(bar + 256, 0u, __ATOMIC_RELAXED, __HIP_MEMORY_SCOPE_AGENT);
        __hip_atomic_store(bar + 272, target, __ATOMIC_RELEASE, __HIP_MEMORY_SCOPE_AGENT);
      }
    }
    while (__hip_atomic_load(bar + 272, __ATOMIC_ACQUIRE, __HIP_MEMORY_SCOPE_AGENT) < target)
      __builtin_amdgcn_s_sleep(2);
  }
  __syncthreads();
}

// ---------- per-wave 32x64 tile GEMM, K=1024 ----------
// EPI: 0 bf16, 1 bf16+bias, 2 f32, 3 f32+bias
template <int EPI>
__device__ void wave_gemm(const u16* __restrict__ A, const u16* __restrict__ W,
                          int ldw, int wkoff, int colbase, const float* __restrict__ bias,
                          void* __restrict__ outp, int ldo) {
  const int lane = threadIdx.x & 63;
  const int r = lane & 15, kg = (lane >> 4) * 8;
  const u16* Ar = A + (size_t)r * 1024 + kg;
  const u16* Wr = W + (size_t)(colbase + r) * ldw + wkoff + kg;
  f32x4 acc[2][4] = {};
#pragma unroll 2
  for (int k0 = 0; k0 < 1024; k0 += 32) {
    bf16x8 a0 = *(const bf16x8*)(Ar + k0);
    bf16x8 a1 = *(const bf16x8*)(Ar + 16 * 1024 + k0);
    bf16x8 b0 = *(const bf16x8*)(Wr + k0);
    bf16x8 b1 = *(const bf16x8*)(Wr + (size_t)16 * ldw + k0);
    bf16x8 b2 = *(const bf16x8*)(Wr + (size_t)32 * ldw + k0);
    bf16x8 b3 = *(const bf16x8*)(Wr + (size_t)48 * ldw + k0);
    acc[0][0] = mfma16(a0, b0, acc[0][0]);
    acc[1][0] = mfma16(a1, b0, acc[1][0]);
    acc[0][1] = mfma16(a0, b1, acc[0][1]);
    acc[1][1] = mfma16(a1, b1, acc[1][1]);
    acc[0][2] = mfma16(a0, b2, acc[0][2]);
    acc[1][2] = mfma16(a1, b2, acc[1][2]);
    acc[0][3] = mfma16(a0, b3, acc[0][3]);
    acc[1][3] = mfma16(a1, b3, acc[1][3]);
  }
#pragma unroll
  for (int mi = 0; mi < 2; ++mi)
#pragma unroll
    for (int nj = 0; nj < 4; ++nj) {
      int col = colbase + nj * 16 + (lane & 15);
      int row0 = mi * 16 + ((lane >> 4) << 2);
#pragma unroll
      for (int reg = 0; reg < 4; ++reg) {
        float v = acc[mi][nj][reg];
        if (EPI == 1 || EPI == 3) v += bias[col];
        if (EPI <= 1) ((u16*)outp)[(size_t)(row0 + reg) * ldo + col] = f2b(v);
        else ((float*)outp)[(size_t)(row0 + reg) * ldo + col] = v;
      }
    }
}

// ---------- block 32x64 grouped-col GEMM: 8-wave K-split (KSW=128) -> sg[32][64] ----------
__device__ void grouped_gemm8(const u16* __restrict__ A, const u16* __restrict__ Wm,
                              int ldw, int wkoff, int grp, float* red, float* sg) {
  const int tid = threadIdx.x, w = tid >> 6, lane = tid & 63;
  const int r = lane & 15, kg = (lane >> 4) * 8;
  const int kw0 = w * 128;
  const u16* Ar = A + (size_t)r * 1024 + kw0 + kg;
  const u16* W0 = Wm + (size_t)(grp * 16 + r) * ldw + wkoff + kw0 + kg;
  const u16* W1 = W0 + (size_t)1024 * ldw;
  const u16* W2 = W0 + (size_t)2048 * ldw;
  const u16* W3 = W0 + (size_t)3072 * ldw;
  f32x4 acc[2][4] = {};
#pragma unroll
  for (int k0 = 0; k0 < 128; k0 += 32) {
    bf16x8 a0 = *(const bf16x8*)(Ar + k0);
    bf16x8 a1 = *(const bf16x8*)(Ar + 16 * 1024 + k0);
    bf16x8 b0 = *(const bf16x8*)(W0 + k0);
    bf16x8 b1 = *(const bf16x8*)(W1 + k0);
    bf16x8 b2 = *(const bf16x8*)(W2 + k0);
    bf16x8 b3 = *(const bf16x8*)(W3 + k0);
    acc[0][0] = mfma16(a0, b0, acc[0][0]);
    acc[1][0] = mfma16(a1, b0, acc[1][0]);
    acc[0][1] = mfma16(a0, b1, acc[0][1]);
    acc[1][1] = mfma16(a1, b1, acc[1][1]);
    acc[0][2] = mfma16(a0, b2, acc[0][2]);
    acc[1][2] = mfma16(a1, b2, acc[1][2]);
    acc[0][3] = mfma16(a0, b3, acc[0][3]);
    acc[1][3] = mfma16(a1, b3, acc[1][3]);
  }
#pragma unroll
  for (int mi = 0; mi < 2; ++mi)
#pragma unroll
    for (int nj = 0; nj < 4; ++nj)
#pragma unroll
      for (int reg = 0; reg < 4; ++reg)
        red[(((w * 8) + mi * 4 + nj) * 64 + lane) * 4 + reg] = acc[mi][nj][reg];
  __syncthreads();
  {
    const int p2 = w;
    const int mi = p2 >> 2, nj = p2 & 3;
#pragma unroll
    for (int reg = 0; reg < 4; ++reg) {
      float v = 0.f;
#pragma unroll
      for (int ww = 0; ww < 8; ++ww)
        v += red[(((ww * 8) + p2) * 64 + lane) * 4 + reg];
      sg[(mi * 16 + ((lane >> 4) << 2) + reg) * 64 + nj * 16 + (lane & 15)] = v;
    }
  }
  __syncthreads();
}

// ---------- comb: 32-col tile per block, 8-wave K-split; +combX(optional)+bias, relu -> nbuf ----------
template <int KTOT, bool HASX>
__device__ void comb8(const Params& p, int cb, int t, float* red) {
  const int tid = threadIdx.x, w = tid >> 6, lane = tid & 63;
  const int r = lane & 15, kg = (lane >> 4) * 8;
  constexpr int KSW = KTOT / 8;
  const int kw0 = w * KSW;
  const u16* Abase;
  int koff;
  if (KTOT == 2048) { Abase = (kw0 < 1024) ? p.xb : p.vb; koff = kw0 & 1023; }
  else { Abase = p.vb; koff = kw0; }
  const u16* Ar = Abase + (size_t)r * 1024 + koff + kg;
  const int wko = (KTOT == 1024) ? 1024 : 0;
  const u16* W0 = p.wcomb + (size_t)(cb * 32 + r) * 2048 + wko + kw0 + kg;
  const u16* W1 = W0 + (size_t)16 * 2048;
  f32x4 acc[2][2] = {};
#pragma unroll
  for (int k0 = 0; k0 < KSW; k0 += 32) {
    bf16x8 a0 = *(const bf16x8*)(Ar + k0);
    bf16x8 a1 = *(const bf16x8*)(Ar + 16 * 1024 + k0);
    bf16x8 b0 = *(const bf16x8*)(W0 + k0);
    bf16x8 b1 = *(const bf16x8*)(W1 + k0);
    acc[0][0] = mfma16(a0, b0, acc[0][0]);
    acc[1][0] = mfma16(a1, b0, acc[1][0]);
    acc[0][1] = mfma16(a0, b1, acc[0][1]);
    acc[1][1] = mfma16(a1, b1, acc[1][1]);
  }
#pragma unroll
  for (int mi = 0; mi < 2; ++mi)
#pragma unroll
    for (int nj = 0; nj < 2; ++nj)
#pragma unroll
      for (int reg = 0; reg < 4; ++reg)
        red[(((w * 4) + mi * 2 + nj) * 64 + lane) * 4 + reg] = acc[mi][nj][reg];
  __syncthreads();
  if (w < 4) {
    const int p2 = w, mi = p2 >> 1, nj = p2 & 1;
#pragma unroll
    for (int reg = 0; reg < 4; ++reg) {
      float v = 0.f;
#pragma unroll
      for (int ww = 0; ww < 8; ++ww)
        v += red[(((ww * 4) + p2) * 64 + lane) * 4 + reg];
      int row = mi * 16 + ((lane >> 4) << 2) + reg;
      int col = cb * 32 + nj * 16 + (lane & 15);
      if (HASX) v += p.combX[(size_t)(t * 32 + row) * 1024 + col];
      v += p.comb_b[col];
      p.nbuf[(size_t)row * 1024 + col] = f2b(fmaxf(v, 0.f));
    }
  }
  __syncthreads();
}

// ---------- log-softmax loss over one bf16 logits row (512 threads) ----------
template <bool AM>
__device__ void loss_row_bf16(const u16* __restrict__ row, int tgt,
                              float* __restrict__ loss_out, int* __restrict__ am_out,
                              float* sh) {
  float* sm = sh;
  float* ss = sh + 512;
  float* sbv = sh + 1024;
  int* sbi = (int*)(sh + 1536);
  const int tid = threadIdx.x;
  float m = -INFINITY, ssum = 0.f, bestv = -INFINITY;
  int besti = 0x7fffffff;
  for (int v = tid; v < V_; v += BT) {
    float x = b2f(row[v]);
    if (x > m) { ssum = ssum * expf(m - x) + 1.f; m = x; }
    else ssum += expf(x - m);
    if (AM) { if (x > bestv) { bestv = x; besti = v; } }
  }
  sm[tid] = m; ss[tid] = ssum;
  if (AM) { sbv[tid] = bestv; sbi[tid] = besti; }
  __syncthreads();
  for (int off = 256; off; off >>= 1) {
    if (tid < off) {
      float m2 = sm[tid + off], s2 = ss[tid + off];
      float mn = fmaxf(sm[tid], m2);
      ss[tid] = ss[tid] * expf(sm[tid] - mn) + s2 * expf(m2 - mn);
      sm[tid] = mn;
      if (AM) {
        float bv2 = sbv[tid + off];
        int bi2 = sbi[tid + off];
        if (bv2 > sbv[tid] || (bv2 == sbv[tid] && bi2 < sbi[tid])) { sbv[tid] = bv2; sbi[tid] = bi2; }
      }
    }
    __syncthreads();
  }
  if (tid == 0) {
    float lp = b2f(row[tgt]) - (sm[0] + logf(ss[0]));
    *loss_out = -lp * (1.f / 32.f);
    if (AM) *am_out = sbi[0];
  }
  __syncthreads();
}

// =================== main persistent kernel ===================
__global__ void binit(unsigned* bar) {
  int i = threadIdx.x;
  if (i < 288) bar[i] = 0u;
}

__global__ __launch_bounds__(BT) void seq2seq_all(Params p) {
  __shared__ float red_s[16384];   // 64 KB
  __shared__ float sg_s[2048];     // 8 KB
  unsigned bargen = 0;
  const int tid = threadIdx.x, bid = blockIdx.x;
  const int gtid = bid * BT + tid;
  const int gwid = bid * 8 + (tid >> 6);
  const int utf = p.use_tf[0];

  // ---------- phase 0: zero state + weight conversions + gathers ----------
  for (int i = gtid; i < B_ * H_; i += NTHR) { p.cbuf[i] = 0.f; p.hbuf[i] = 0; }
  for (int i = gtid; i < G_ * H_ / 4; i += NTHR) {
    float4 v = *(const float4*)(p.enc_Wih + (size_t)i * 4);
    *(ushort4*)(p.wencWih + (size_t)i * 4) = make_ushort4(f2b(v.x), f2b(v.y), f2b(v.z), f2b(v.w));
  }
  for (int i = gtid; i < G_ * H_ / 4; i += NTHR) {
    float4 v = *(const float4*)(p.enc_Whh + (size_t)i * 4);
    *(ushort4*)(p.wencWhh + (size_t)i * 4) = make_ushort4(f2b(v.x), f2b(v.y), f2b(v.z), f2b(v.w));
  }
  for (int i = gtid; i < 2 * H_ * H_ / 4; i += NTHR) {
    float4 v = *(const float4*)(p.comb_W + (size_t)i * 4);
    *(ushort4*)(p.wcomb + (size_t)i * 4) = make_ushort4(f2b(v.x), f2b(v.y), f2b(v.z), f2b(v.w));
  }
  for (int i = gtid; i < S_ * 2 * H_ / 4; i += NTHR) {
    float4 v = *(const float4*)(p.attn_W + (size_t)i * 4);
    *(ushort4*)(p.wattn + (size_t)i * 4) = make_ushort4(f2b(v.x), f2b(v.y), f2b(v.z), f2b(v.w));
  }
  for (int i = gtid; i < V_ * H_ / 4; i += NTHR) {
    float4 v = *(const float4*)(p.out_W + (size_t)i * 4);
    *(ushort4*)(p.wout + (size_t)i * 4) = make_ushort4(f2b(v.x), f2b(v.y), f2b(v.z), f2b(v.w));
  }
  for (int i = gtid; i < G_ * 512; i += NTHR) {   // [dec_Wih | dec_Whh]
    int n = i >> 9, k4 = (i & 511) * 4;
    const float* src = (k4 < 1024) ? (p.dec_Wih + (size_t)n * 1024 + k4)
                                   : (p.dec_Whh + (size_t)n * 1024 + (k4 - 1024));
    float4 v = *(const float4*)src;
    *(ushort4*)(p.wdecG + (size_t)n * 2048 + k4) = make_ushort4(f2b(v.x), f2b(v.y), f2b(v.z), f2b(v.w));
  }
  for (int i = gtid; i < S_ * B_ * 256; i += NTHR) {   // encoder embedding gather
    int m = i >> 8, k4 = (i & 255) * 4;
    float4 v = *(const float4*)(p.enc_emb + (size_t)p.input[m] * 1024 + k4);
    *(ushort4*)(p.Xbf + (size_t)m * 1024 + k4) = make_ushort4(f2b(v.x), f2b(v.y), f2b(v.z), f2b(v.w));
  }
  for (int i = gtid; i < T_ * B_ * 256; i += NTHR) {   // teacher-forced decoder x (relu)
    int m = i >> 8, k4 = (i & 255) * 4;
    int t = m >> 5, b = m & 31;
    int tok = (t == 0) ? 0 : p.target[(t - 1) * 32 + b];
    float4 v = *(const float4*)(p.dec_emb + (size_t)tok * 1024 + k4);
    *(ushort4*)(p.xball + (size_t)m * 1024 + k4) =
        make_ushort4(f2b(fmaxf(v.x, 0.f)), f2b(fmaxf(v.y, 0.f)),
                     f2b(fmaxf(v.z, 0.f)), f2b(fmaxf(v.w, 0.f)));
  }
  gbar(p.bar, ++bargen);

  // ---------- phase 1: batched GEMMs: encX (4096) | combX (1024) | scoreX (64) ----------
  for (int task = gwid; task < 4096 + 1024 + 64; task += NWAVE) {
    if (task < 4096) {
      int mt = task >> 6, ct = task & 63;
      wave_gemm<0>(p.Xbf + (size_t)mt * 32 * 1024, p.wencWih, 1024, 0, ct * 64,
                   nullptr, p.encXbf + (size_t)mt * 32 * G_, G_);
    } else if (task < 5120) {
      int tt = task - 4096, mt = tt >> 4, ct = tt & 15;
      wave_gemm<2>(p.xball + (size_t)mt * 32 * 1024, p.wcomb, 2048, 0, ct * 64,
                   nullptr, p.combX + (size_t)mt * 32 * 1024, 1024);
    } else {
      int mt = task - 5120;
      wave_gemm<3>(p.xball + (size_t)mt * 32 * 1024, p.wattn, 2048, 0, 0,
                   p.attn_b, p.scoreX + (size_t)mt * 32 * 64, 64);
    }
  }
  gbar(p.bar, ++bargen);

  // ---------- phase 2: encoder, 1 barrier/step ----------
  int pe = 0;
  for (int s = 0; s < 64; ++s) {
    if (bid < 64) {
      const u16* hprev = p.hbuf + (size_t)pe * B_ * H_;
      u16* hnext = p.hbuf + (size_t)(pe ^ 1) * B_ * H_;
      grouped_gemm8(hprev, p.wencWhh, 1024, 0, bid, red_s, sg_s);
      {
        int slot = tid;
        int b = slot >> 4, jj = slot & 15, j = bid * 16 + jj;
        size_t xo = (size_t)(s * 32 + b) * G_;
        float g0 = sg_s[b * 64 + jj]      + b2f(p.encXbf[xo + j])        + p.enc_b[j];
        float g1 = sg_s[b * 64 + 16 + jj] + b2f(p.encXbf[xo + 1024 + j]) + p.enc_b[1024 + j];
        float g2 = sg_s[b * 64 + 32 + jj] + b2f(p.encXbf[xo + 2048 + j]) + p.enc_b[2048 + j];
        float g3 = sg_s[b * 64 + 48 + jj] + b2f(p.encXbf[xo + 3072 + j]) + p.enc_b[3072 + j];
        float ig = sigf(g0), fg = sigf(g1), gg = tanhf(g2), og = sigf(g3);
        float cn = fg * p.cbuf[b * 1024 + j] + ig * gg;
        float hn = og * tanhf(cn);
        p.cbuf[b * 1024 + j] = cn;
        u16 hb2 = f2b(hn);
        hnext[b * 1024 + j] = hb2;
        p.enc_bs[((size_t)b * 1024 + j) * 64 + s] = hb2;
      }
    }
    pe ^= 1;
    gbar(p.bar, ++bargen);
  }

  // ---------- phase 3: decoder ----------
  int pd = pe;   // == 0
  if (utf) {
    for (int t = 0; t < 64; ++t) {
      const u16* hprev = p.hbuf + (size_t)pd * B_ * H_;
      u16* hnext = p.hbuf + (size_t)(pd ^ 1) * B_ * H_;
      const bool batch = ((t & 7) == 0) && (t > 0);   // grid-uniform
      // ---- phase A: attention h-part (0..31) || gatesH (64..127) ----
      if (bid < 32) {
        float* hsh = red_s;            // 1024
        float* ssc = red_s + 1024;     // 512
        float* aw  = red_s + 1536;     // 64
        const int b = bid;
        {
          ushort2 hq = *(const ushort2*)(hprev + (size_t)b * 1024 + tid * 2);
          hsh[tid * 2] = b2f(hq.x);
          hsh[tid * 2 + 1] = b2f(hq.y);
        }
        __syncthreads();
        {
          const int sidx = tid & 63, q = tid >> 6;
          const u16* wr = p.wattn + (size_t)sidx * 2048 + 1024 + q * 128;
          const float* src = hsh + q * 128;
          float acc = 0.f;
          for (int k8 = 0; k8 < 16; ++k8) {
            bf16x8 v = *(const bf16x8*)(wr + k8 * 8);
#pragma unroll
            for (int e = 0; e < 8; ++e)
              acc = fmaf(src[k8 * 8 + e], b2f((u16)v[e]), acc);
          }
          ssc[q * 64 + sidx] = acc;
        }
        __syncthreads();
        if (tid < 64) {
          float sc = p.scoreX[(size_t)(t * 32 + b) * 64 + tid];
#pragma unroll
          for (int q = 0; q < 8; ++q) sc += ssc[q * 64 + tid];
          float m = sc;
#pragma unroll
          for (int off = 32; off; off >>= 1) m = fmaxf(m, __shfl_xor(m, off));
          float e = expf(sc - m), sum = e;
#pragma unroll
          for (int off = 32; off; off >>= 1) sum += __shfl_xor(sum, off);
          aw[tid] = e / sum;
        }
        __syncthreads();
        for (int j = tid; j < 1024; j += BT) {
          const u16* rowp = p.enc_bs + ((size_t)b * 1024 + j) * 64;
          float acc = 0.f;
#pragma unroll
          for (int s8 = 0; s8 < 8; ++s8) {
            bf16x8 v = *(const bf16x8*)(rowp + s8 * 8);
#pragma unroll
            for (int e = 0; e < 8; ++e)
              acc = fmaf(aw[s8 * 8 + e], b2f((u16)v[e]), acc);
          }
          p.vb[(size_t)b * 1024 + j] = f2b(acc);
        }
      } else if (bid >= 64 && bid < 128) {
        const int grp = bid - 64;
        grouped_gemm8(hprev, p.wdecG, 2048, 1024, grp, red_s, sg_s);
        {
          int slot = tid;
          int b = slot >> 4, jj = slot & 15, j = grp * 16 + jj;
          p.gatesH[(size_t)b * G_ + j]        = sg_s[b * 64 + jj];
          p.gatesH[(size_t)b * G_ + 1024 + j] = sg_s[b * 64 + 16 + jj];
          p.gatesH[(size_t)b * G_ + 2048 + j] = sg_s[b * 64 + 32 + jj];
          p.gatesH[(size_t)b * G_ + 3072 + j] = sg_s[b * 64 + 48 + jj];
        }
      }
      gbar(p.bar, ++bargen);
      // ---- phase B: comb-v (0..31) || batched logits for h[t-8..t-1] (32..255, every 8th step) ----
      if (bid < 32) {
        comb8<1024, true>(p, bid, t, red_s);
      } else if (batch) {
        const u16* Abase = p.hall + (size_t)(t - 8) * 32 * 1024;
        for (int task = (bid - 32) * 8 + (tid >> 6); task < 4000; task += 224 * 8) {
          int ct = task >> 3, mt = task & 7;
          wave_gemm<1>(Abase + (size_t)mt * 32 * 1024, p.wout, 1024, 0, ct * 64,
                       p.out_b, p.ring + (size_t)mt * 32 * V_, V_);
        }
      }
      gbar(p.bar, ++bargen);
      // ---- phase C: gates-x + LSTM (0..63) || batch loss (64..191, every 8th step) ----
      if (bid < 64) {
        grouped_gemm8(p.nbuf, p.wdecG, 2048, 0, bid, red_s, sg_s);
        {
          int slot = tid;
          int b = slot >> 4, jj = slot & 15, j = bid * 16 + jj;
          float g0 = sg_s[b * 64 + jj]      + p.gatesH[(size_t)b * G_ + j]        + p.dec_b[j];
          float g1 = sg_s[b * 64 + 16 + jj] + p.gatesH[(size_t)b * G_ + 1024 + j] + p.dec_b[1024 + j];
          float g2 = sg_s[b * 64 + 32 + jj] + p.gatesH[(size_t)b * G_ + 2048 + j] + p.dec_b[2048 + j];
          float g3 = sg_s[b * 64 + 48 + jj] + p.gatesH[(size_t)b * G_ + 3072 + j] + p.dec_b[3072 + j];
          float ig = sigf(g0), fg = sigf(g1), gg = tanhf(g2), og = sigf(g3);
          float cn = fg * p.cbuf[b * 1024 + j] + ig * gg;
          float hn = og * tanhf(cn);
          p.cbuf[b * 1024 + j] = cn;
          u16 hb2 = f2b(hn);
          hnext[b * 1024 + j] = hb2;
          p.hall[((size_t)t * 32 + b) * 1024 + j] = hb2;
        }
      } else if (bid >= 64 && bid < 192 && batch) {
        int base = (bid - 64) * 2;
        for (int rr = 0; rr < 2; ++rr) {
          int m = base + rr, gm = (t - 8) * 32 + m;
          loss_row_bf16<false>(p.ring + (size_t)m * V_, p.target[gm], &p.loss_p[gm],
                               nullptr, red_s);
        }
      }
      gbar(p.bar, ++bargen);
      pd ^= 1;
    }
    // ---- E1: batched logits for h[56..63] on all 256 blocks ----
    {
      const u16* Abase = p.hall + (size_t)56 * 32 * 1024;
      for (int task = bid * 8 + (tid >> 6); task < 4000; task += 2048) {
        int ct = task >> 3, mt = task & 7;
        wave_gemm<1>(Abase + (size_t)mt * 32 * 1024, p.wout, 1024, 0, ct * 64,
                     p.out_b, p.ring + (size_t)mt * 32 * V_, V_);
      }
    }
    gbar(p.bar, ++bargen);
    // ---- E2: loss rows 1792..2047 on blocks 0..127 ----
    if (bid < 128) {
      for (int rr = 0; rr < 2; ++rr) {
        int m = bid * 2 + rr, gm = 56 * 32 + m;
        loss_row_bf16<false>(p.ring + (size_t)m * V_, p.target[gm], &p.loss_p[gm],
                             nullptr, red_s);
      }
    }
    gbar(p.bar, ++bargen);
  } else {
    // ---- tf=0: per-step feedback path (correct, not speed-critical) ----
    for (int t = 0; t < 64; ++t) {
      const u16* hprev = p.hbuf + (size_t)pd * B_ * H_;
      u16* hnext = p.hbuf + (size_t)(pd ^ 1) * B_ * H_;
      if (bid < 32) {
        float* xsh = red_s;
        float* hsh = red_s + 1024;
        float* ssc = red_s + 2048;
        float* aw  = red_s + 2560;
        const int b = bid;
        int tok = (t > 0) ? p.prevtok[b] : 0;
        {
          float2 v = *(const float2*)(p.dec_emb + (size_t)tok * 1024 + tid * 2);
          float x0 = fmaxf(v.x, 0.f), x1 = fmaxf(v.y, 0.f);
          xsh[tid * 2] = x0; xsh[tid * 2 + 1] = x1;
          *(ushort2*)(p.xb + (size_t)b * 1024 + tid * 2) = make_ushort2(f2b(x0), f2b(x1));
          ushort2 hq = *(const ushort2*)(hprev + (size_t)b * 1024 + tid * 2);
          hsh[tid * 2] = b2f(hq.x); hsh[tid * 2 + 1] = b2f(hq.y);
        }
        __syncthreads();
        {
          const int sidx = tid & 63, q = tid >> 6;
          const u16* wr = p.wattn + (size_t)sidx * 2048 + q * 256;
          const float* src = (q < 4) ? (xsh + q * 256) : (hsh + (q - 4) * 256);
          float acc = 0.f;
          for (int k8 = 0; k8 < 32; ++k8) {
            bf16x8 v = *(const bf16x8*)(wr + k8 * 8);
#pragma unroll
            for (int e = 0; e < 8; ++e)
              acc = fmaf(src[k8 * 8 + e], b2f((u16)v[e]), acc);
          }
          ssc[q * 64 + sidx] = acc;
        }
        __syncthreads();
        if (tid < 64) {
          float sc = p.attn_b[tid];
#pragma unroll
          for (int q = 0; q < 8; ++q) sc += ssc[q * 64 + tid];
          float m = sc;
#pragma unroll
          for (int off = 32; off; off >>= 1) m = fmaxf(m, __shfl_xor(m, off));
          float e = expf(sc - m), sum = e;
#pragma unroll
          for (int off = 32; off; off >>= 1) sum += __shfl_xor(sum, off);
          aw[tid] = e / sum;
        }
        __syncthreads();
        for (int j = tid; j < 1024; j += BT) {
          const u16* rowp = p.enc_bs + ((size_t)b * 1024 + j) * 64;
          float acc = 0.f;
#pragma unroll
          for (int s8 = 0; s8 < 8; ++s8) {
            bf16x8 v = *(const bf16x8*)(rowp + s8 * 8);
#pragma unroll
            for (int e = 0; e < 8; ++e)
              acc = fmaf(aw[s8 * 8 + e], b2f((u16)v[e]), acc);
          }
          p.vb[(size_t)b * 1024 + j] = f2b(acc);
        }
      } else if (bid >= 64 && bid < 128) {
        const int grp = bid - 64;
        grouped_gemm8(hprev, p.wdecG, 2048, 1024, grp, red_s, sg_s);
        {
          int slot = tid;
          int b = slot >> 4, jj = slot & 15, j = grp * 16 + jj;
          p.gatesH[(size_t)b * G_ + j]        = sg_s[b * 64 + jj];
          p.gatesH[(size_t)b * G_ + 1024 + j] = sg_s[b * 64 + 16 + jj];
          p.gatesH[(size_t)b * G_ + 2048 + j] = sg_s[b * 64 + 32 + jj];
          p.gatesH[(size_t)b * G_ + 3072 + j] = sg_s[b * 64 + 48 + jj];
        }
      }
      gbar(p.bar, ++bargen);
      if (bid < 32) comb8<2048, false>(p, bid, t, red_s);
      gbar(p.bar, ++bargen);
      if (bid < 64) {
        grouped_gemm8(p.nbuf, p.wdecG, 2048, 0, bid, red_s, sg_s);
        {
          int slot = tid;
          int b = slot >> 4, jj = slot & 15, j = bid * 16 + jj;
          float g0 = sg_s[b * 64 + jj]      + p.gatesH[(size_t)b * G_ + j]        + p.dec_b[j];
          float g1 = sg_s[b * 64 + 16 + jj] + p.gatesH[(size_t)b * G_ + 1024 + j] + p.dec_b[1024 + j];
          float g2 = sg_s[b * 64 + 32 + jj] + p.gatesH[(size_t)b * G_ + 2048 + j] + p.dec_b[2048 + j];
          float g3 = sg_s[b * 64 + 48 + jj] + p.gatesH[(size_t)b * G_ + 3072 + j] + p.dec_b[3072 + j];
          float ig = sigf(g0), fg = sigf(g1), gg = tanhf(g2), og = sigf(g3);
          float cn = fg * p.cbuf[b * 1024 + j] + ig * gg;
          float hn = og * tanhf(cn);
          p.cbuf[b * 1024 + j] = cn;
          u16 hb2 = f2b(hn);
          hnext[b * 1024 + j] = hb2;
          p.hall[((size_t)t * 32 + b) * 1024 + j] = hb2;
        }
      }
      gbar(p.bar, ++bargen);
      pd ^= 1;
      for (int task = gwid; task < 500; task += NWAVE)
        wave_gemm<1>(p.hbuf + (size_t)pd * B_ * H_, p.wout, 1024, 0, task * 64,
                     p.out_b, p.ring, V_);
      gbar(p.bar, ++bargen);
      if (bid < 32)
        loss_row_bf16<true>(p.ring + (size_t)bid * V_, p.target[t * 32 + bid],
                            &p.loss_p[t * 32 + bid], &p.prevtok[bid], red_s);
      gbar(p.bar, ++bargen);
    }
  }

  // ---------- final sum ----------
  if (bid == 0) {
    float a = 0.f;
    for (int i = tid; i < T_ * B_; i += BT) a += p.loss_p[i];
    red_s[tid] = a;
    __syncthreads();
    for (int off = 256; off; off >>= 1) {
      if (tid < off) red_s[tid] += red_s[tid + off];
      __syncthreads();
    }
    if (tid == 0) p.out[0] = red_s[0];
  }
}

// ---------------- host launch ----------------
extern "C" void kernel_launch(void* const* d_in, const int* in_sizes, int n_in,
                              void* d_out, int out_size, void* d_ws, size_t ws_size,
                              hipStream_t stream) {
  (void)in_sizes; (void)n_in; (void)out_size; (void)ws_size;
  Params p;
  p.input   = (const int*)d_in[0];
  p.target  = (const int*)d_in[1];
  p.use_tf  = (const int*)d_in[2];
  p.enc_emb = (const float*)d_in[3];
  p.enc_Wih = (const float*)d_in[4];
  p.enc_Whh = (const float*)d_in[5];
  p.enc_b   = (const float*)d_in[6];
  p.dec_emb = (const float*)d_in[7];
  p.dec_Wih = (const float*)d_in[8];
  p.dec_Whh = (const float*)d_in[9];
  p.dec_b   = (const float*)d_in[10];
  p.attn_W  = (const float*)d_in[11];
  p.attn_b  = (const float*)d_in[12];
  p.comb_W  = (const float*)d_in[13];
  p.comb_b  = (const float*)d_in[14];
  p.out_W   = (const float*)d_in[15];
  p.out_b   = (const float*)d_in[16];
  p.out     = (float*)d_out;

  char* ws = (char*)d_ws;
  size_t off = 0;
  auto alloc = [&](size_t bytes) {
    void* q = ws + off;
    off += ((bytes + 255) & ~(size_t)255);
    return q;
  };
  p.Xbf     = (u16*)alloc((size_t)S_ * B_ * H_ * 2);       // 4.2 MB
  p.encXbf  = (u16*)alloc((size_t)S_ * B_ * G_ * 2);       // 16.8 MB (dead after encoder; ring aliases)
  p.enc_bs  = (u16*)alloc((size_t)B_ * H_ * S_ * 2);       // 4.2 MB
  p.hall    = (u16*)alloc((size_t)T_ * B_ * H_ * 2);       // 4.2 MB
  p.hbuf    = (u16*)alloc((size_t)2 * B_ * H_ * 2);
  p.xb      = (u16*)alloc((size_t)B_ * H_ * 2);
  p.vb      = (u16*)alloc((size_t)B_ * H_ * 2);
  p.nbuf    = (u16*)alloc((size_t)B_ * H_ * 2);
  p.xball   = (u16*)alloc((size_t)T_ * B_ * H_ * 2);       // 4.2 MB
  p.combX   = (float*)alloc((size_t)T_ * B_ * H_ * 4);     // 8.4 MB
  p.scoreX  = (float*)alloc((size_t)T_ * B_ * 64 * 4);     // 0.5 MB
  p.gatesH  = (float*)alloc((size_t)B_ * G_ * 4);          // 0.5 MB
  p.cbuf    = (float*)alloc((size_t)B_ * H_ * 4);
  p.loss_p  = (float*)alloc((size_t)T_ * B_ * 4);
  p.prevtok = (int*)alloc(B_ * 4);
  p.bar     = (unsigned*)alloc(1024);
  p.wencWih = (u16*)alloc((size_t)G_ * H_ * 2);            // 8.4 MB
  p.wencWhh = (u16*)alloc((size_t)G_ * H_ * 2);            // 8.4 MB
  p.wdecG   = (u16*)alloc((size_t)G_ * 2 * H_ * 2);        // 16.8 MB
  p.wcomb   = (u16*)alloc((size_t)H_ * 2 * H_ * 2);        // 4.2 MB
  p.wattn   = (u16*)alloc((size_t)S_ * 2 * H_ * 2);        // 0.26 MB
  p.wout    = (u16*)alloc((size_t)V_ * H_ * 2);            // 65.5 MB
  // logits ring: 256 rows x 32000 bf16 = 16.38 MB, aliases dead-after-encoder encXbf (16.8 MB)
  p.ring = p.encXbf;
  // total ~147 MB

  binit<<<1, 288, 0, stream>>>(p.bar);
  seq2seq_all<<<NB, BT, 0, stream>>>(p);
}

// Round 10
// 5771.775 us; speedup vs baseline: 3.0851x; 1.1087x over previous
//
#include <hip/hip_runtime.h>
#include <cmath>
#include <cstddef>

// S=T=64, B=32, H=1024, G=4H, V=32000
constexpr int S_ = 64, T_ = 64, B_ = 32, H_ = 1024, G_ = 4096, V_ = 32000;
constexpr int NB = 256, BT = 512, NTHR = NB * BT, NWAVE = NB * 8;

typedef unsigned short u16;   // bf16 bit pattern
typedef __attribute__((ext_vector_type(8))) short bf16x8;
typedef __attribute__((ext_vector_type(4))) float f32x4;

__device__ __forceinline__ float sigf(float x) { return 1.f / (1.f + expf(-x)); }
__device__ __forceinline__ float b2f(u16 u) { return __uint_as_float(((unsigned)u) << 16); }
__device__ __forceinline__ u16 f2b(float f) {
  unsigned u = __float_as_uint(f);
  return (u16)((u + 0x7fff + ((u >> 16) & 1)) >> 16);  // RNE
}
__device__ __forceinline__ f32x4 mfma16(bf16x8 a, bf16x8 b, f32x4 c) {
  return __builtin_amdgcn_mfma_f32_16x16x32_bf16(a, b, c, 0, 0, 0);
}

struct Params {
  const int *input, *target, *use_tf;
  const float *enc_emb, *enc_Wih, *enc_Whh, *enc_b;
  const float *dec_emb, *dec_Wih, *dec_Whh, *dec_b;
  const float *attn_W, *attn_b, *comb_W, *comb_b, *out_W, *out_b;
  float* out;
  u16 *Xbf, *encXbf, *enc_bs, *hall, *hbuf, *xb, *vb, *nbuf, *xball, *ring;
  float *combX, *scoreX, *gatesH, *cbuf, *loss_p;
  int* prevtok;
  u16 *wencWih, *wencWhh, *wdecG, *wcomb, *wattn, *wout;
  unsigned* bar;
};

// ---------- two-level device-scope grid barrier ----------
__device__ __forceinline__ void gbar(unsigned* bar, unsigned target) {
  __syncthreads();
  if (threadIdx.x == 0) {
    __threadfence();
    int g = blockIdx.x >> 4;
    unsigned a = __hip_atomic_fetch_add(bar + g * 16, 1u, __ATOMIC_ACQ_REL,
                                        __HIP_MEMORY_SCOPE_AGENT);
    if (a == 15u) {
      unsigned r = __hip_atomic_fetch_add(bar + 256, 1u, __ATOMIC_ACQ_REL,
                                          __HIP_MEMORY_SCOPE_AGENT);
      if (r == 15u) {
        for (int i = 0; i < 16; ++i)
          __hip_atomic_store(bar + i * 16, 0u, __ATOMIC_RELAXED, __HIP_MEMORY_SCOPE_AGENT);
        __hip_atomic_store(bar + 256, 0u, __ATOMIC_RELAXED, __HIP_MEMORY_SCOPE_AGENT);
        __hip_atomic_store(bar + 272, target, __ATOMIC_RELEASE, __HIP_MEMORY_SCOPE_AGENT);
      }
    }
    while (__hip_atomic_load(bar + 272, __ATOMIC_ACQUIRE, __HIP_MEMORY_SCOPE_AGENT) < target)
      __builtin_amdgcn_s_sleep(2);
  }
  __syncthreads();
}

// ---------- per-wave 32x64 tile GEMM, K=1024 ----------
// EPI: 0 bf16, 1 bf16+bias, 2 f32, 3 f32+bias
template <int EPI>
__device__ void wave_gemm(const u16* __restrict__ A, const u16* __restrict__ W,
                          int ldw, int wkoff, int colbase, const float* __restrict__ bias,
                          void* __restrict__ outp, int ldo) {
  const int lane = threadIdx.x & 63;
  const int r = lane & 15, kg = (lane >> 4) * 8;
  const u16* Ar = A + (size_t)r * 1024 + kg;
  const u16* Wr = W + (size_t)(colbase + r) * ldw + wkoff + kg;
  f32x4 acc[2][4] = {};
#pragma unroll 2
  for (int k0 = 0; k0 < 1024; k0 += 32) {
    bf16x8 a0 = *(const bf16x8*)(Ar + k0);
    bf16x8 a1 = *(const bf16x8*)(Ar + 16 * 1024 + k0);
    bf16x8 b0 = *(const bf16x8*)(Wr + k0);
    bf16x8 b1 = *(const bf16x8*)(Wr + (size_t)16 * ldw + k0);
    bf16x8 b2 = *(const bf16x8*)(Wr + (size_t)32 * ldw + k0);
    bf16x8 b3 = *(const bf16x8*)(Wr + (size_t)48 * ldw + k0);
    acc[0][0] = mfma16(a0, b0, acc[0][0]);
    acc[1][0] = mfma16(a1, b0, acc[1][0]);
    acc[0][1] = mfma16(a0, b1, acc[0][1]);
    acc[1][1] = mfma16(a1, b1, acc[1][1]);
    acc[0][2] = mfma16(a0, b2, acc[0][2]);
    acc[1][2] = mfma16(a1, b2, acc[1][2]);
    acc[0][3] = mfma16(a0, b3, acc[0][3]);
    acc[1][3] = mfma16(a1, b3, acc[1][3]);
  }
#pragma unroll
  for (int mi = 0; mi < 2; ++mi)
#pragma unroll
    for (int nj = 0; nj < 4; ++nj) {
      int col = colbase + nj * 16 + (lane & 15);
      int row0 = mi * 16 + ((lane >> 4) << 2);
#pragma unroll
      for (int reg = 0; reg < 4; ++reg) {
        float v = acc[mi][nj][reg];
        if (EPI == 1 || EPI == 3) v += bias[col];
        if (EPI <= 1) ((u16*)outp)[(size_t)(row0 + reg) * ldo + col] = f2b(v);
        else ((float*)outp)[(size_t)(row0 + reg) * ldo + col] = v;
      }
    }
}

// ---------- streamed block 32x64 grouped-col GEMM (tf=0 path) ----------
__device__ void grouped_gemm8(const u16* __restrict__ A, const u16* __restrict__ Wm,
                              int ldw, int wkoff, int grp, float* red, float* sg) {
  const int tid = threadIdx.x, w = tid >> 6, lane = tid & 63;
  const int r = lane & 15, kg = (lane >> 4) * 8;
  const int kw0 = w * 128;
  const u16* Ar = A + (size_t)r * 1024 + kw0 + kg;
  const u16* W0 = Wm + (size_t)(grp * 16 + r) * ldw + wkoff + kw0 + kg;
  const u16* W1 = W0 + (size_t)1024 * ldw;
  const u16* W2 = W0 + (size_t)2048 * ldw;
  const u16* W3 = W0 + (size_t)3072 * ldw;
  f32x4 acc[2][4] = {};
#pragma unroll
  for (int k0 = 0; k0 < 128; k0 += 32) {
    bf16x8 a0 = *(const bf16x8*)(Ar + k0);
    bf16x8 a1 = *(const bf16x8*)(Ar + 16 * 1024 + k0);
    bf16x8 b0 = *(const bf16x8*)(W0 + k0);
    bf16x8 b1 = *(const bf16x8*)(W1 + k0);
    bf16x8 b2 = *(const bf16x8*)(W2 + k0);
    bf16x8 b3 = *(const bf16x8*)(W3 + k0);
    acc[0][0] = mfma16(a0, b0, acc[0][0]);
    acc[1][0] = mfma16(a1, b0, acc[1][0]);
    acc[0][1] = mfma16(a0, b1, acc[0][1]);
    acc[1][1] = mfma16(a1, b1, acc[1][1]);
    acc[0][2] = mfma16(a0, b2, acc[0][2]);
    acc[1][2] = mfma16(a1, b2, acc[1][2]);
    acc[0][3] = mfma16(a0, b3, acc[0][3]);
    acc[1][3] = mfma16(a1, b3, acc[1][3]);
  }
#pragma unroll
  for (int mi = 0; mi < 2; ++mi)
#pragma unroll
    for (int nj = 0; nj < 4; ++nj)
#pragma unroll
      for (int reg = 0; reg < 4; ++reg)
        red[(((w * 8) + mi * 4 + nj) * 64 + lane) * 4 + reg] = acc[mi][nj][reg];
  __syncthreads();
  {
    const int p2 = w;
    const int mi = p2 >> 2, nj = p2 & 3;
#pragma unroll
    for (int reg = 0; reg < 4; ++reg) {
      float v = 0.f;
#pragma unroll
      for (int ww = 0; ww < 8; ++ww)
        v += red[(((ww * 8) + p2) * 64 + lane) * 4 + reg];
      sg[(mi * 16 + ((lane >> 4) << 2) + reg) * 64 + nj * 16 + (lane & 15)] = v;
    }
  }
  __syncthreads();
}

// ---------- pinned-weight loaders: 16 frags = 64 VGPR/thread ----------
__device__ __forceinline__ void load_wpin_gates(const u16* Wm, int ldw, int wkoff,
                                                int grp, bf16x8* wp) {
  const int w = threadIdx.x >> 6, lane = threadIdx.x & 63;
  const int r = lane & 15, kg = (lane >> 4) * 8;
  const int kw0 = w * 128;
  const u16* W0 = Wm + (size_t)(grp * 16 + r) * ldw + wkoff + kw0 + kg;
#pragma unroll
  for (int q = 0; q < 4; ++q)
#pragma unroll
    for (int ks = 0; ks < 4; ++ks)
      wp[q * 4 + ks] = *(const bf16x8*)(W0 + (size_t)(q * 1024) * ldw + ks * 32);
}

__device__ __forceinline__ void load_wpin_comb(const u16* Wm, int cb, bf16x8* wp) {
  const int w = threadIdx.x >> 6, lane = threadIdx.x & 63;
  const int r = lane & 15, kg = (lane >> 4) * 8;
  const int kw0 = w * 128;
  const u16* W0 = Wm + (size_t)(cb * 32 + r) * 2048 + 1024 + kw0 + kg;
#pragma unroll
  for (int h = 0; h < 2; ++h)
#pragma unroll
    for (int ks = 0; ks < 4; ++ks)
      wp[h * 4 + ks] = *(const bf16x8*)(W0 + (size_t)(h * 16) * 2048 + ks * 32);
}

// ---------- pinned grouped-col GEMM -> sg[32][64] (same math/order as grouped_gemm8) ----------
__device__ void grouped_gemm8_pinned(const u16* __restrict__ A, const bf16x8* wp,
                                     float* red, float* sg) {
  const int tid = threadIdx.x, w = tid >> 6, lane = tid & 63;
  const int r = lane & 15, kg = (lane >> 4) * 8;
  const int kw0 = w * 128;
  const u16* Ar = A + (size_t)r * 1024 + kw0 + kg;
  f32x4 acc[2][4] = {};
#pragma unroll
  for (int ks = 0; ks < 4; ++ks) {
    bf16x8 a0 = *(const bf16x8*)(Ar + ks * 32);
    bf16x8 a1 = *(const bf16x8*)(Ar + 16 * 1024 + ks * 32);
    acc[0][0] = mfma16(a0, wp[0 + ks], acc[0][0]);
    acc[1][0] = mfma16(a1, wp[0 + ks], acc[1][0]);
    acc[0][1] = mfma16(a0, wp[4 + ks], acc[0][1]);
    acc[1][1] = mfma16(a1, wp[4 + ks], acc[1][1]);
    acc[0][2] = mfma16(a0, wp[8 + ks], acc[0][2]);
    acc[1][2] = mfma16(a1, wp[8 + ks], acc[1][2]);
    acc[0][3] = mfma16(a0, wp[12 + ks], acc[0][3]);
    acc[1][3] = mfma16(a1, wp[12 + ks], acc[1][3]);
  }
#pragma unroll
  for (int mi = 0; mi < 2; ++mi)
#pragma unroll
    for (int nj = 0; nj < 4; ++nj)
#pragma unroll
      for (int reg = 0; reg < 4; ++reg)
        red[(((w * 8) + mi * 4 + nj) * 64 + lane) * 4 + reg] = acc[mi][nj][reg];
  __syncthreads();
  {
    const int p2 = w;
    const int mi = p2 >> 2, nj = p2 & 3;
#pragma unroll
    for (int reg = 0; reg < 4; ++reg) {
      float v = 0.f;
#pragma unroll
      for (int ww = 0; ww < 8; ++ww)
        v += red[(((ww * 8) + p2) * 64 + lane) * 4 + reg];
      sg[(mi * 16 + ((lane >> 4) << 2) + reg) * 64 + nj * 16 + (lane & 15)] = v;
    }
  }
  __syncthreads();
}

// ---------- streamed comb (tf=0): K=2048 over [xb|vb] ----------
template <int KTOT, bool HASX>
__device__ void comb8(const Params& p, int cb, int t, float* red) {
  const int tid = threadIdx.x, w = tid >> 6, lane = tid & 63;
  const int r = lane & 15, kg = (lane >> 4) * 8;
  constexpr int KSW = KTOT / 8;
  const int kw0 = w * KSW;
  const u16* Abase;
  int koff;
  if (KTOT == 2048) { Abase = (kw0 < 1024) ? p.xb : p.vb; koff = kw0 & 1023; }
  else { Abase = p.vb; koff = kw0; }
  const u16* Ar = Abase + (size_t)r * 1024 + koff + kg;
  const int wko = (KTOT == 1024) ? 1024 : 0;
  const u16* W0 = p.wcomb + (size_t)(cb * 32 + r) * 2048 + wko + kw0 + kg;
  const u16* W1 = W0 + (size_t)16 * 2048;
  f32x4 acc[2][2] = {};
#pragma unroll
  for (int k0 = 0; k0 < KSW; k0 += 32) {
    bf16x8 a0 = *(const bf16x8*)(Ar + k0);
    bf16x8 a1 = *(const bf16x8*)(Ar + 16 * 1024 + k0);
    bf16x8 b0 = *(const bf16x8*)(W0 + k0);
    bf16x8 b1 = *(const bf16x8*)(W1 + k0);
    acc[0][0] = mfma16(a0, b0, acc[0][0]);
    acc[1][0] = mfma16(a1, b0, acc[1][0]);
    acc[0][1] = mfma16(a0, b1, acc[0][1]);
    acc[1][1] = mfma16(a1, b1, acc[1][1]);
  }
#pragma unroll
  for (int mi = 0; mi < 2; ++mi)
#pragma unroll
    for (int nj = 0; nj < 2; ++nj)
#pragma unroll
      for (int reg = 0; reg < 4; ++reg)
        red[(((w * 4) + mi * 2 + nj) * 64 + lane) * 4 + reg] = acc[mi][nj][reg];
  __syncthreads();
  if (w < 4) {
    const int p2 = w, mi = p2 >> 1, nj = p2 & 1;
#pragma unroll
    for (int reg = 0; reg < 4; ++reg) {
      float v = 0.f;
#pragma unroll
      for (int ww = 0; ww < 8; ++ww)
        v += red[(((ww * 4) + p2) * 64 + lane) * 4 + reg];
      int row = mi * 16 + ((lane >> 4) << 2) + reg;
      int col = cb * 32 + nj * 16 + (lane & 15);
      if (HASX) v += p.combX[(size_t)(t * 32 + row) * 1024 + col];
      v += p.comb_b[col];
      p.nbuf[(size_t)row * 1024 + col] = f2b(fmaxf(v, 0.f));
    }
  }
  __syncthreads();
}

// ---------- pinned comb (tf=1): v-half K=1024 + combX + bias, relu -> nbuf ----------
__device__ void comb8_pinned(const Params& p, int cb, int t, const bf16x8* wp, float* red) {
  const int tid = threadIdx.x, w = tid >> 6, lane = tid & 63;
  const int r = lane & 15, kg = (lane >> 4) * 8;
  const int kw0 = w * 128;
  const u16* Ar = p.vb + (size_t)r * 1024 + kw0 + kg;
  f32x4 acc[2][2] = {};
#pragma unroll
  for (int ks = 0; ks < 4; ++ks) {
    bf16x8 a0 = *(const bf16x8*)(Ar + ks * 32);
    bf16x8 a1 = *(const bf16x8*)(Ar + 16 * 1024 + ks * 32);
    acc[0][0] = mfma16(a0, wp[0 + ks], acc[0][0]);
    acc[1][0] = mfma16(a1, wp[0 + ks], acc[1][0]);
    acc[0][1] = mfma16(a0, wp[4 + ks], acc[0][1]);
    acc[1][1] = mfma16(a1, wp[4 + ks], acc[1][1]);
  }
#pragma unroll
  for (int mi = 0; mi < 2; ++mi)
#pragma unroll
    for (int nj = 0; nj < 2; ++nj)
#pragma unroll
      for (int reg = 0; reg < 4; ++reg)
        red[(((w * 4) + mi * 2 + nj) * 64 + lane) * 4 + reg] = acc[mi][nj][reg];
  __syncthreads();
  if (w < 4) {
    const int p2 = w, mi = p2 >> 1, nj = p2 & 1;
#pragma unroll
    for (int reg = 0; reg < 4; ++reg) {
      float v = 0.f;
#pragma unroll
      for (int ww = 0; ww < 8; ++ww)
        v += red[(((ww * 4) + p2) * 64 + lane) * 4 + reg];
      int row = mi * 16 + ((lane >> 4) << 2) + reg;
      int col = cb * 32 + nj * 16 + (lane & 15);
      v += p.combX[(size_t)(t * 32 + row) * 1024 + col] + p.comb_b[col];
      p.nbuf[(size_t)row * 1024 + col] = f2b(fmaxf(v, 0.f));
    }
  }
  __syncthreads();
}

// ---------- log-softmax loss over one bf16 logits row (512 threads) ----------
template <bool AM>
__device__ void loss_row_bf16(const u16* __restrict__ row, int tgt,
                              float* __restrict__ loss_out, int* __restrict__ am_out,
                              float* sh) {
  float* sm = sh;
  float* ss = sh + 512;
  float* sbv = sh + 1024;
  int* sbi = (int*)(sh + 1536);
  const int tid = threadIdx.x;
  float m = -INFINITY, ssum = 0.f, bestv = -INFINITY;
  int besti = 0x7fffffff;
  for (int v = tid; v < V_; v += BT) {
    float x = b2f(row[v]);
    if (x > m) { ssum = ssum * expf(m - x) + 1.f; m = x; }
    else ssum += expf(x - m);
    if (AM) { if (x > bestv) { bestv = x; besti = v; } }
  }
  sm[tid] = m; ss[tid] = ssum;
  if (AM) { sbv[tid] = bestv; sbi[tid] = besti; }
  __syncthreads();
  for (int off = 256; off; off >>= 1) {
    if (tid < off) {
      float m2 = sm[tid + off], s2 = ss[tid + off];
      float mn = fmaxf(sm[tid], m2);
      ss[tid] = ss[tid] * expf(sm[tid] - mn) + s2 * expf(m2 - mn);
      sm[tid] = mn;
      if (AM) {
        float bv2 = sbv[tid + off];
        int bi2 = sbi[tid + off];
        if (bv2 > sbv[tid] || (bv2 == sbv[tid] && bi2 < sbi[tid])) { sbv[tid] = bv2; sbi[tid] = bi2; }
      }
    }
    __syncthreads();
  }
  if (tid == 0) {
    float lp = b2f(row[tgt]) - (sm[0] + logf(ss[0]));
    *loss_out = -lp * (1.f / 32.f);
    if (AM) *am_out = sbi[0];
  }
  __syncthreads();
}

// =================== main persistent kernel ===================
__global__ void binit(unsigned* bar) {
  int i = threadIdx.x;
  if (i < 288) bar[i] = 0u;
}

__global__ __launch_bounds__(BT, 2) void seq2seq_all(Params p) {
  __shared__ float red_s[16384];   // 64 KB
  __shared__ float sg_s[2048];     // 8 KB
  unsigned bargen = 0;
  const int tid = threadIdx.x, bid = blockIdx.x;
  const int gtid = bid * BT + tid;
  const int gwid = bid * 8 + (tid >> 6);
  const int utf = p.use_tf[0];
  bf16x8 wpin[16];   // register-stationary weight slice (role depends on bid)

  // ---------- phase 0: zero state + weight conversions + gathers ----------
  for (int i = gtid; i < B_ * H_; i += NTHR) { p.cbuf[i] = 0.f; p.hbuf[i] = 0; }
  for (int i = gtid; i < G_ * H_ / 4; i += NTHR) {
    float4 v = *(const float4*)(p.enc_Wih + (size_t)i * 4);
    *(ushort4*)(p.wencWih + (size_t)i * 4) = make_ushort4(f2b(v.x), f2b(v.y), f2b(v.z), f2b(v.w));
  }
  for (int i = gtid; i < G_ * H_ / 4; i += NTHR) {
    float4 v = *(const float4*)(p.enc_Whh + (size_t)i * 4);
    *(ushort4*)(p.wencWhh + (size_t)i * 4) = make_ushort4(f2b(v.x), f2b(v.y), f2b(v.z), f2b(v.w));
  }
  for (int i = gtid; i < 2 * H_ * H_ / 4; i += NTHR) {
    float4 v = *(const float4*)(p.comb_W + (size_t)i * 4);
    *(ushort4*)(p.wcomb + (size_t)i * 4) = make_ushort4(f2b(v.x), f2b(v.y), f2b(v.z), f2b(v.w));
  }
  for (int i = gtid; i < S_ * 2 * H_ / 4; i += NTHR) {
    float4 v = *(const float4*)(p.attn_W + (size_t)i * 4);
    *(ushort4*)(p.wattn + (size_t)i * 4) = make_ushort4(f2b(v.x), f2b(v.y), f2b(v.z), f2b(v.w));
  }
  for (int i = gtid; i < V_ * H_ / 4; i += NTHR) {
    float4 v = *(const float4*)(p.out_W + (size_t)i * 4);
    *(ushort4*)(p.wout + (size_t)i * 4) = make_ushort4(f2b(v.x), f2b(v.y), f2b(v.z), f2b(v.w));
  }
  for (int i = gtid; i < G_ * 512; i += NTHR) {   // [dec_Wih | dec_Whh]
    int n = i >> 9, k4 = (i & 511) * 4;
    const float* src = (k4 < 1024) ? (p.dec_Wih + (size_t)n * 1024 + k4)
                                   : (p.dec_Whh + (size_t)n * 1024 + (k4 - 1024));
    float4 v = *(const float4*)src;
    *(ushort4*)(p.wdecG + (size_t)n * 2048 + k4) = make_ushort4(f2b(v.x), f2b(v.y), f2b(v.z), f2b(v.w));
  }
  for (int i = gtid; i < S_ * B_ * 256; i += NTHR) {   // encoder embedding gather
    int m = i >> 8, k4 = (i & 255) * 4;
    float4 v = *(const float4*)(p.enc_emb + (size_t)p.input[m] * 1024 + k4);
    *(ushort4*)(p.Xbf + (size_t)m * 1024 + k4) = make_ushort4(f2b(v.x), f2b(v.y), f2b(v.z), f2b(v.w));
  }
  for (int i = gtid; i < T_ * B_ * 256; i += NTHR) {   // teacher-forced decoder x (relu)
    int m = i >> 8, k4 = (i & 255) * 4;
    int t = m >> 5, b = m & 31;
    int tok = (t == 0) ? 0 : p.target[(t - 1) * 32 + b];
    float4 v = *(const float4*)(p.dec_emb + (size_t)tok * 1024 + k4);
    *(ushort4*)(p.xball + (size_t)m * 1024 + k4) =
        make_ushort4(f2b(fmaxf(v.x, 0.f)), f2b(fmaxf(v.y, 0.f)),
                     f2b(fmaxf(v.z, 0.f)), f2b(fmaxf(v.w, 0.f)));
  }
  gbar(p.bar, ++bargen);

  // ---------- phase 1: batched GEMMs: encX (4096) | combX (1024) | scoreX (64) ----------
  for (int task = gwid; task < 4096 + 1024 + 64; task += NWAVE) {
    if (task < 4096) {
      int mt = task >> 6, ct = task & 63;
      wave_gemm<0>(p.Xbf + (size_t)mt * 32 * 1024, p.wencWih, 1024, 0, ct * 64,
                   nullptr, p.encXbf + (size_t)mt * 32 * G_, G_);
    } else if (task < 5120) {
      int tt = task - 4096, mt = tt >> 4, ct = tt & 15;
      wave_gemm<2>(p.xball + (size_t)mt * 32 * 1024, p.wcomb, 2048, 0, ct * 64,
                   nullptr, p.combX + (size_t)mt * 32 * 1024, 1024);
    } else {
      int mt = task - 5120;
      wave_gemm<3>(p.xball + (size_t)mt * 32 * 1024, p.wattn, 2048, 0, 0,
                   p.attn_b, p.scoreX + (size_t)mt * 32 * 64, 64);
    }
  }
  gbar(p.bar, ++bargen);

  // ---------- phase 2: encoder on blocks 64..127 with pinned encWhh ----------
  if (bid >= 64 && bid < 128)
    load_wpin_gates(p.wencWhh, 1024, 0, bid - 64, wpin);
  int pe = 0;
  for (int s = 0; s < 64; ++s) {
    if (bid >= 64 && bid < 128) {
      const int grp = bid - 64;
      const u16* hprev = p.hbuf + (size_t)pe * B_ * H_;
      u16* hnext = p.hbuf + (size_t)(pe ^ 1) * B_ * H_;
      grouped_gemm8_pinned(hprev, wpin, red_s, sg_s);
      {
        int slot = tid;
        int b = slot >> 4, jj = slot & 15, j = grp * 16 + jj;
        size_t xo = (size_t)(s * 32 + b) * G_;
        float g0 = sg_s[b * 64 + jj]      + b2f(p.encXbf[xo + j])        + p.enc_b[j];
        float g1 = sg_s[b * 64 + 16 + jj] + b2f(p.encXbf[xo + 1024 + j]) + p.enc_b[1024 + j];
        float g2 = sg_s[b * 64 + 32 + jj] + b2f(p.encXbf[xo + 2048 + j]) + p.enc_b[2048 + j];
        float g3 = sg_s[b * 64 + 48 + jj] + b2f(p.encXbf[xo + 3072 + j]) + p.enc_b[3072 + j];
        float ig = sigf(g0), fg = sigf(g1), gg = tanhf(g2), og = sigf(g3);
        float cn = fg * p.cbuf[b * 1024 + j] + ig * gg;
        float hn = og * tanhf(cn);
        p.cbuf[b * 1024 + j] = cn;
        u16 hb2 = f2b(hn);
        hnext[b * 1024 + j] = hb2;
        p.enc_bs[((size_t)b * 1024 + j) * 64 + s] = hb2;
      }
    }
    pe ^= 1;
    gbar(p.bar, ++bargen);
  }

  // ---------- phase 3: decoder ----------
  int pd = pe;   // == 0
  if (utf) {
    // re-pin for decoder roles
    if (bid < 32)                      load_wpin_comb(p.wcomb, bid, wpin);
    else if (bid >= 64 && bid < 128)   load_wpin_gates(p.wdecG, 2048, 1024, bid - 64, wpin);
    else if (bid >= 128 && bid < 192)  load_wpin_gates(p.wdecG, 2048, 0, bid - 128, wpin);
    for (int t = 0; t < 64; ++t) {
      const u16* hprev = p.hbuf + (size_t)pd * B_ * H_;
      u16* hnext = p.hbuf + (size_t)(pd ^ 1) * B_ * H_;
      const bool batch = ((t & 7) == 0) && (t > 0);   // grid-uniform
      // ---- phase A: attention h-part (0..31) || gatesH pinned (64..127) ----
      if (bid < 32) {
        float* hsh = red_s;            // 1024
        float* ssc = red_s + 1024;     // 512
        float* aw  = red_s + 1536;     // 64
        const int b = bid;
        {
          ushort2 hq = *(const ushort2*)(hprev + (size_t)b * 1024 + tid * 2);
          hsh[tid * 2] = b2f(hq.x);
          hsh[tid * 2 + 1] = b2f(hq.y);
        }
        __syncthreads();
        {
          const int sidx = tid & 63, q = tid >> 6;
          const u16* wr = p.wattn + (size_t)sidx * 2048 + 1024 + q * 128;
          const float* src = hsh + q * 128;
          float acc = 0.f;
          for (int k8 = 0; k8 < 16; ++k8) {
            bf16x8 v = *(const bf16x8*)(wr + k8 * 8);
#pragma unroll
            for (int e = 0; e < 8; ++e)
              acc = fmaf(src[k8 * 8 + e], b2f((u16)v[e]), acc);
          }
          ssc[q * 64 + sidx] = acc;
        }
        __syncthreads();
        if (tid < 64) {
          float sc = p.scoreX[(size_t)(t * 32 + b) * 64 + tid];
#pragma unroll
          for (int q = 0; q < 8; ++q) sc += ssc[q * 64 + tid];
          float m = sc;
#pragma unroll
          for (int off = 32; off; off >>= 1) m = fmaxf(m, __shfl_xor(m, off));
          float e = expf(sc - m), sum = e;
#pragma unroll
          for (int off = 32; off; off >>= 1) sum += __shfl_xor(sum, off);
          aw[tid] = e / sum;
        }
        __syncthreads();
        for (int j = tid; j < 1024; j += BT) {
          const u16* rowp = p.enc_bs + ((size_t)b * 1024 + j) * 64;
          float acc = 0.f;
#pragma unroll
          for (int s8 = 0; s8 < 8; ++s8) {
            bf16x8 v = *(const bf16x8*)(rowp + s8 * 8);
#pragma unroll
            for (int e = 0; e < 8; ++e)
              acc = fmaf(aw[s8 * 8 + e], b2f((u16)v[e]), acc);
          }
          p.vb[(size_t)b * 1024 + j] = f2b(acc);
        }
      } else if (bid >= 64 && bid < 128) {
        const int grp = bid - 64;
        grouped_gemm8_pinned(hprev, wpin, red_s, sg_s);
        {
          int slot = tid;
          int b = slot >> 4, jj = slot & 15, j = grp * 16 + jj;
          p.gatesH[(size_t)b * G_ + j]        = sg_s[b * 64 + jj];
          p.gatesH[(size_t)b * G_ + 1024 + j] = sg_s[b * 64 + 16 + jj];
          p.gatesH[(size_t)b * G_ + 2048 + j] = sg_s[b * 64 + 32 + jj];
          p.gatesH[(size_t)b * G_ + 3072 + j] = sg_s[b * 64 + 48 + jj];
        }
      }
      gbar(p.bar, ++bargen);
      // ---- phase B: comb-v pinned (0..31) || batched logits h[t-8..t-1] (32..255, every 8th) ----
      if (bid < 32) {
        comb8_pinned(p, bid, t, wpin, red_s);
      } else if (batch) {
        const u16* Abase = p.hall + (size_t)(t - 8) * 32 * 1024;
        for (int task = (bid - 32) * 8 + (tid >> 6); task < 4000; task += 224 * 8) {
          int ct = task >> 3, mt = task & 7;
          wave_gemm<1>(Abase + (size_t)mt * 32 * 1024, p.wout, 1024, 0, ct * 64,
                       p.out_b, p.ring + (size_t)mt * 32 * V_, V_);
        }
      }
      gbar(p.bar, ++bargen);
      // ---- phase C: gates-x pinned + LSTM (128..191) || batch loss (192..255) ----
      if (bid >= 128 && bid < 192) {
        const int grp = bid - 128;
        grouped_gemm8_pinned(p.nbuf, wpin, red_s, sg_s);
        {
          int slot = tid;
          int b = slot >> 4, jj = slot & 15, j = grp * 16 + jj;
          float g0 = sg_s[b * 64 + jj]      + p.gatesH[(size_t)b * G_ + j]        + p.dec_b[j];
          float g1 = sg_s[b * 64 + 16 + jj] + p.gatesH[(size_t)b * G_ + 1024 + j] + p.dec_b[1024 + j];
          float g2 = sg_s[b * 64 + 32 + jj] + p.gatesH[(size_t)b * G_ + 2048 + j] + p.dec_b[2048 + j];
          float g3 = sg_s[b * 64 + 48 + jj] + p.gatesH[(size_t)b * G_ + 3072 + j] + p.dec_b[3072 + j];
          float ig = sigf(g0), fg = sigf(g1), gg = tanhf(g2), og = sigf(g3);
          float cn = fg * p.cbuf[b * 1024 + j] + ig * gg;
          float hn = og * tanhf(cn);
          p.cbuf[b * 1024 + j] = cn;
          u16 hb2 = f2b(hn);
          hnext[b * 1024 + j] = hb2;
          p.hall[((size_t)t * 32 + b) * 1024 + j] = hb2;
        }
      } else if (bid >= 192 && batch) {
        int base = (bid - 192) * 4;
        for (int rr = 0; rr < 4; ++rr) {
          int m = base + rr, gm = (t - 8) * 32 + m;
          loss_row_bf16<false>(p.ring + (size_t)m * V_, p.target[gm], &p.loss_p[gm],
                               nullptr, red_s);
        }
      }
      gbar(p.bar, ++bargen);
      pd ^= 1;
    }
    // ---- E1: batched logits for h[56..63] on all 256 blocks ----
    {
      const u16* Abase = p.hall + (size_t)56 * 32 * 1024;
      for (int task = bid * 8 + (tid >> 6); task < 4000; task += 2048) {
        int ct = task >> 3, mt = task & 7;
        wave_gemm<1>(Abase + (size_t)mt * 32 * 1024, p.wout, 1024, 0, ct * 64,
                     p.out_b, p.ring + (size_t)mt * 32 * V_, V_);
      }
    }
    gbar(p.bar, ++bargen);
    // ---- E2: loss rows 1792..2047 on blocks 0..127 ----
    if (bid < 128) {
      for (int rr = 0; rr < 2; ++rr) {
        int m = bid * 2 + rr, gm = 56 * 32 + m;
        loss_row_bf16<false>(p.ring + (size_t)m * V_, p.target[gm], &p.loss_p[gm],
                             nullptr, red_s);
      }
    }
    gbar(p.bar, ++bargen);
  } else {
    // ---- tf=0: per-step feedback path (correct, not speed-critical) ----
    for (int t = 0; t < 64; ++t) {
      const u16* hprev = p.hbuf + (size_t)pd * B_ * H_;
      u16* hnext = p.hbuf + (size_t)(pd ^ 1) * B_ * H_;
      if (bid < 32) {
        float* xsh = red_s;
        float* hsh = red_s + 1024;
        float* ssc = red_s + 2048;
        float* aw  = red_s + 2560;
        const int b = bid;
        int tok = (t > 0) ? p.prevtok[b] : 0;
        {
          float2 v = *(const float2*)(p.dec_emb + (size_t)tok * 1024 + tid * 2);
          float x0 = fmaxf(v.x, 0.f), x1 = fmaxf(v.y, 0.f);
          xsh[tid * 2] = x0; xsh[tid * 2 + 1] = x1;
          *(ushort2*)(p.xb + (size_t)b * 1024 + tid * 2) = make_ushort2(f2b(x0), f2b(x1));
          ushort2 hq = *(const ushort2*)(hprev + (size_t)b * 1024 + tid * 2);
          hsh[tid * 2] = b2f(hq.x); hsh[tid * 2 + 1] = b2f(hq.y);
        }
        __syncthreads();
        {
          const int sidx = tid & 63, q = tid >> 6;
          const u16* wr = p.wattn + (size_t)sidx * 2048 + q * 256;
          const float* src = (q < 4) ? (xsh + q * 256) : (hsh + (q - 4) * 256);
          float acc = 0.f;
          for (int k8 = 0; k8 < 32; ++k8) {
            bf16x8 v = *(const bf16x8*)(wr + k8 * 8);
#pragma unroll
            for (int e = 0; e < 8; ++e)
              acc = fmaf(src[k8 * 8 + e], b2f((u16)v[e]), acc);
          }
          ssc[q * 64 + sidx] = acc;
        }
        __syncthreads();
        if (tid < 64) {
          float sc = p.attn_b[tid];
#pragma unroll
          for (int q = 0; q < 8; ++q) sc += ssc[q * 64 + tid];
          float m = sc;
#pragma unroll
          for (int off = 32; off; off >>= 1) m = fmaxf(m, __shfl_xor(m, off));
          float e = expf(sc - m), sum = e;
#pragma unroll
          for (int off = 32; off; off >>= 1) sum += __shfl_xor(sum, off);
          aw[tid] = e / sum;
        }
        __syncthreads();
        for (int j = tid; j < 1024; j += BT) {
          const u16* rowp = p.enc_bs + ((size_t)b * 1024 + j) * 64;
          float acc = 0.f;
#pragma unroll
          for (int s8 = 0; s8 < 8; ++s8) {
            bf16x8 v = *(const bf16x8*)(rowp + s8 * 8);
#pragma unroll
            for (int e = 0; e < 8; ++e)
              acc = fmaf(aw[s8 * 8 + e], b2f((u16)v[e]), acc);
          }
          p.vb[(size_t)b * 1024 + j] = f2b(acc);
        }
      } else if (bid >= 64 && bid < 128) {
        const int grp = bid - 64;
        grouped_gemm8(hprev, p.wdecG, 2048, 1024, grp, red_s, sg_s);
        {
          int slot = tid;
          int b = slot >> 4, jj = slot & 15, j = grp * 16 + jj;
          p.gatesH[(size_t)b * G_ + j]        = sg_s[b * 64 + jj];
          p.gatesH[(size_t)b * G_ + 1024 + j] = sg_s[b * 64 + 16 + jj];
          p.gatesH[(size_t)b * G_ + 2048 + j] = sg_s[b * 64 + 32 + jj];
          p.gatesH[(size_t)b * G_ + 3072 + j] = sg_s[b * 64 + 48 + jj];
        }
      }
      gbar(p.bar, ++bargen);
      if (bid < 32) comb8<2048, false>(p, bid, t, red_s);
      gbar(p.bar, ++bargen);
      if (bid < 64) {
        grouped_gemm8(p.nbuf, p.wdecG, 2048, 0, bid, red_s, sg_s);
        {
          int slot = tid;
          int b = slot >> 4, jj = slot & 15, j = bid * 16 + jj;
          float g0 = sg_s[b * 64 + jj]      + p.gatesH[(size_t)b * G_ + j]        + p.dec_b[j];
          float g1 = sg_s[b * 64 + 16 + jj] + p.gatesH[(size_t)b * G_ + 1024 + j] + p.dec_b[1024 + j];
          float g2 = sg_s[b * 64 + 32 + jj] + p.gatesH[(size_t)b * G_ + 2048 + j] + p.dec_b[2048 + j];
          float g3 = sg_s[b * 64 + 48 + jj] + p.gatesH[(size_t)b * G_ + 3072 + j] + p.dec_b[3072 + j];
          float ig = sigf(g0), fg = sigf(g1), gg = tanhf(g2), og = sigf(g3);
          float cn = fg * p.cbuf[b * 1024 + j] + ig * gg;
          float hn = og * tanhf(cn);
          p.cbuf[b * 1024 + j] = cn;
          u16 hb2 = f2b(hn);
          hnext[b * 1024 + j] = hb2;
          p.hall[((size_t)t * 32 + b) * 1024 + j] = hb2;
        }
      }
      gbar(p.bar, ++bargen);
      pd ^= 1;
      for (int task = gwid; task < 500; task += NWAVE)
        wave_gemm<1>(p.hbuf + (size_t)pd * B_ * H_, p.wout, 1024, 0, task * 64,
                     p.out_b, p.ring, V_);
      gbar(p.bar, ++bargen);
      if (bid < 32)
        loss_row_bf16<true>(p.ring + (size_t)bid * V_, p.target[t * 32 + bid],
                            &p.loss_p[t * 32 + bid], &p.prevtok[bid], red_s);
      gbar(p.bar, ++bargen);
    }
  }

  // ---------- final sum ----------
  if (bid == 0) {
    float a = 0.f;
    for (int i = tid; i < T_ * B_; i += BT) a += p.loss_p[i];
    red_s[tid] = a;
    __syncthreads();
    for (int off = 256; off; off >>= 1) {
      if (tid < off) red_s[tid] += red_s[tid + off];
      __syncthreads();
    }
    if (tid == 0) p.out[0] = red_s[0];
  }
}

// ---------------- host launch ----------------
extern "C" void kernel_launch(void* const* d_in, const int* in_sizes, int n_in,
                              void* d_out, int out_size, void* d_ws, size_t ws_size,
                              hipStream_t stream) {
  (void)in_sizes; (void)n_in; (void)out_size; (void)ws_size;
  Params p;
  p.input   = (const int*)d_in[0];
  p.target  = (const int*)d_in[1];
  p.use_tf  = (const int*)d_in[2];
  p.enc_emb = (const float*)d_in[3];
  p.enc_Wih = (const float*)d_in[4];
  p.enc_Whh = (const float*)d_in[5];
  p.enc_b   = (const float*)d_in[6];
  p.dec_emb = (const float*)d_in[7];
  p.dec_Wih = (const float*)d_in[8];
  p.dec_Whh = (const float*)d_in[9];
  p.dec_b   = (const float*)d_in[10];
  p.attn_W  = (const float*)d_in[11];
  p.attn_b  = (const float*)d_in[12];
  p.comb_W  = (const float*)d_in[13];
  p.comb_b  = (const float*)d_in[14];
  p.out_W   = (const float*)d_in[15];
  p.out_b   = (const float*)d_in[16];
  p.out     = (float*)d_out;

  char* ws = (char*)d_ws;
  size_t off = 0;
  auto alloc = [&](size_t bytes) {
    void* q = ws + off;
    off += ((bytes + 255) & ~(size_t)255);
    return q;
  };
  p.Xbf     = (u16*)alloc((size_t)S_ * B_ * H_ * 2);       // 4.2 MB
  p.encXbf  = (u16*)alloc((size_t)S_ * B_ * G_ * 2);       // 16.8 MB (dead after encoder; ring aliases)
  p.enc_bs  = (u16*)alloc((size_t)B_ * H_ * S_ * 2);       // 4.2 MB
  p.hall    = (u16*)alloc((size_t)T_ * B_ * H_ * 2);       // 4.2 MB
  p.hbuf    = (u16*)alloc((size_t)2 * B_ * H_ * 2);
  p.xb      = (u16*)alloc((size_t)B_ * H_ * 2);
  p.vb      = (u16*)alloc((size_t)B_ * H_ * 2);
  p.nbuf    = (u16*)alloc((size_t)B_ * H_ * 2);
  p.xball   = (u16*)alloc((size_t)T_ * B_ * H_ * 2);       // 4.2 MB
  p.combX   = (float*)alloc((size_t)T_ * B_ * H_ * 4);     // 8.4 MB
  p.scoreX  = (float*)alloc((size_t)T_ * B_ * 64 * 4);     // 0.5 MB
  p.gatesH  = (float*)alloc((size_t)B_ * G_ * 4);          // 0.5 MB
  p.cbuf    = (float*)alloc((size_t)B_ * H_ * 4);
  p.loss_p  = (float*)alloc((size_t)T_ * B_ * 4);
  p.prevtok = (int*)alloc(B_ * 4);
  p.bar     = (unsigned*)alloc(1024);
  p.wencWih = (u16*)alloc((size_t)G_ * H_ * 2);            // 8.4 MB
  p.wencWhh = (u16*)alloc((size_t)G_ * H_ * 2);            // 8.4 MB
  p.wdecG   = (u16*)alloc((size_t)G_ * 2 * H_ * 2);        // 16.8 MB
  p.wcomb   = (u16*)alloc((size_t)H_ * 2 * H_ * 2);        // 4.2 MB
  p.wattn   = (u16*)alloc((size_t)S_ * 2 * H_ * 2);        // 0.26 MB
  p.wout    = (u16*)alloc((size_t)V_ * H_ * 2);            // 65.5 MB
  // logits ring: 256 rows x 32000 bf16 = 16.38 MB, aliases dead-after-encoder encXbf (16.8 MB)
  p.ring = p.encXbf;
  // total ~147 MB

  binit<<<1, 288, 0, stream>>>(p.bar);
  seq2seq_all<<<NB, BT, 0, stream>>>(p);
}